// Round 5
// baseline (2505.127 us; speedup 1.0000x reference)
//
#include <hip/hip_runtime.h>
#include <hip/hip_cooperative_groups.h>
#include <math.h>

namespace cg = cooperative_groups;

// ---------------------------------------------------------------------------
// CNN-LSTM video predictor, fp32, round 5:
//  - all convs as "direct" kernels: thread = one output position x CO-tile,
//    weights via wave-uniform loads (scalar pipe), NHWC float4 activations,
//    no LDS, no barriers.
//  - dt4 specialized (CO=3, 4 parities/thread, sigmoid, NCHW float2 stores).
//  - entire LSTM section = ONE cooperative kernel (gx + 32 steps + zs).
// ---------------------------------------------------------------------------

__device__ __forceinline__ float sig_(float x) { return 1.f / (1.f + expf(-x)); }
__device__ __forceinline__ float dot4(float4 a, float4 b) {
    return a.x * b.x + a.y * b.y + a.z * b.z + a.w * b.w;
}
// LSTM column permutation: col c -> original gate row
__device__ __forceinline__ int orig_row(int c) {
    return ((c >> 3) & 3) * 512 + (c >> 5) * 8 + (c & 7);
}

// =================== direct strided conv (s2,k4,p1,relu) ====================
// X: NHWC [256][HI][WI][CI]; Wd: float4 [(ci4*CO+co)*16+tap]; y: NHWC.
template<int CI, int HI, int WI, int CO, int COT>
__global__ __launch_bounds__(256)
void conv_dir(const float* __restrict__ X, const float4* __restrict__ Wd,
              const float* __restrict__ bias, float* __restrict__ y) {
    constexpr int HO = HI / 2, WO = WI / 2, HWO = HO * WO;
    constexpr int MB = (256 * HWO) / 256;
    int bid = blockIdx.x;
    int mblk = bid % MB; int co0 = (bid / MB) * COT;
    int m = mblk * 256 + threadIdx.x;
    int n = m / HWO, rem = m % HWO;
    int oh = rem / WO, ow = rem % WO;
    float acc[COT];
#pragma unroll
    for (int j = 0; j < COT; ++j) acc[j] = bias[co0 + j];
    const float* xn = X + (long)n * HI * WI * CI;
    for (int ci4 = 0; ci4 < CI / 4; ++ci4) {
        float4 xv[16];
#pragma unroll
        for (int r = 0; r < 4; ++r) {
            int ih = 2 * oh + r - 1;
#pragma unroll
            for (int c = 0; c < 4; ++c) {
                int iw = 2 * ow + c - 1;
                float4 v = {0.f, 0.f, 0.f, 0.f};
                if ((unsigned)ih < (unsigned)HI && (unsigned)iw < (unsigned)WI)
                    v = *(const float4*)(xn + ((long)ih * WI + iw) * CI + ci4 * 4);
                xv[r * 4 + c] = v;
            }
        }
        const float4* wp = Wd + ((long)ci4 * CO + co0) * 16;
#pragma unroll
        for (int j = 0; j < COT; ++j)
#pragma unroll
            for (int tap = 0; tap < 16; ++tap)
                acc[j] += dot4(xv[tap], wp[j * 16 + tap]);
    }
    float* yp = y + (long)m * CO + co0;
#pragma unroll
    for (int j = 0; j < COT; ++j) yp[j] = fmaxf(acc[j], 0.f);
}

// ================= direct transposed conv (s2,k4,p1, relu) ==================
// thread = one input position, computes 2x2 output quad x COT channels.
// Wd: float4 [((ci4*CO+co)*4+par)*4+t4], tap(par,t4)=(p+2dh)*4+(q+2dw).
template<int CI, int HI, int WI, int CO, int COT>
__global__ __launch_bounds__(256)
void convt_dir(const float* __restrict__ X, const float4* __restrict__ Wd,
               const float* __restrict__ bias, float* __restrict__ y) {
    constexpr int HWI = HI * WI, MB = (256 * HWI) / 256;
    constexpr int HO = HI * 2, WO = WI * 2;
    int bid = blockIdx.x;
    int mblk = bid % MB; int co0 = (bid / MB) * COT;
    int m = mblk * 256 + threadIdx.x;
    int n = m / HWI, rem = m % HWI;
    int yy = rem / WI, xx = rem % WI;
    float acc[COT][4];
#pragma unroll
    for (int j = 0; j < COT; ++j) {
        float b = bias[co0 + j];
#pragma unroll
        for (int par = 0; par < 4; ++par) acc[j][par] = b;
    }
    const float* xn = X + (long)n * HWI * CI;
    for (int ci4 = 0; ci4 < CI / 4; ++ci4) {
        float4 xv[9];
#pragma unroll
        for (int r = 0; r < 3; ++r) {
            int ih = yy + r - 1;
#pragma unroll
            for (int c = 0; c < 3; ++c) {
                int iw = xx + c - 1;
                float4 v = {0.f, 0.f, 0.f, 0.f};
                if ((unsigned)ih < (unsigned)HI && (unsigned)iw < (unsigned)WI)
                    v = *(const float4*)(xn + ((long)ih * WI + iw) * CI + ci4 * 4);
                xv[r * 3 + c] = v;
            }
        }
        const float4* wp = Wd + ((long)ci4 * CO + co0) * 16;
#pragma unroll
        for (int j = 0; j < COT; ++j)
#pragma unroll
            for (int par = 0; par < 4; ++par) {
                int p = par >> 1, q = par & 1;
#pragma unroll
                for (int t4 = 0; t4 < 4; ++t4) {
                    int dh = t4 >> 1, dw = t4 & 1;
                    acc[j][par] += dot4(xv[(p + dh) * 3 + (q + dw)],
                                        wp[(j * 4 + par) * 4 + t4]);
                }
            }
    }
#pragma unroll
    for (int par = 0; par < 4; ++par) {
        int p = par >> 1, q = par & 1;
        float* yp = y + (((long)n * HO + 2 * yy + p) * WO + 2 * xx + q) * CO + co0;
#pragma unroll
        for (int j = 0; j < COT; ++j) yp[j] = fmaxf(acc[j][par], 0.f);
    }
}

// ============== dt4: CO=3, sigmoid, NCHW output, float2 stores ==============
__global__ __launch_bounds__(256)
void dt4_direct(const float* __restrict__ X, const float4* __restrict__ Wd,
                const float* __restrict__ bias, float* __restrict__ out) {
    int m = blockIdx.x * 256 + threadIdx.x;  // 262144
    int n = m >> 10, rem = m & 1023;
    int yy = rem >> 5, xx = rem & 31;
    float acc[3][4];
#pragma unroll
    for (int j = 0; j < 3; ++j) {
        float b = bias[j];
#pragma unroll
        for (int par = 0; par < 4; ++par) acc[j][par] = b;
    }
    const float* xn = X + (long)n * 1024 * 32;
    for (int ci4 = 0; ci4 < 8; ++ci4) {
        float4 xv[9];
#pragma unroll
        for (int r = 0; r < 3; ++r) {
            int ih = yy + r - 1;
#pragma unroll
            for (int c = 0; c < 3; ++c) {
                int iw = xx + c - 1;
                float4 v = {0.f, 0.f, 0.f, 0.f};
                if ((unsigned)ih < 32u && (unsigned)iw < 32u)
                    v = *(const float4*)(xn + ((long)ih * 32 + iw) * 32 + ci4 * 4);
                xv[r * 3 + c] = v;
            }
        }
        const float4* wp = Wd + ci4 * 48;
#pragma unroll
        for (int j = 0; j < 3; ++j)
#pragma unroll
            for (int par = 0; par < 4; ++par) {
                int p = par >> 1, q = par & 1;
#pragma unroll
                for (int t4 = 0; t4 < 4; ++t4) {
                    int dh = t4 >> 1, dw = t4 & 1;
                    acc[j][par] += dot4(xv[(p + dh) * 3 + (q + dw)],
                                        wp[(j * 4 + par) * 4 + t4]);
                }
            }
    }
#pragma unroll
    for (int j = 0; j < 3; ++j)
#pragma unroll
        for (int p = 0; p < 2; ++p) {
            float2 v;
            v.x = sig_(acc[j][p * 2 + 0]);
            v.y = sig_(acc[j][p * 2 + 1]);
            *(float2*)(out + (((long)n * 3 + j) * 64 + 2 * yy + p) * 64 + 2 * xx) = v;
        }
}

// ========================= weight / layout prep =============================
// conv OIHW -> float4[(ci4*CO+co)*16+tap], ci zero-padded CIS->CIP
template<int CIS, int CIP, int CO>
__global__ void perm_dirw(const float* __restrict__ w, float4* __restrict__ out) {
    int idx = blockIdx.x * 256 + threadIdx.x;
    if (idx >= (CIP / 4) * CO * 16) return;
    int tap = idx & 15; int co = (idx >> 4) % CO; int ci4 = (idx >> 4) / CO;
    float4 v; float* pv = (float*)&v;
#pragma unroll
    for (int l = 0; l < 4; ++l) {
        int ci = ci4 * 4 + l;
        pv[l] = (ci < CIS) ? w[((long)co * CIS + ci) * 16 + tap] : 0.f;
    }
    out[idx] = v;
}

// convT OIHW -> float4[((ci4*CO+co)*4+par)*4+t4] with tap=(p+2dh)*4+(q+2dw)
template<int CI, int CO>
__global__ void perm_dirwT(const float* __restrict__ w, float4* __restrict__ out) {
    int idx = blockIdx.x * 256 + threadIdx.x;
    if (idx >= (CI / 4) * CO * 16) return;
    int t4 = idx & 3; int par = (idx >> 2) & 3;
    int co = (idx >> 4) % CO; int ci4 = (idx >> 4) / CO;
    int p = par >> 1, q = par & 1, dh = t4 >> 1, dw = t4 & 1;
    int tap = (p + 2 * dh) * 4 + (q + 2 * dw);
    float4 v; float* pv = (float*)&v;
#pragma unroll
    for (int l = 0; l < 4; ++l)
        pv[l] = w[((long)co * CI + ci4 * 4 + l) * 16 + tap];
    out[idx] = v;
}

// video NCHW -> NHWC padded to 4 channels
__global__ void to_nhwc4(const float* __restrict__ v, float* __restrict__ out) {
    int idx = blockIdx.x * 256 + threadIdx.x;  // 4,194,304
    int c = idx & 3; int w = (idx >> 2) & 63; int h = (idx >> 8) & 63; int n = idx >> 14;
    out[idx] = (c < 3) ? v[(((long)n * 3 + c) * 64 + h) * 64 + w] : 0.f;
}

__global__ void transp(const float* __restrict__ in, float* __restrict__ out,
                       int R, int C) {
    long idx = (long)blockIdx.x * 256 + threadIdx.x;
    if (idx >= (long)R * C) return;
    int r = (int)(idx % R), c = (int)(idx / R);
    out[idx] = in[(long)r * C + c];
}

__global__ void perm_wih(const float* __restrict__ wih, float* __restrict__ out) {
    int idx = blockIdx.x * 256 + threadIdx.x;  // 262144
    int c = idx & 2047, m = idx >> 11;
    out[idx] = wih[orig_row(c) * 128 + m];
}

__global__ void pack_whh(const float* __restrict__ whh, float4* __restrict__ out) {
    int idx = blockIdx.x * 256 + threadIdx.x;  // 262144
    int c = idx & 2047, k4 = idx >> 11;
    const float4* src = (const float4*)(whh + orig_row(c) * 512);
    out[idx] = src[k4];
}

__global__ __launch_bounds__(256)
void merge_dc(const float* __restrict__ wih_d, const float* __restrict__ fc_w,
              const float* __restrict__ whh_d, float* __restrict__ out) {
    int cb = (blockIdx.x >> 3) * 64, kb = (blockIdx.x & 7) * 64;
    int tid = threadIdx.x;
    int cgl = (tid & 15) * 4, kgl = (tid >> 4) * 4;
    __shared__ float At[64][65];
    __shared__ float Bt[64][65];
    float acc[4][4] = {};
    for (int mc = 0; mc < 128; mc += 64) {
        __syncthreads();
        for (int i = tid; i < 4096; i += 256) {
            int cl = i >> 6, m = i & 63;
            At[cl][m] = wih_d[orig_row(cb + cl) * 128 + mc + m];
            Bt[cl][m] = fc_w[(mc + cl) * 512 + kb + m];
        }
        __syncthreads();
        for (int m = 0; m < 64; ++m) {
            float a[4], b[4];
#pragma unroll
            for (int i = 0; i < 4; ++i) { a[i] = At[cgl + i][m]; b[i] = Bt[m][kgl + i]; }
#pragma unroll
            for (int i = 0; i < 4; ++i)
#pragma unroll
                for (int j = 0; j < 4; ++j) acc[i][j] += a[i] * b[j];
        }
    }
    for (int i = 0; i < 4; ++i) {
        int c = cb + cgl + i; int orow = orig_row(c);
        for (int j = 0; j < 4; ++j) {
            int k = kb + kgl + j;
            out[((k >> 2) * 2048 + c) * 4 + (k & 3)] = acc[i][j] + whh_d[orow * 512 + k];
        }
    }
}

__global__ void biasdc_k(const float* __restrict__ bih, const float* __restrict__ bhh,
                         const float* __restrict__ wih_d, const float* __restrict__ fc_b,
                         float* __restrict__ out) {
    int c = blockIdx.x * 256 + threadIdx.x;
    if (c >= 2048) return;
    int orow = orig_row(c);
    float s = bih[orow] + bhh[orow];
    for (int m = 0; m < 128; ++m) s += fc_b[m] * wih_d[orow * 128 + m];
    out[c] = s;
}

// fcmu_w [128][4096 chw] -> FCMUP[k_hwc][j]
__global__ void perm_fcmu(const float* __restrict__ w, float* __restrict__ out) {
    int idx = blockIdx.x * 256 + threadIdx.x;  // 524288
    int j = idx & 127; int k = idx >> 7;
    out[idx] = w[(long)j * 4096 + (k & 255) * 16 + (k >> 8)];
}

// dfc_w [4096 chw][128] -> DFCP[m][j_hwc]; dfc_b -> DFCB[j_hwc]
__global__ void perm_dfc(const float* __restrict__ w, const float* __restrict__ b,
                         float* __restrict__ outw, float* __restrict__ outb) {
    int idx = blockIdx.x * 256 + threadIdx.x;  // 524288
    int j = idx & 4095; int m = idx >> 12;
    int jc = (j & 255) * 16 + (j >> 8);
    outw[idx] = w[(long)jc * 128 + m];
    if (idx < 4096) outb[idx] = b[(idx & 255) * 16 + (idx >> 8)];
}

// ============================ FC kernels =====================================
__global__ __launch_bounds__(512)
void fcmu_part(const float* __restrict__ x, const float* __restrict__ wP,
               float* __restrict__ part) {
    int rg = blockIdx.x >> 3, ks = blockIdx.x & 7;
    int tid = threadIdx.x;
    __shared__ float xl[16 * 512];
    for (int i = tid; i < 8192; i += 512)
        xl[i] = x[(long)(rg * 16 + (i >> 9)) * 4096 + ks * 512 + (i & 511)];
    __syncthreads();
    int j = tid & 127, rq = tid >> 7;
    float acc[4] = {0, 0, 0, 0};
    for (int k = 0; k < 512; ++k) {
        float wv = wP[(ks * 512 + k) * 128 + j];
#pragma unroll
        for (int i = 0; i < 4; ++i) acc[i] += xl[(rq + 4 * i) * 512 + k] * wv;
    }
    for (int i = 0; i < 4; ++i)
        part[((long)ks * 256 + rg * 16 + rq + 4 * i) * 128 + j] = acc[i];
}

__global__ void fcmu_red(const float* __restrict__ part, const float* __restrict__ b,
                         float* __restrict__ z) {
    int idx = blockIdx.x * 256 + threadIdx.x;  // 32768
    float s = b[idx & 127];
    for (int k = 0; k < 8; ++k) s += part[k * 32768 + idx];
    z[idx] = s;
}

__global__ __launch_bounds__(512)
void dfc_k(const float* __restrict__ zs, const float* __restrict__ dP,
           const float* __restrict__ db, float* __restrict__ out) {
    int rg = blockIdx.x >> 3, jc = blockIdx.x & 7;
    int tid = threadIdx.x;
    __shared__ float zl[16 * 128];
    for (int i = tid; i < 2048; i += 512) zl[i] = zs[(long)rg * 2048 + i];
    __syncthreads();
    int j = jc * 512 + tid;
    float acc[16];
#pragma unroll
    for (int r = 0; r < 16; ++r) acc[r] = 0.f;
    for (int m = 0; m < 128; ++m) {
        float wv = dP[(long)m * 4096 + j];
#pragma unroll
        for (int r = 0; r < 16; ++r) acc[r] += zl[r * 128 + m] * wv;
    }
    float bv = db[j];
    for (int r = 0; r < 16; ++r)
        out[(long)(rg * 16 + r) * 4096 + j] = fmaxf(acc[r] + bv, 0.f);
}

// ============== cooperative LSTM mega-kernel (64 blocks x 512) ==============
__global__ __launch_bounds__(512)
void lstm_chain(const float* __restrict__ Z,
                const float* __restrict__ wihPE, const float* __restrict__ bihE,
                const float* __restrict__ bhhE,
                const float* __restrict__ wihPD, const float* __restrict__ bihD,
                const float* __restrict__ bhhD,
                const float4* __restrict__ whE, const float4* __restrict__ whD0,
                const float4* __restrict__ whDC,
                const float* __restrict__ biasdc,
                const float* __restrict__ fcP, const float* __restrict__ fcb,
                float* __restrict__ gxe, float* __restrict__ gxd0,
                float* __restrict__ hA, float* __restrict__ hB,
                float* __restrict__ hall, float* __restrict__ zsOut) {
    cg::grid_group grid = cg::this_grid();
    __shared__ float hs[8192];
    __shared__ float gb[16][32];
    int bid = blockIdx.x, tid = threadIdx.x;

    // ---- phase 1: gx encoder (all blocks); gx dec0 (blocks 0-3); zero h0 ----
    {
        int rg = bid >> 2, cch = bid & 3;
        for (int i = tid; i < 2048; i += 512)
            hs[i] = Z[(long)(rg * 16 + (i >> 7)) * 128 + (i & 127)];
        __syncthreads();
        int c = cch * 512 + tid;
        int orow = orig_row(c);
        float bsum = bihE[orow] + bhhE[orow];
        float acc[16];
#pragma unroll
        for (int r = 0; r < 16; ++r) acc[r] = bsum;
        for (int m2 = 0; m2 < 128; ++m2) {
            float wv = wihPE[m2 * 2048 + c];
#pragma unroll
            for (int r = 0; r < 16; ++r) acc[r] += hs[r * 128 + m2] * wv;
        }
        for (int r = 0; r < 16; ++r) gxe[(long)(rg * 16 + r) * 2048 + c] = acc[r];
        if (tid < 128) hA[bid * 128 + tid] = 0.f;
        if (bid < 4) {
            __syncthreads();
            for (int i = tid; i < 2048; i += 512)
                hs[i] = Z[(long)((i >> 7) * 16 + 15) * 128 + (i & 127)];
            __syncthreads();
            int c2 = bid * 512 + tid;
            int orow2 = orig_row(c2);
            float bs2 = bihD[orow2] + bhhD[orow2];
            float acc2[16];
#pragma unroll
            for (int r = 0; r < 16; ++r) acc2[r] = bs2;
            for (int m2 = 0; m2 < 128; ++m2) {
                float wv = wihPD[m2 * 2048 + c2];
#pragma unroll
                for (int r = 0; r < 16; ++r) acc2[r] += hs[r * 128 + m2] * wv;
            }
            for (int r = 0; r < 16; ++r) gxd0[(long)r * 2048 + c2] = acc2[r];
        }
    }
    grid.sync();

    // ---- phase 2: 16 encoder + 16 decoder steps ----
    int col = tid & 31, nn = tid >> 5;
    int cgc = bid * 32 + col;
    float creg = 0.f;
    float* hin = hA; float* hout = hB;
    for (int t = 0; t < 32; ++t) {
        const float4* wh4 = (t < 16) ? whE : ((t == 16) ? whD0 : whDC);
        float acc;
        if (t < 16)       acc = gxe[(long)nn * 32768 + t * 2048 + cgc];
        else if (t == 16) acc = gxd0[nn * 2048 + cgc];
        else              acc = biasdc[cgc];
        const float4* wp = wh4 + cgc;
        const float4* hv = (const float4*)(hin + nn * 512);
#pragma unroll 8
        for (int k4 = 0; k4 < 128; ++k4)
            acc += dot4(wp[(long)k4 * 2048], hv[k4]);
        gb[nn][col] = acc;
        __syncthreads();
        if (col < 8) {
            float gi = sig_(gb[nn][col]);
            float gf = sig_(gb[nn][col + 8]);
            float gg = tanhf(gb[nn][col + 16]);
            float go = sig_(gb[nn][col + 24]);
            float cv = gf * creg + gi * gg; creg = cv;
            float hvv = go * tanhf(cv);
            int j = bid * 8 + col;
            hout[nn * 512 + j] = hvv;
            if (t >= 16) hall[(long)(t - 16) * 8192 + nn * 512 + j] = hvv;
        }
        grid.sync();
        float* tmp = hin; hin = hout; hout = tmp;
    }

    // ---- phase 3: zs (blocks 0-15) ----
    if (bid < 16) {
        int t = bid;
        const float* h = hall + (long)t * 8192;
        for (int i = tid; i < 8192; i += 512) hs[i] = h[i];
        __syncthreads();
        int j = tid & 127, ng = tid >> 7;
        float acc[4] = {0, 0, 0, 0};
        for (int k = 0; k < 512; ++k) {
            float wv = fcP[k * 128 + j];
#pragma unroll
            for (int i = 0; i < 4; ++i) acc[i] += hs[(ng + 4 * i) * 512 + k] * wv;
        }
        float bv = fcb[j];
        for (int i = 0; i < 4; ++i)
            zsOut[((ng + 4 * i) * 16 + t) * 128 + j] = acc[i] + bv;
    }
}

extern "C" void kernel_launch(void* const* d_in, const int* in_sizes, int n_in,
                              void* d_out, int out_size, void* d_ws, size_t ws_size,
                              hipStream_t stream) {
    (void)in_sizes; (void)n_in; (void)out_size; (void)ws_size;
    const float* video  = (const float*)d_in[0];
    const float* ec1_w  = (const float*)d_in[2];  const float* ec1_b = (const float*)d_in[3];
    const float* ec2_w  = (const float*)d_in[4];  const float* ec2_b = (const float*)d_in[5];
    const float* ec3_w  = (const float*)d_in[6];  const float* ec3_b = (const float*)d_in[7];
    const float* ec4_w  = (const float*)d_in[8];  const float* ec4_b = (const float*)d_in[9];
    const float* fcmu_w = (const float*)d_in[10]; const float* fcmu_b = (const float*)d_in[11];
    const float* dfc_w  = (const float*)d_in[12]; const float* dfc_b = (const float*)d_in[13];
    const float* dt1_w  = (const float*)d_in[14]; const float* dt1_b = (const float*)d_in[15];
    const float* dt2_w  = (const float*)d_in[16]; const float* dt2_b = (const float*)d_in[17];
    const float* dt3_w  = (const float*)d_in[18]; const float* dt3_b = (const float*)d_in[19];
    const float* dt4_w  = (const float*)d_in[20]; const float* dt4_b = (const float*)d_in[21];
    const float* wih_e  = (const float*)d_in[22]; const float* whh_e = (const float*)d_in[23];
    const float* bih_e  = (const float*)d_in[24]; const float* bhh_e = (const float*)d_in[25];
    const float* wih_d  = (const float*)d_in[26]; const float* whh_d = (const float*)d_in[27];
    const float* bih_d  = (const float*)d_in[28]; const float* bhh_d = (const float*)d_in[29];
    const float* fc_w   = (const float*)d_in[30]; const float* fc_b  = (const float*)d_in[31];

    float* ws = (float*)d_ws;
    float* A1 = ws;                 // 8,388,608 floats
    float* A2 = ws + 8388608;       // 4,194,304
    float* A3 = ws + 12582912;      // 2,097,152
    float* A4 = ws + 14680064;      // 1,048,576
    // tables living in A1 (valid after ec2 completes, dead before dt3 output)
    float* WT3d   = A1;             // 131072
    float* WT4d   = A1 + 131072;    // 524288
    float* WTd1   = A1 + 655360;    // 524288
    float* WTd2   = A1 + 1179648;   // 131072
    float* WH4_E  = A1 + 1310720;   // 1048576
    float* WH4_D0 = A1 + 2359296;   // 1048576
    float* WH4_DC = A1 + 3407872;   // 1048576
    float* WIHP_E = A1 + 4456448;   // 262144
    float* WIHP_D = A1 + 4718592;   // 262144
    float* GX_E   = A1 + 4980736;   // 524288
    float* GX_D0  = A1 + 5505024;   // 32768
    float* BIASDC = A1 + 5537792;   // 2048
    float* HA     = A1 + 5539840;   // 8192
    float* HB     = A1 + 5548032;   // 8192
    float* HALL   = A1 + 5556224;   // 131072
    float* FCMUP  = A1 + 5687296;   // 524288
    float* ZPART  = A1 + 6211584;   // 262144
    float* FCP    = A1 + 6473728;   // 65536
    float* DFCP   = A1 + 6539264;   // 524288
    float* DFCB   = A1 + 7063552;   // 4096
    float* Z      = A1 + 7067648;   // 32768
    float* ZS     = A1 + 7100416;   // 32768
    // persistent tail
    float* WT1d = ws + 15728640;    // 2048
    float* WT2d = ws + 15730688;    // 32768
    float* WTd3 = ws + 15763456;    // 32768
    float* WTd4 = ws + 15796224;    // 1536
    float* X0   = A2;

    // ---- tables needed before A1 frees (tail) ----
    perm_dirw<3, 4, 32><<<2, 256, 0, stream>>>(ec1_w, (float4*)WT1d);
    perm_dirw<32, 32, 64><<<32, 256, 0, stream>>>(ec2_w, (float4*)WT2d);
    perm_dirwT<64, 32><<<32, 256, 0, stream>>>(dt3_w, (float4*)WTd3);
    perm_dirwT<32, 3><<<2, 256, 0, stream>>>(dt4_w, (float4*)WTd4);

    // ---- encoder conv1/conv2 ----
    to_nhwc4<<<16384, 256, 0, stream>>>(video, X0);
    conv_dir<4, 64, 64, 32, 32><<<1024, 256, 0, stream>>>(X0, (const float4*)WT1d, ec1_b, A1);
    conv_dir<32, 32, 32, 64, 32><<<512, 256, 0, stream>>>(A1, (const float4*)WT2d, ec2_b, A2);

    // ---- A1 free: remaining prep ----
    perm_dirw<64, 64, 128><<<128, 256, 0, stream>>>(ec3_w, (float4*)WT3d);
    perm_dirw<128, 128, 256><<<512, 256, 0, stream>>>(ec4_w, (float4*)WT4d);
    perm_dirwT<256, 128><<<512, 256, 0, stream>>>(dt1_w, (float4*)WTd1);
    perm_dirwT<128, 64><<<128, 256, 0, stream>>>(dt2_w, (float4*)WTd2);
    perm_fcmu<<<2048, 256, 0, stream>>>(fcmu_w, FCMUP);
    perm_dfc<<<2048, 256, 0, stream>>>(dfc_w, dfc_b, DFCP, DFCB);
    transp<<<256, 256, 0, stream>>>(fc_w, FCP, 128, 512);
    perm_wih<<<1024, 256, 0, stream>>>(wih_e, WIHP_E);
    perm_wih<<<1024, 256, 0, stream>>>(wih_d, WIHP_D);
    pack_whh<<<1024, 256, 0, stream>>>(whh_e, (float4*)WH4_E);
    pack_whh<<<1024, 256, 0, stream>>>(whh_d, (float4*)WH4_D0);
    merge_dc<<<256, 256, 0, stream>>>(wih_d, fc_w, whh_d, WH4_DC);
    biasdc_k<<<8, 256, 0, stream>>>(bih_d, bhh_d, wih_d, fc_b, BIASDC);

    // ---- encoder conv3/conv4 + fcmu ----
    conv_dir<64, 16, 16, 128, 16><<<512, 256, 0, stream>>>(A2, (const float4*)WT3d, ec3_b, A3);
    conv_dir<128, 8, 8, 256, 8><<<512, 256, 0, stream>>>(A3, (const float4*)WT4d, ec4_b, A4);
    fcmu_part<<<128, 512, 0, stream>>>(A4, FCMUP, ZPART);
    fcmu_red<<<128, 256, 0, stream>>>(ZPART, fcmu_b, Z);

    // ---- cooperative LSTM chain (gx + 32 steps + zs) ----
    {
        const float* Zp = Z;
        const float* wihPE = WIHP_E; const float* wihPD = WIHP_D;
        const float4* whE = (const float4*)WH4_E;
        const float4* whD0 = (const float4*)WH4_D0;
        const float4* whDC = (const float4*)WH4_DC;
        const float* biasdc = BIASDC; const float* fcP = FCP;
        float* gxe = GX_E; float* gxd0 = GX_D0;
        float* hA = HA; float* hB = HB; float* hall = HALL; float* zsOut = ZS;
        void* cargs[] = {
            (void*)&Zp, (void*)&wihPE, (void*)&bih_e, (void*)&bhh_e,
            (void*)&wihPD, (void*)&bih_d, (void*)&bhh_d,
            (void*)&whE, (void*)&whD0, (void*)&whDC,
            (void*)&biasdc, (void*)&fcP, (void*)&fc_b,
            (void*)&gxe, (void*)&gxd0, (void*)&hA, (void*)&hB,
            (void*)&hall, (void*)&zsOut };
        hipLaunchCooperativeKernel((void*)lstm_chain, dim3(64), dim3(512),
                                   cargs, 0, stream);
    }

    // ---- decoder ----
    dfc_k<<<128, 512, 0, stream>>>(ZS, DFCP, DFCB, A4);
    convt_dir<256, 4, 4, 128, 4><<<512, 256, 0, stream>>>(A4, (const float4*)WTd1, dt1_b, A3);
    convt_dir<128, 8, 8, 64, 8><<<512, 256, 0, stream>>>(A3, (const float4*)WTd2, dt2_b, A2);
    convt_dir<64, 16, 16, 32, 8><<<1024, 256, 0, stream>>>(A2, (const float4*)WTd3, dt3_b, A1);
    dt4_direct<<<1024, 256, 0, stream>>>(A1, (const float4*)WTd4, dt4_b, (float*)d_out);
}

// Round 6
// 1214.537 us; speedup vs baseline: 2.0626x; 2.0626x over previous
//
#include <hip/hip_runtime.h>
#include <math.h>

// ---------------------------------------------------------------------------
// CNN-LSTM video predictor, fp32, round 6: round-4 implicit-GEMM convs
// (KC=32), specialized dt4_direct, per-step LSTM chain (no cooperative sync).
// ---------------------------------------------------------------------------

__device__ __forceinline__ float sig_(float x) { return 1.f / (1.f + expf(-x)); }
__device__ __forceinline__ float dot4(float4 a, float4 b) {
    return a.x * b.x + a.y * b.y + a.z * b.z + a.w * b.w;
}
__device__ __forceinline__ int orig_row(int c) {
    return ((c >> 3) & 3) * 512 + (c >> 5) * 8 + (c & 7);
}

// =============== encoder conv as implicit GEMM (s2, k4, p1, relu) ==========
template<int CI, int HI, int WI, int CO, int BM, int BN, int TM, int TN, int KC>
__global__ __launch_bounds__(256)
void conv_gemm(const float* __restrict__ X, const float* __restrict__ Wt,
               const float* __restrict__ bias, float* __restrict__ y) {
    constexpr int HO = HI / 2, WO = WI / 2;
    constexpr int HWO = HO * WO;
    constexpr int MTOT = 256 * HWO;
    constexpr int MT = MTOT / BM;
    constexpr int MG = BM / TM, NG = BN / TN;
    static_assert(MG * NG == 256, "bad tile");
    __shared__ float Xs[KC][BM + 4];
    __shared__ float Ws[KC][BN + 4];
    int bid = blockIdx.x;
    int mt = bid % MT, nt = bid / MT;
    int m0 = mt * BM, n0 = nt * BN;
    int tid = threadIdx.x;
    int tmg = tid % MG, tng = tid / MG;
    float acc[TM][TN] = {};

    for (int tap = 0; tap < 16; ++tap) {
        int kh = tap >> 2, kw = tap & 3;
        for (int cc = 0; cc < CI; cc += KC) {
            __syncthreads();
            for (int item = tid; item < BM * (KC / 4); item += 256) {
                int row = item / (KC / 4), kq = item % (KC / 4);
                int m = m0 + row;
                int n_ = m / HWO, rem = m % HWO;
                int oh = rem / WO, ow = rem % WO;
                int ih = 2 * oh + kh - 1, iw = 2 * ow + kw - 1;
                float4 v = {0.f, 0.f, 0.f, 0.f};
                if (ih >= 0 && ih < HI && iw >= 0 && iw < WI)
                    v = *(const float4*)(X + (((long)n_ * HI + ih) * WI + iw) * CI + cc + kq * 4);
                Xs[kq * 4 + 0][row] = v.x; Xs[kq * 4 + 1][row] = v.y;
                Xs[kq * 4 + 2][row] = v.z; Xs[kq * 4 + 3][row] = v.w;
            }
            for (int item = tid; item < KC * (BN / 4); item += 256) {
                int kr = item / (BN / 4), jq = item % (BN / 4);
                *(float4*)&Ws[kr][jq * 4] =
                    *(const float4*)(Wt + ((long)tap * CI + cc + kr) * CO + n0 + jq * 4);
            }
            __syncthreads();
#pragma unroll
            for (int k = 0; k < KC; ++k) {
                float a[TM], b[TN];
#pragma unroll
                for (int i = 0; i < TM; ++i) a[i] = Xs[k][tmg * TM + i];
#pragma unroll
                for (int j = 0; j < TN; ++j) b[j] = Ws[k][tng * TN + j];
#pragma unroll
                for (int i = 0; i < TM; ++i)
#pragma unroll
                    for (int j = 0; j < TN; ++j) acc[i][j] += a[i] * b[j];
            }
        }
    }
#pragma unroll
    for (int i = 0; i < TM; ++i) {
        long m = m0 + tmg * TM + i;
#pragma unroll
        for (int j = 0; j < TN; ++j) {
            int co = n0 + tng * TN + j;
            y[m * CO + co] = fmaxf(acc[i][j] + bias[co], 0.f);
        }
    }
}

// =============== transposed conv as parity implicit GEMM ====================
template<int CI, int HI, int WI, int CO, int COR, int BM, int BN, int TM, int TN,
         int KC, int ACT, int NCHW>
__global__ __launch_bounds__(256)
void convt_gemm(const float* __restrict__ X, const float* __restrict__ Wt,
                const float* __restrict__ bias, float* __restrict__ y) {
    constexpr int HO = HI * 2, WO = WI * 2;
    constexpr int HWI = HI * WI;
    constexpr int MTOT = 256 * HWI;
    constexpr int MT = MTOT / BM;
    constexpr int NT = CO / BN;
    constexpr int MG = BM / TM, NG = BN / TN;
    static_assert(MG * NG == 256, "bad tile");
    __shared__ float Xs[KC][BM + 4];
    __shared__ float Ws[KC][BN + 4];
    int bid = blockIdx.x;
    int mt = bid % MT; bid /= MT;
    int nt = bid % NT; int par = bid / NT;
    int p = par >> 1, q = par & 1;
    int m0 = mt * BM, n0 = nt * BN;
    int tid = threadIdx.x;
    int tmg = tid % MG, tng = tid / MG;
    float acc[TM][TN] = {};

    for (int t4 = 0; t4 < 4; ++t4) {
        int dh = t4 >> 1, dw = t4 & 1;
        int tap = (p + 2 * dh) * 4 + (q + 2 * dw);
        for (int cc = 0; cc < CI; cc += KC) {
            __syncthreads();
            for (int item = tid; item < BM * (KC / 4); item += 256) {
                int row = item / (KC / 4), kq = item % (KC / 4);
                int m = m0 + row;
                int n_ = m / HWI, rem = m % HWI;
                int yy = rem / WI, xx = rem % WI;
                int ih = yy + p + dh - 1, iw = xx + q + dw - 1;
                float4 v = {0.f, 0.f, 0.f, 0.f};
                if (ih >= 0 && ih < HI && iw >= 0 && iw < WI)
                    v = *(const float4*)(X + (((long)n_ * HI + ih) * WI + iw) * CI + cc + kq * 4);
                Xs[kq * 4 + 0][row] = v.x; Xs[kq * 4 + 1][row] = v.y;
                Xs[kq * 4 + 2][row] = v.z; Xs[kq * 4 + 3][row] = v.w;
            }
            for (int item = tid; item < KC * (BN / 4); item += 256) {
                int kr = item / (BN / 4), jq = item % (BN / 4);
                *(float4*)&Ws[kr][jq * 4] =
                    *(const float4*)(Wt + ((long)tap * CI + cc + kr) * CO + n0 + jq * 4);
            }
            __syncthreads();
#pragma unroll
            for (int k = 0; k < KC; ++k) {
                float a[TM], b[TN];
#pragma unroll
                for (int i = 0; i < TM; ++i) a[i] = Xs[k][tmg * TM + i];
#pragma unroll
                for (int j = 0; j < TN; ++j) b[j] = Ws[k][tng * TN + j];
#pragma unroll
                for (int i = 0; i < TM; ++i)
#pragma unroll
                    for (int j = 0; j < TN; ++j) acc[i][j] += a[i] * b[j];
            }
        }
    }
#pragma unroll
    for (int i = 0; i < TM; ++i) {
        int m = m0 + tmg * TM + i;
        int n_ = m / HWI, rem = m % HWI;
        int oh = 2 * (rem / WI) + p, ow = 2 * (rem % WI) + q;
#pragma unroll
        for (int j = 0; j < TN; ++j) {
            int co = n0 + tng * TN + j;
            float v = acc[i][j] + bias[co];
            v = (ACT == 1) ? sig_(v) : fmaxf(v, 0.f);
            if (NCHW) {
                if (co < COR)
                    y[(((long)n_ * COR + co) * HO + oh) * WO + ow] = v;
            } else {
                y[(((long)n_ * HO + oh) * WO + ow) * CO + co] = v;
            }
        }
    }
}

// ============== dt4: CO=3, sigmoid, NCHW output, float2 stores ==============
__global__ __launch_bounds__(256)
void dt4_direct(const float* __restrict__ X, const float4* __restrict__ Wd,
                const float* __restrict__ bias, float* __restrict__ out) {
    int m = blockIdx.x * 256 + threadIdx.x;  // 262144
    int n = m >> 10, rem = m & 1023;
    int yy = rem >> 5, xx = rem & 31;
    float acc[3][4];
#pragma unroll
    for (int j = 0; j < 3; ++j) {
        float b = bias[j];
#pragma unroll
        for (int par = 0; par < 4; ++par) acc[j][par] = b;
    }
    const float* xn = X + (long)n * 1024 * 32;
    for (int ci4 = 0; ci4 < 8; ++ci4) {
        float4 xv[9];
#pragma unroll
        for (int r = 0; r < 3; ++r) {
            int ih = yy + r - 1;
#pragma unroll
            for (int c = 0; c < 3; ++c) {
                int iw = xx + c - 1;
                float4 v = {0.f, 0.f, 0.f, 0.f};
                if ((unsigned)ih < 32u && (unsigned)iw < 32u)
                    v = *(const float4*)(xn + ((long)ih * 32 + iw) * 32 + ci4 * 4);
                xv[r * 3 + c] = v;
            }
        }
        const float4* wp = Wd + ci4 * 48;
#pragma unroll
        for (int j = 0; j < 3; ++j)
#pragma unroll
            for (int par = 0; par < 4; ++par) {
                int p = par >> 1, q = par & 1;
#pragma unroll
                for (int t4 = 0; t4 < 4; ++t4) {
                    int dh = t4 >> 1, dw = t4 & 1;
                    acc[j][par] += dot4(xv[(p + dh) * 3 + (q + dw)],
                                        wp[(j * 4 + par) * 4 + t4]);
                }
            }
    }
#pragma unroll
    for (int j = 0; j < 3; ++j)
#pragma unroll
        for (int p = 0; p < 2; ++p) {
            float2 v;
            v.x = sig_(acc[j][p * 2 + 0]);
            v.y = sig_(acc[j][p * 2 + 1]);
            *(float2*)(out + (((long)n * 3 + j) * 64 + 2 * yy + p) * 64 + 2 * xx) = v;
        }
}

// ========================= layout / weight prep =============================
template<int CI_S, int CI_P, int CO_S, int CO_P>
__global__ void perm_w(const float* __restrict__ w, float* __restrict__ out) {
    int idx = blockIdx.x * 256 + threadIdx.x;
    constexpr int TOT = 16 * CI_P * CO_P;
    if (idx >= TOT) return;
    int co = idx % CO_P; int ci = (idx / CO_P) % CI_P; int t = idx / (CO_P * CI_P);
    out[idx] = (ci < CI_S && co < CO_S) ? w[((long)co * CI_S + ci) * 16 + t] : 0.f;
}

// convT OIHW -> float4[((ci4*CO+co)*4+par)*4+t4] with tap=(p+2dh)*4+(q+2dw)
template<int CI, int CO>
__global__ void perm_dirwT(const float* __restrict__ w, float4* __restrict__ out) {
    int idx = blockIdx.x * 256 + threadIdx.x;
    if (idx >= (CI / 4) * CO * 16) return;
    int t4 = idx & 3; int par = (idx >> 2) & 3;
    int co = (idx >> 4) % CO; int ci4 = (idx >> 4) / CO;
    int p = par >> 1, q = par & 1, dh = t4 >> 1, dw = t4 & 1;
    int tap = (p + 2 * dh) * 4 + (q + 2 * dw);
    float4 v; float* pv = (float*)&v;
#pragma unroll
    for (int l = 0; l < 4; ++l)
        pv[l] = w[((long)co * CI + ci4 * 4 + l) * 16 + tap];
    out[idx] = v;
}

__global__ void to_nhwc4(const float* __restrict__ v, float* __restrict__ out) {
    int idx = blockIdx.x * 256 + threadIdx.x;  // 4,194,304
    int c = idx & 3; int w = (idx >> 2) & 63; int h = (idx >> 8) & 63; int n = idx >> 14;
    out[idx] = (c < 3) ? v[(((long)n * 3 + c) * 64 + h) * 64 + w] : 0.f;
}

__global__ void perm_fcmu(const float* __restrict__ w, float* __restrict__ out) {
    int idx = blockIdx.x * 256 + threadIdx.x;  // 524288
    int j = idx & 127; int k = idx >> 7;
    out[idx] = w[(long)j * 4096 + (k & 255) * 16 + (k >> 8)];
}

__global__ void perm_dfc(const float* __restrict__ w, const float* __restrict__ b,
                         float* __restrict__ outw, float* __restrict__ outb) {
    int idx = blockIdx.x * 256 + threadIdx.x;  // 524288
    int j = idx & 4095; int m = idx >> 12;
    int jc = (j & 255) * 16 + (j >> 8);
    outw[idx] = w[(long)jc * 128 + m];
    if (idx < 4096) outb[idx] = b[(idx & 255) * 16 + (idx >> 8)];
}

__global__ void transp(const float* __restrict__ in, float* __restrict__ out,
                       int R, int C) {
    long idx = (long)blockIdx.x * 256 + threadIdx.x;
    if (idx >= (long)R * C) return;
    int r = (int)(idx % R), c = (int)(idx / R);
    out[idx] = in[(long)r * C + c];
}

__global__ void perm_wih(const float* __restrict__ wih, float* __restrict__ out) {
    int idx = blockIdx.x * 256 + threadIdx.x;  // < 262144
    int c = idx & 2047, m = idx >> 11;
    out[idx] = wih[orig_row(c) * 128 + m];
}

__global__ void pack_whh(const float* __restrict__ whh, float4* __restrict__ out) {
    int idx = blockIdx.x * 256 + threadIdx.x;  // < 262144
    int c = idx & 2047, k4 = idx >> 11;
    const float4* src = (const float4*)(whh + orig_row(c) * 512);
    out[idx] = src[k4];
}

__global__ __launch_bounds__(256)
void merge_dc(const float* __restrict__ wih_d, const float* __restrict__ fc_w,
              const float* __restrict__ whh_d, float* __restrict__ out) {
    int cb = (blockIdx.x >> 3) * 64, kb = (blockIdx.x & 7) * 64;
    int tid = threadIdx.x;
    int cgl = (tid & 15) * 4, kgl = (tid >> 4) * 4;
    __shared__ float At[64][65];
    __shared__ float Bt[64][65];
    float acc[4][4] = {};
    for (int mc = 0; mc < 128; mc += 64) {
        __syncthreads();
        for (int i = tid; i < 4096; i += 256) {
            int cl = i >> 6, m = i & 63;
            At[cl][m] = wih_d[orig_row(cb + cl) * 128 + mc + m];
            Bt[cl][m] = fc_w[(mc + cl) * 512 + kb + m];
        }
        __syncthreads();
        for (int m = 0; m < 64; ++m) {
            float a[4], b[4];
#pragma unroll
            for (int i = 0; i < 4; ++i) { a[i] = At[cgl + i][m]; b[i] = Bt[m][kgl + i]; }
#pragma unroll
            for (int i = 0; i < 4; ++i)
#pragma unroll
                for (int j = 0; j < 4; ++j) acc[i][j] += a[i] * b[j];
        }
    }
    for (int i = 0; i < 4; ++i) {
        int c = cb + cgl + i; int orow = orig_row(c);
        for (int j = 0; j < 4; ++j) {
            int k = kb + kgl + j;
            out[((k >> 2) * 2048 + c) * 4 + (k & 3)] = acc[i][j] + whh_d[orow * 512 + k];
        }
    }
}

__global__ void biasdc_k(const float* __restrict__ bih, const float* __restrict__ bhh,
                         const float* __restrict__ wih_d, const float* __restrict__ fc_b,
                         float* __restrict__ out) {
    int c = blockIdx.x * 256 + threadIdx.x;
    if (c >= 2048) return;
    int orow = orig_row(c);
    float s = bih[orow] + bhh[orow];
    for (int m = 0; m < 128; ++m) s += fc_b[m] * wih_d[orow * 128 + m];
    out[c] = s;
}

// ============================ LSTM path =====================================
__global__ __launch_bounds__(512)
void gx_kernel(const float* __restrict__ z, int zrstride,
               const float* __restrict__ wihP, const float* __restrict__ bih,
               const float* __restrict__ bhh, float* __restrict__ out) {
    int rg = blockIdx.x >> 2, cch = blockIdx.x & 3;
    int tid = threadIdx.x;
    __shared__ float zl[16 * 128];
    for (int i = tid; i < 2048; i += 512)
        zl[i] = z[(long)(rg * 16 + (i >> 7)) * zrstride + (i & 127)];
    __syncthreads();
    int c = cch * 512 + tid;
    int orow = orig_row(c);
    float bsum = bih[orow] + bhh[orow];
    float acc[16];
#pragma unroll
    for (int r = 0; r < 16; ++r) acc[r] = bsum;
    for (int m = 0; m < 128; ++m) {
        float wv = wihP[m * 2048 + c];
#pragma unroll
        for (int r = 0; r < 16; ++r) acc[r] += zl[r * 128 + m] * wv;
    }
    for (int r = 0; r < 16; ++r) out[(long)(rg * 16 + r) * 2048 + c] = acc[r];
}

__global__ __launch_bounds__(512)
void lstm_step(const float4* __restrict__ wh4, const float* __restrict__ gadd,
               int gstride, const float* __restrict__ h_in, float* __restrict__ h_out,
               float* __restrict__ cst, float* __restrict__ hall) {
    __shared__ float hs[8192];
    __shared__ float gb[16][32];
    int tid = threadIdx.x;
    float4* hs4 = (float4*)hs;
    const float4* hi4 = (const float4*)h_in;
#pragma unroll
    for (int i = 0; i < 4; ++i) hs4[tid + 512 * i] = hi4[tid + 512 * i];
    __syncthreads();
    int col = tid & 31, n = tid >> 5;
    int cg = blockIdx.x * 32 + col;
    float acc = gadd[n * gstride + cg];
    const float4* wp = wh4 + cg;
    const float4* hv = (const float4*)(hs + n * 512);
#pragma unroll 8
    for (int k4 = 0; k4 < 128; ++k4) {
        float4 wv = wp[(long)k4 * 2048];
        float4 h4 = hv[k4];
        acc += wv.x * h4.x + wv.y * h4.y + wv.z * h4.z + wv.w * h4.w;
    }
    gb[n][col] = acc;
    __syncthreads();
    if (col < 8) {
        int j = blockIdx.x * 8 + col;
        float gi = sig_(gb[n][col]);
        float gf = sig_(gb[n][col + 8]);
        float gg = tanhf(gb[n][col + 16]);
        float go = sig_(gb[n][col + 24]);
        int idx = n * 512 + j;
        float cv = gf * cst[idx] + gi * gg;
        cst[idx] = cv;
        float hvv = go * tanhf(cv);
        h_out[idx] = hvv;
        if (hall) hall[idx] = hvv;
    }
}

__global__ __launch_bounds__(512)
void fcmu_part(const float* __restrict__ x, const float* __restrict__ wP,
               float* __restrict__ part) {
    int rg = blockIdx.x >> 3, ks = blockIdx.x & 7;
    int tid = threadIdx.x;
    __shared__ float xl[16 * 512];
    for (int i = tid; i < 8192; i += 512)
        xl[i] = x[(long)(rg * 16 + (i >> 9)) * 4096 + ks * 512 + (i & 511)];
    __syncthreads();
    int j = tid & 127, rq = tid >> 7;
    float acc[4] = {0, 0, 0, 0};
    for (int k = 0; k < 512; ++k) {
        float wv = wP[(ks * 512 + k) * 128 + j];
#pragma unroll
        for (int i = 0; i < 4; ++i) acc[i] += xl[(rq + 4 * i) * 512 + k] * wv;
    }
    for (int i = 0; i < 4; ++i)
        part[((long)ks * 256 + rg * 16 + rq + 4 * i) * 128 + j] = acc[i];
}

__global__ void fcmu_red(const float* __restrict__ part, const float* __restrict__ b,
                         float* __restrict__ z) {
    int idx = blockIdx.x * 256 + threadIdx.x;  // 32768
    float s = b[idx & 127];
    for (int k = 0; k < 8; ++k) s += part[k * 32768 + idx];
    z[idx] = s;
}

__global__ __launch_bounds__(512)
void zs_k(const float* __restrict__ hall, const float* __restrict__ fcP,
          const float* __restrict__ fcb, float* __restrict__ zs) {
    int t = blockIdx.x;
    int tid = threadIdx.x;
    __shared__ float hs[8192];
    const float* h = hall + t * 8192;
    for (int i = tid; i < 8192; i += 512) hs[i] = h[i];
    __syncthreads();
    int j = tid & 127, ng = tid >> 7;
    float acc[4] = {0, 0, 0, 0};
    for (int k = 0; k < 512; ++k) {
        float wv = fcP[k * 128 + j];
#pragma unroll
        for (int i = 0; i < 4; ++i) acc[i] += hs[(ng + 4 * i) * 512 + k] * wv;
    }
    float bv = fcb[j];
    for (int i = 0; i < 4; ++i)
        zs[((ng + 4 * i) * 16 + t) * 128 + j] = acc[i] + bv;
}

__global__ __launch_bounds__(512)
void dfc_k(const float* __restrict__ zs, const float* __restrict__ dP,
           const float* __restrict__ db, float* __restrict__ out) {
    int rg = blockIdx.x >> 3, jc = blockIdx.x & 7;
    int tid = threadIdx.x;
    __shared__ float zl[16 * 128];
    for (int i = tid; i < 2048; i += 512) zl[i] = zs[(long)rg * 2048 + i];
    __syncthreads();
    int j = jc * 512 + tid;
    float acc[16];
#pragma unroll
    for (int r = 0; r < 16; ++r) acc[r] = 0.f;
    for (int m = 0; m < 128; ++m) {
        float wv = dP[(long)m * 4096 + j];
#pragma unroll
        for (int r = 0; r < 16; ++r) acc[r] += zl[r * 128 + m] * wv;
    }
    float bv = db[j];
    for (int r = 0; r < 16; ++r)
        out[(long)(rg * 16 + r) * 4096 + j] = fmaxf(acc[r] + bv, 0.f);
}

extern "C" void kernel_launch(void* const* d_in, const int* in_sizes, int n_in,
                              void* d_out, int out_size, void* d_ws, size_t ws_size,
                              hipStream_t stream) {
    (void)in_sizes; (void)n_in; (void)out_size; (void)ws_size;
    const float* video  = (const float*)d_in[0];
    const float* ec1_w  = (const float*)d_in[2];  const float* ec1_b = (const float*)d_in[3];
    const float* ec2_w  = (const float*)d_in[4];  const float* ec2_b = (const float*)d_in[5];
    const float* ec3_w  = (const float*)d_in[6];  const float* ec3_b = (const float*)d_in[7];
    const float* ec4_w  = (const float*)d_in[8];  const float* ec4_b = (const float*)d_in[9];
    const float* fcmu_w = (const float*)d_in[10]; const float* fcmu_b = (const float*)d_in[11];
    const float* dfc_w  = (const float*)d_in[12]; const float* dfc_b = (const float*)d_in[13];
    const float* dt1_w  = (const float*)d_in[14]; const float* dt1_b = (const float*)d_in[15];
    const float* dt2_w  = (const float*)d_in[16]; const float* dt2_b = (const float*)d_in[17];
    const float* dt3_w  = (const float*)d_in[18]; const float* dt3_b = (const float*)d_in[19];
    const float* dt4_w  = (const float*)d_in[20]; const float* dt4_b = (const float*)d_in[21];
    const float* wih_e  = (const float*)d_in[22]; const float* whh_e = (const float*)d_in[23];
    const float* bih_e  = (const float*)d_in[24]; const float* bhh_e = (const float*)d_in[25];
    const float* wih_d  = (const float*)d_in[26]; const float* whh_d = (const float*)d_in[27];
    const float* bih_d  = (const float*)d_in[28]; const float* bhh_d = (const float*)d_in[29];
    const float* fc_w   = (const float*)d_in[30]; const float* fc_b  = (const float*)d_in[31];

    float* ws = (float*)d_ws;
    float* A1 = ws;               // 8,388,608  ec1out -> [LSTM packs] -> dt3out
    float* A2 = ws + 8388608;     // 4,194,304  X0 -> ec2out -> WT4 -> dt2out
    float* A3 = ws + 12582912;    // 2,097,152  ec3out -> dt1out
    float* A4 = ws + 14680064;    // 1,048,576  ec4out -> dfcout
    // A1-region packs (valid after ec2 completes)
    float* WH4_E  = A1;                 // 1,048,576 (reused for whh_d pack later)
    float* WH4_DC = A1 + 1048576;       // 1,048,576
    float* WIHP_E = A1 + 2097152;       // 262,144
    float* WIHP_D = A1 + 2359296;       // 262,144
    float* GX_E   = A1 + 2621440;       // 524,288
    float* GX_D0  = A1 + 3145728;       // 32,768
    float* BIASDC = A1 + 3178496;       // 2,048
    float* HA     = A1 + 3180544;       // 8,192
    float* HB     = A1 + 3188736;       // 8,192
    float* CB     = A1 + 3196928;       // 8,192
    float* HALL   = A1 + 3205120;       // 131,072
    float* FCMUP  = A1 + 3336192;       // 524,288
    float* ZPART  = A1 + 3860480;       // 262,144
    float* FCP    = A1 + 4122624;       // 65,536
    float* DFCP   = A1 + 4188160;       // 524,288
    float* DFCB   = A1 + 4712448;       // 4,096
    float* Z      = A1 + 4716544;       // 32,768
    float* ZS     = A1 + 4749312;       // 32,768
    float* WT3    = A1 + 4782080;       // 131,072
    float* WTd1   = A1 + 4913152;       // 524,288
    float* WTd2   = A1 + 5437440;       // 131,072
    float* WT4    = A2;                 // 524,288 (prepped after ec3, dead before dt2)
    // persistent tail
    float* WT1    = ws + 15728640;      // 2,048
    float* WT2    = ws + 15730688;      // 32,768
    float* WTd3   = ws + 15763456;      // 32,768
    float* WTd4   = ws + 15796224;      // 1,536 (dirwT format for dt4_direct)
    float* X0     = A2;

    // ---- weight tables needed before A1 frees (tail) ----
    perm_w<3, 4, 32, 32><<<8, 256, 0, stream>>>(ec1_w, WT1);
    perm_w<32, 32, 64, 64><<<128, 256, 0, stream>>>(ec2_w, WT2);
    perm_w<64, 64, 32, 32><<<128, 256, 0, stream>>>(dt3_w, WTd3);
    perm_dirwT<32, 3><<<2, 256, 0, stream>>>(dt4_w, (float4*)WTd4);

    // ---- encoder ----
    to_nhwc4<<<16384, 256, 0, stream>>>(video, X0);
    conv_gemm<4, 64, 64, 32, 128, 32, 4, 4, 4><<<2048, 256, 0, stream>>>(X0, WT1, ec1_b, A1);
    conv_gemm<32, 32, 32, 64, 128, 64, 4, 8, 32><<<512, 256, 0, stream>>>(A1, WT2, ec2_b, A2);

    // ---- A1 now free: all remaining prep ----
    perm_w<64, 64, 128, 128><<<512, 256, 0, stream>>>(ec3_w, WT3);
    perm_w<256, 256, 128, 128><<<2048, 256, 0, stream>>>(dt1_w, WTd1);
    perm_w<128, 128, 64, 64><<<512, 256, 0, stream>>>(dt2_w, WTd2);
    perm_fcmu<<<2048, 256, 0, stream>>>(fcmu_w, FCMUP);
    perm_dfc<<<2048, 256, 0, stream>>>(dfc_w, dfc_b, DFCP, DFCB);
    transp<<<256, 256, 0, stream>>>(fc_w, FCP, 128, 512);
    perm_wih<<<1024, 256, 0, stream>>>(wih_e, WIHP_E);
    perm_wih<<<1024, 256, 0, stream>>>(wih_d, WIHP_D);
    pack_whh<<<1024, 256, 0, stream>>>(whh_e, (float4*)WH4_E);
    merge_dc<<<256, 256, 0, stream>>>(wih_d, fc_w, whh_d, WH4_DC);
    biasdc_k<<<8, 256, 0, stream>>>(bih_d, bhh_d, wih_d, fc_b, BIASDC);
    hipMemsetAsync(HA, 0, 3 * 8192 * sizeof(float), stream);

    conv_gemm<64, 16, 16, 128, 128, 32, 4, 4, 32><<<512, 256, 0, stream>>>(A2, WT3, ec3_b, A3);
    perm_w<128, 128, 256, 256><<<2048, 256, 0, stream>>>(ec4_w, WT4);
    conv_gemm<128, 8, 8, 256, 64, 32, 4, 2, 32><<<512, 256, 0, stream>>>(A3, WT4, ec4_b, A4);

    // ---- fcmu -> Z ----
    fcmu_part<<<128, 512, 0, stream>>>(A4, FCMUP, ZPART);
    fcmu_red<<<128, 256, 0, stream>>>(ZPART, fcmu_b, Z);

    // ---- x projections ----
    gx_kernel<<<64, 512, 0, stream>>>(Z, 128, WIHP_E, bih_e, bhh_e, GX_E);
    gx_kernel<<<4, 512, 0, stream>>>(Z + 15 * 128, 2048, WIHP_D, bih_d, bhh_d, GX_D0);

    // ---- LSTM chains (per-step launches; grid-wide coop sync measured 5x slower) ----
    float* hin = HA; float* hout = HB;
    for (int t = 0; t < 16; ++t) {
        lstm_step<<<64, 512, 0, stream>>>((const float4*)WH4_E, GX_E + t * 2048, 32768,
                                          hin, hout, CB, (float*)nullptr);
        float* tmp = hin; hin = hout; hout = tmp;
    }
    pack_whh<<<1024, 256, 0, stream>>>(whh_d, (float4*)WH4_E);  // reuse slot for dec step 0
    lstm_step<<<64, 512, 0, stream>>>((const float4*)WH4_E, GX_D0, 2048,
                                      hin, hout, CB, HALL);
    { float* tmp = hin; hin = hout; hout = tmp; }
    for (int t = 1; t < 16; ++t) {
        lstm_step<<<64, 512, 0, stream>>>((const float4*)WH4_DC, BIASDC, 0,
                                          hin, hout, CB, HALL + t * 8192);
        float* tmp = hin; hin = hout; hout = tmp;
    }
    zs_k<<<16, 512, 0, stream>>>(HALL, FCP, fc_b, ZS);

    // ---- decoder ----
    dfc_k<<<128, 512, 0, stream>>>(ZS, DFCP, DFCB, A4);
    convt_gemm<256, 4, 4, 128, 128, 64, 64, 4, 4, 32, 0, 0><<<512, 256, 0, stream>>>(A4, WTd1, dt1_b, A3);
    convt_gemm<128, 8, 8, 64, 64, 128, 64, 4, 8, 32, 0, 0><<<512, 256, 0, stream>>>(A3, WTd2, dt2_b, A2);
    convt_gemm<64, 16, 16, 32, 32, 256, 32, 8, 4, 32, 0, 0><<<1024, 256, 0, stream>>>(A2, WTd3, dt3_b, A1);
    dt4_direct<<<1024, 256, 0, stream>>>(A1, (const float4*)WTd4, dt4_b, (float*)d_out);
}

// Round 7
// 899.117 us; speedup vs baseline: 2.7862x; 1.3508x over previous
//
#include <hip/hip_runtime.h>
#include <math.h>

// ---------------------------------------------------------------------------
// CNN-LSTM video predictor, round 7: all conv GEMMs on MFMA bf16 with hi/lo
// split (3 MFMAs / tile, fp32-class accuracy). Activations as 2 bf16 NHWC
// planes. LSTM/FC path = round 6 (proven), adapted to plane format.
// ---------------------------------------------------------------------------

typedef float f32x4 __attribute__((ext_vector_type(4)));
typedef short bf16x8 __attribute__((ext_vector_type(8)));

__device__ __forceinline__ float sig_(float x) { return 1.f / (1.f + expf(-x)); }
__device__ __forceinline__ float dot4(float4 a, float4 b) {
    return a.x * b.x + a.y * b.y + a.z * b.z + a.w * b.w;
}
__device__ __forceinline__ int orig_row(int c) {
    return ((c >> 3) & 3) * 512 + (c >> 5) * 8 + (c & 7);
}
// fp32 -> bf16 (RNE) and back
__device__ __forceinline__ unsigned short f2bf(float f) {
    unsigned int b = __float_as_uint(f);
    return (unsigned short)((b + 0x7fffu + ((b >> 16) & 1u)) >> 16);
}
__device__ __forceinline__ float bf2f(unsigned short h) {
    return __uint_as_float(((unsigned int)h) << 16);
}
// load 4 fp32 values from hi/lo bf16 plane pair at element offset off (8B aligned)
__device__ __forceinline__ float4 ld4bf(const unsigned short* hp, const unsigned short* lp, long off) {
    uint2 h = *(const uint2*)(hp + off);
    uint2 l = *(const uint2*)(lp + off);
    float4 r;
    r.x = __uint_as_float((h.x & 0xffffu) << 16) + __uint_as_float((l.x & 0xffffu) << 16);
    r.y = __uint_as_float(h.x & 0xffff0000u)     + __uint_as_float(l.x & 0xffff0000u);
    r.z = __uint_as_float((h.y & 0xffffu) << 16) + __uint_as_float((l.y & 0xffffu) << 16);
    r.w = __uint_as_float(h.y & 0xffff0000u)     + __uint_as_float(l.y & 0xffff0000u);
    return r;
}

// =================== MFMA conv / convT (split bf16) ========================
// MODE 0: conv s2 k4 p1 (K = CIP*16, k = tap*CIP + ci).
// MODE 1: convT parity (p,q) (K = CIP*4, k = t4*CIP + ci), grid z = parity.
// SRCF32=1 (ec1): A read from fp32 NHWC4, split on the fly (CIP==4).
// WB: packed per-lane fragments [par][plane(hi,lo)][nt16][kb32][lane][8].
// Output: relu(v+bias) split-stored to Yhi/Ylo NHWC planes.
template<int CIP, int HI, int WI, int CO, int WM, int WN, int MODE, int SRCF32>
__global__ __launch_bounds__(64 * WM * WN)
void conv_mfma(const unsigned short* __restrict__ Ahi, const unsigned short* __restrict__ Alo,
               const float* __restrict__ Af,
               const unsigned short* __restrict__ WB, const float* __restrict__ bias,
               unsigned short* __restrict__ Yhi, unsigned short* __restrict__ Ylo) {
    constexpr int K   = CIP * (MODE ? 4 : 16);
    constexpr int K32 = K / 32;
    constexpr int HO  = MODE ? HI * 2 : HI / 2;
    constexpr int WO  = MODE ? WI * 2 : WI / 2;
    constexpr int SH  = MODE ? HI : HI / 2;
    constexpr int SW  = MODE ? WI : WI / 2;
    constexpr int HWS = SH * SW;
    constexpr int MT  = (256 * HWS) / (32 * WM);
    constexpr int NT  = CO / (32 * WN);
    constexpr int PLANE = CO * K;

    int bid = blockIdx.x;
    int mt = bid % MT; bid /= MT;
    int nt = bid % NT; int par = bid / NT;
    int p = par >> 1, q = par & 1;

    int tid = threadIdx.x;
    int lane = tid & 63, wid = tid >> 6;
    int wm = wid % WM, wn = wid / WM;
    int mbase = mt * (32 * WM) + wm * 32;
    int nbase = nt * (32 * WN) + wn * 32;
    int lm = lane & 15, lg = lane >> 4;

    int ani[2], asy[2], asx[2];
#pragma unroll
    for (int i = 0; i < 2; ++i) {
        int m = mbase + 16 * i + lm;
        ani[i] = m / HWS; int r = m % HWS; asy[i] = r / SW; asx[i] = r % SW;
    }

    f32x4 acc[2][2];
#pragma unroll
    for (int i = 0; i < 2; ++i)
#pragma unroll
        for (int j = 0; j < 2; ++j)
#pragma unroll
            for (int e = 0; e < 4; ++e) acc[i][j][e] = 0.f;

    const unsigned short* WBp = WB + (long)par * 2 * PLANE;

    for (int kb = 0; kb < K; kb += 32) {
        int k0 = kb + lg * 8;
        bf16x8 ah[2], al[2];
        if constexpr (SRCF32) {
            // CIP==4: 8 k's = 2 taps x 4 ci, fp32 source, split on the fly
            int t0 = k0 >> 2;
#pragma unroll
            for (int i = 0; i < 2; ++i) {
                float f[8];
#pragma unroll
                for (int h = 0; h < 2; ++h) {
                    int tap = t0 + h;
                    int ih = 2 * asy[i] + (tap >> 2) - 1;
                    int iw = 2 * asx[i] + (tap & 3) - 1;
                    float4 v = {0.f, 0.f, 0.f, 0.f};
                    if ((unsigned)ih < (unsigned)HI && (unsigned)iw < (unsigned)WI)
                        v = *(const float4*)(Af + (((long)ani[i] * HI + ih) * WI + iw) * 4);
                    f[h * 4 + 0] = v.x; f[h * 4 + 1] = v.y;
                    f[h * 4 + 2] = v.z; f[h * 4 + 3] = v.w;
                }
#pragma unroll
                for (int e = 0; e < 8; ++e) {
                    unsigned short hh = f2bf(f[e]);
                    ah[i][e] = (short)hh;
                    al[i][e] = (short)f2bf(f[e] - bf2f(hh));
                }
            }
        } else {
            int tap = k0 / CIP;
            int ci  = k0 & (CIP - 1);
#pragma unroll
            for (int i = 0; i < 2; ++i) {
                int ih, iw;
                if constexpr (MODE == 0) {
                    ih = 2 * asy[i] + (tap >> 2) - 1;
                    iw = 2 * asx[i] + (tap & 3) - 1;
                } else {
                    ih = asy[i] + p + (tap >> 1) - 1;
                    iw = asx[i] + q + (tap & 1) - 1;
                }
                bf16x8 zh, zl;
#pragma unroll
                for (int e = 0; e < 8; ++e) { zh[e] = 0; zl[e] = 0; }
                if ((unsigned)ih < (unsigned)HI && (unsigned)iw < (unsigned)WI) {
                    long off = (((long)ani[i] * HI + ih) * WI + iw) * CIP + ci;
                    zh = *(const bf16x8*)(Ahi + off);
                    zl = *(const bf16x8*)(Alo + off);
                }
                ah[i] = zh; al[i] = zl;
            }
        }
        bf16x8 bh[2], bl[2];
#pragma unroll
        for (int j = 0; j < 2; ++j) {
            long bidx = ((long)((nbase >> 4) + j) * K32 + (kb >> 5)) * 512 + lane * 8;
            bh[j] = *(const bf16x8*)(WBp + bidx);
            bl[j] = *(const bf16x8*)(WBp + PLANE + bidx);
        }
#pragma unroll
        for (int i = 0; i < 2; ++i)
#pragma unroll
            for (int j = 0; j < 2; ++j) {
                acc[i][j] = __builtin_amdgcn_mfma_f32_16x16x32_bf16(ah[i], bh[j], acc[i][j], 0, 0, 0);
                acc[i][j] = __builtin_amdgcn_mfma_f32_16x16x32_bf16(ah[i], bl[j], acc[i][j], 0, 0, 0);
                acc[i][j] = __builtin_amdgcn_mfma_f32_16x16x32_bf16(al[i], bh[j], acc[i][j], 0, 0, 0);
            }
    }

    // epilogue: D row=(lane>>4)*4+r, col=lane&15 within each 16x16 subtile
#pragma unroll
    for (int i = 0; i < 2; ++i)
#pragma unroll
        for (int j = 0; j < 2; ++j)
#pragma unroll
            for (int r = 0; r < 4; ++r) {
                int m = mbase + 16 * i + lg * 4 + r;
                int co = nbase + 16 * j + lm;
                float v = acc[i][j][r] + bias[co];
                v = fmaxf(v, 0.f);
                long off;
                if constexpr (MODE == 0) {
                    off = (long)m * CO + co;
                } else {
                    int ni = m / HWS; int rm = m % HWS;
                    int oy = 2 * (rm / SW) + p, ox = 2 * (rm % SW) + q;
                    off = (((long)ni * HO + oy) * WO + ox) * CO + co;
                }
                unsigned short hh = f2bf(v);
                Yhi[off] = hh;
                Ylo[off] = f2bf(v - bf2f(hh));
            }
}

// ============== dt4: CO=3, sigmoid, NCHW output, reads planes ===============
__global__ __launch_bounds__(256)
void dt4_direct(const unsigned short* __restrict__ Xh, const unsigned short* __restrict__ Xl,
                const float4* __restrict__ Wd, const float* __restrict__ bias,
                float* __restrict__ out) {
    int m = blockIdx.x * 256 + threadIdx.x;  // 262144
    int n = m >> 10, rem = m & 1023;
    int yy = rem >> 5, xx = rem & 31;
    float acc[3][4];
#pragma unroll
    for (int j = 0; j < 3; ++j) {
        float b = bias[j];
#pragma unroll
        for (int par = 0; par < 4; ++par) acc[j][par] = b;
    }
    long nb = (long)n * 1024 * 32;
    for (int ci4 = 0; ci4 < 8; ++ci4) {
        float4 xv[9];
#pragma unroll
        for (int r = 0; r < 3; ++r) {
            int ih = yy + r - 1;
#pragma unroll
            for (int c = 0; c < 3; ++c) {
                int iw = xx + c - 1;
                float4 v = {0.f, 0.f, 0.f, 0.f};
                if ((unsigned)ih < 32u && (unsigned)iw < 32u)
                    v = ld4bf(Xh, Xl, nb + ((long)ih * 32 + iw) * 32 + ci4 * 4);
                xv[r * 3 + c] = v;
            }
        }
        const float4* wp = Wd + ci4 * 48;
#pragma unroll
        for (int j = 0; j < 3; ++j)
#pragma unroll
            for (int par = 0; par < 4; ++par) {
                int p = par >> 1, q = par & 1;
#pragma unroll
                for (int t4 = 0; t4 < 4; ++t4) {
                    int dh = t4 >> 1, dw = t4 & 1;
                    acc[j][par] += dot4(xv[(p + dh) * 3 + (q + dw)],
                                        wp[(j * 4 + par) * 4 + t4]);
                }
            }
    }
#pragma unroll
    for (int j = 0; j < 3; ++j)
#pragma unroll
        for (int p = 0; p < 2; ++p) {
            float2 v;
            v.x = sig_(acc[j][p * 2 + 0]);
            v.y = sig_(acc[j][p * 2 + 1]);
            *(float2*)(out + (((long)n * 3 + j) * 64 + 2 * yy + p) * 64 + 2 * xx) = v;
        }
}

// ========================= weight / layout prep =============================
// conv OIHW -> fragment-packed hi/lo: [2][CO/16][K/32][64][8], k=tap*CIP+ci
template<int CIS, int CIP, int CO>
__global__ void pack_wb_conv(const float* __restrict__ w, unsigned short* __restrict__ out) {
    constexpr int K = CIP * 16;
    int idx = blockIdx.x * 256 + threadIdx.x;
    if (idx >= CO * K) return;
    int j = idx & 7, lane = (idx >> 3) & 63;
    int kb = (idx >> 9) % (K / 32), nt = idx / (512 * (K / 32));
    int k = kb * 32 + (lane >> 4) * 8 + j;
    int tap = k / CIP, ci = k & (CIP - 1);
    int co = nt * 16 + (lane & 15);
    float f = (ci < CIS) ? w[((long)co * CIS + ci) * 16 + tap] : 0.f;
    unsigned short hi = f2bf(f);
    out[idx] = hi;
    out[CO * K + idx] = f2bf(f - bf2f(hi));
}

// convT OIHW -> [par][2][CO/16][Kp/32][64][8], k=t4*CI+ci, tap=(p+2dh)*4+(q+2dw)
template<int CI, int CO>
__global__ void pack_wb_convt(const float* __restrict__ w, unsigned short* __restrict__ out) {
    constexpr int Kp = CI * 4;
    int idx = blockIdx.x * 256 + threadIdx.x;
    if (idx >= 4 * CO * Kp) return;
    int par = idx / (CO * Kp); int rem = idx % (CO * Kp);
    int j = rem & 7, lane = (rem >> 3) & 63;
    int kb = (rem >> 9) % (Kp / 32), nt = rem / (512 * (Kp / 32));
    int k = kb * 32 + (lane >> 4) * 8 + j;
    int t4 = k / CI, ci = k & (CI - 1);
    int p = par >> 1, q = par & 1, dh = t4 >> 1, dw = t4 & 1;
    int tap = (p + 2 * dh) * 4 + (q + 2 * dw);
    int co = nt * 16 + (lane & 15);
    float f = w[((long)co * CI + ci) * 16 + tap];
    unsigned short hi = f2bf(f);
    out[(long)par * 2 * CO * Kp + rem] = hi;
    out[(long)par * 2 * CO * Kp + CO * Kp + rem] = f2bf(f - bf2f(hi));
}

// convT OIHW -> float4[((ci4*CO+co)*4+par)*4+t4] (for dt4_direct, fp32)
template<int CI, int CO>
__global__ void perm_dirwT(const float* __restrict__ w, float4* __restrict__ out) {
    int idx = blockIdx.x * 256 + threadIdx.x;
    if (idx >= (CI / 4) * CO * 16) return;
    int t4 = idx & 3; int par = (idx >> 2) & 3;
    int co = (idx >> 4) % CO; int ci4 = (idx >> 4) / CO;
    int p = par >> 1, q = par & 1, dh = t4 >> 1, dw = t4 & 1;
    int tap = (p + 2 * dh) * 4 + (q + 2 * dw);
    float4 v; float* pv = (float*)&v;
#pragma unroll
    for (int l = 0; l < 4; ++l)
        pv[l] = w[((long)co * CI + ci4 * 4 + l) * 16 + tap];
    out[idx] = v;
}

__global__ void to_nhwc4(const float* __restrict__ v, float* __restrict__ out) {
    int idx = blockIdx.x * 256 + threadIdx.x;  // 4,194,304
    int c = idx & 3; int w = (idx >> 2) & 63; int h = (idx >> 8) & 63; int n = idx >> 14;
    out[idx] = (c < 3) ? v[(((long)n * 3 + c) * 64 + h) * 64 + w] : 0.f;
}

__global__ void perm_fcmu(const float* __restrict__ w, float* __restrict__ out) {
    int idx = blockIdx.x * 256 + threadIdx.x;  // 524288
    int j = idx & 127; int k = idx >> 7;
    out[idx] = w[(long)j * 4096 + (k & 255) * 16 + (k >> 8)];
}

__global__ void perm_dfc(const float* __restrict__ w, const float* __restrict__ b,
                         float* __restrict__ outw, float* __restrict__ outb) {
    int idx = blockIdx.x * 256 + threadIdx.x;  // 524288
    int j = idx & 4095; int m = idx >> 12;
    int jc = (j & 255) * 16 + (j >> 8);
    outw[idx] = w[(long)jc * 128 + m];
    if (idx < 4096) outb[idx] = b[(idx & 255) * 16 + (idx >> 8)];
}

__global__ void transp(const float* __restrict__ in, float* __restrict__ out,
                       int R, int C) {
    long idx = (long)blockIdx.x * 256 + threadIdx.x;
    if (idx >= (long)R * C) return;
    int r = (int)(idx % R), c = (int)(idx / R);
    out[idx] = in[(long)r * C + c];
}

__global__ void perm_wih(const float* __restrict__ wih, float* __restrict__ out) {
    int idx = blockIdx.x * 256 + threadIdx.x;  // 262144
    int c = idx & 2047, m = idx >> 11;
    out[idx] = wih[orig_row(c) * 128 + m];
}

__global__ void pack_whh(const float* __restrict__ whh, float4* __restrict__ out) {
    int idx = blockIdx.x * 256 + threadIdx.x;  // 262144
    int c = idx & 2047, k4 = idx >> 11;
    const float4* src = (const float4*)(whh + orig_row(c) * 512);
    out[idx] = src[k4];
}

__global__ __launch_bounds__(256)
void merge_dc(const float* __restrict__ wih_d, const float* __restrict__ fc_w,
              const float* __restrict__ whh_d, float* __restrict__ out) {
    int cb = (blockIdx.x >> 3) * 64, kb = (blockIdx.x & 7) * 64;
    int tid = threadIdx.x;
    int cgl = (tid & 15) * 4, kgl = (tid >> 4) * 4;
    __shared__ float At[64][65];
    __shared__ float Bt[64][65];
    float acc[4][4] = {};
    for (int mc = 0; mc < 128; mc += 64) {
        __syncthreads();
        for (int i = tid; i < 4096; i += 256) {
            int cl = i >> 6, m = i & 63;
            At[cl][m] = wih_d[orig_row(cb + cl) * 128 + mc + m];
            Bt[cl][m] = fc_w[(mc + cl) * 512 + kb + m];
        }
        __syncthreads();
        for (int m = 0; m < 64; ++m) {
            float a[4], b[4];
#pragma unroll
            for (int i = 0; i < 4; ++i) { a[i] = At[cgl + i][m]; b[i] = Bt[m][kgl + i]; }
#pragma unroll
            for (int i = 0; i < 4; ++i)
#pragma unroll
                for (int j = 0; j < 4; ++j) acc[i][j] += a[i] * b[j];
        }
    }
    for (int i = 0; i < 4; ++i) {
        int c = cb + cgl + i; int orow = orig_row(c);
        for (int j = 0; j < 4; ++j) {
            int k = kb + kgl + j;
            out[((k >> 2) * 2048 + c) * 4 + (k & 3)] = acc[i][j] + whh_d[orow * 512 + k];
        }
    }
}

__global__ void biasdc_k(const float* __restrict__ bih, const float* __restrict__ bhh,
                         const float* __restrict__ wih_d, const float* __restrict__ fc_b,
                         float* __restrict__ out) {
    int c = blockIdx.x * 256 + threadIdx.x;
    if (c >= 2048) return;
    int orow = orig_row(c);
    float s = bih[orow] + bhh[orow];
    for (int m = 0; m < 128; ++m) s += fc_b[m] * wih_d[orow * 128 + m];
    out[c] = s;
}

// ============================ LSTM / FC path ================================
__global__ __launch_bounds__(512)
void gx_kernel(const float* __restrict__ z, int zrstride,
               const float* __restrict__ wihP, const float* __restrict__ bih,
               const float* __restrict__ bhh, float* __restrict__ out) {
    int rg = blockIdx.x >> 2, cch = blockIdx.x & 3;
    int tid = threadIdx.x;
    __shared__ float zl[16 * 128];
    for (int i = tid; i < 2048; i += 512)
        zl[i] = z[(long)(rg * 16 + (i >> 7)) * zrstride + (i & 127)];
    __syncthreads();
    int c = cch * 512 + tid;
    int orow = orig_row(c);
    float bsum = bih[orow] + bhh[orow];
    float acc[16];
#pragma unroll
    for (int r = 0; r < 16; ++r) acc[r] = bsum;
    for (int m = 0; m < 128; ++m) {
        float wv = wihP[m * 2048 + c];
#pragma unroll
        for (int r = 0; r < 16; ++r) acc[r] += zl[r * 128 + m] * wv;
    }
    for (int r = 0; r < 16; ++r) out[(long)(rg * 16 + r) * 2048 + c] = acc[r];
}

__global__ __launch_bounds__(512)
void lstm_step(const float4* __restrict__ wh4, const float* __restrict__ gadd,
               int gstride, const float* __restrict__ h_in, float* __restrict__ h_out,
               float* __restrict__ cst, float* __restrict__ hall) {
    __shared__ float hs[8192];
    __shared__ float gb[16][32];
    int tid = threadIdx.x;
    float4* hs4 = (float4*)hs;
    const float4* hi4 = (const float4*)h_in;
#pragma unroll
    for (int i = 0; i < 4; ++i) hs4[tid + 512 * i] = hi4[tid + 512 * i];
    __syncthreads();
    int col = tid & 31, n = tid >> 5;
    int cg = blockIdx.x * 32 + col;
    float acc = gadd[n * gstride + cg];
    const float4* wp = wh4 + cg;
    const float4* hv = (const float4*)(hs + n * 512);
#pragma unroll 8
    for (int k4 = 0; k4 < 128; ++k4) {
        float4 wv = wp[(long)k4 * 2048];
        float4 h4 = hv[k4];
        acc += wv.x * h4.x + wv.y * h4.y + wv.z * h4.z + wv.w * h4.w;
    }
    gb[n][col] = acc;
    __syncthreads();
    if (col < 8) {
        int j = blockIdx.x * 8 + col;
        float gi = sig_(gb[n][col]);
        float gf = sig_(gb[n][col + 8]);
        float gg = tanhf(gb[n][col + 16]);
        float go = sig_(gb[n][col + 24]);
        int idx = n * 512 + j;
        float cv = gf * cst[idx] + gi * gg;
        cst[idx] = cv;
        float hvv = go * tanhf(cv);
        h_out[idx] = hvv;
        if (hall) hall[idx] = hvv;
    }
}

__global__ __launch_bounds__(512)
void fcmu_part(const unsigned short* __restrict__ xh, const unsigned short* __restrict__ xl,
               const float* __restrict__ wP, float* __restrict__ part) {
    int rg = blockIdx.x >> 3, ks = blockIdx.x & 7;
    int tid = threadIdx.x;
    __shared__ float xls[16 * 512];
    for (int i = tid; i < 8192; i += 512) {
        long gi = (long)(rg * 16 + (i >> 9)) * 4096 + ks * 512 + (i & 511);
        xls[i] = bf2f(xh[gi]) + bf2f(xl[gi]);
    }
    __syncthreads();
    int j = tid & 127, rq = tid >> 7;
    float acc[4] = {0, 0, 0, 0};
    for (int k = 0; k < 512; ++k) {
        float wv = wP[(ks * 512 + k) * 128 + j];
#pragma unroll
        for (int i = 0; i < 4; ++i) acc[i] += xls[(rq + 4 * i) * 512 + k] * wv;
    }
    for (int i = 0; i < 4; ++i)
        part[((long)ks * 256 + rg * 16 + rq + 4 * i) * 128 + j] = acc[i];
}

__global__ void fcmu_red(const float* __restrict__ part, const float* __restrict__ b,
                         float* __restrict__ z) {
    int idx = blockIdx.x * 256 + threadIdx.x;  // 32768
    float s = b[idx & 127];
    for (int k = 0; k < 8; ++k) s += part[k * 32768 + idx];
    z[idx] = s;
}

__global__ __launch_bounds__(512)
void zs_k(const float* __restrict__ hall, const float* __restrict__ fcP,
          const float* __restrict__ fcb, float* __restrict__ zs) {
    int t = blockIdx.x;
    int tid = threadIdx.x;
    __shared__ float hs[8192];
    const float* h = hall + t * 8192;
    for (int i = tid; i < 8192; i += 512) hs[i] = h[i];
    __syncthreads();
    int j = tid & 127, ng = tid >> 7;
    float acc[4] = {0, 0, 0, 0};
    for (int k = 0; k < 512; ++k) {
        float wv = fcP[k * 128 + j];
#pragma unroll
        for (int i = 0; i < 4; ++i) acc[i] += hs[(ng + 4 * i) * 512 + k] * wv;
    }
    float bv = fcb[j];
    for (int i = 0; i < 4; ++i)
        zs[((ng + 4 * i) * 16 + t) * 128 + j] = acc[i] + bv;
}

// dfc: relu FC, split-stores to B4 planes (NHWC [256][4][4][256])
__global__ __launch_bounds__(512)
void dfc_k(const float* __restrict__ zs, const float* __restrict__ dP,
           const float* __restrict__ db,
           unsigned short* __restrict__ outh, unsigned short* __restrict__ outl) {
    int rg = blockIdx.x >> 3, jc = blockIdx.x & 7;
    int tid = threadIdx.x;
    __shared__ float zl[16 * 128];
    for (int i = tid; i < 2048; i += 512) zl[i] = zs[(long)rg * 2048 + i];
    __syncthreads();
    int j = jc * 512 + tid;
    float acc[16];
#pragma unroll
    for (int r = 0; r < 16; ++r) acc[r] = 0.f;
    for (int m = 0; m < 128; ++m) {
        float wv = dP[(long)m * 4096 + j];
#pragma unroll
        for (int r = 0; r < 16; ++r) acc[r] += zl[r * 128 + m] * wv;
    }
    float bv = db[j];
    for (int r = 0; r < 16; ++r) {
        float v = fmaxf(acc[r] + bv, 0.f);
        long idx = (long)(rg * 16 + r) * 4096 + j;
        unsigned short hh = f2bf(v);
        outh[idx] = hh;
        outl[idx] = f2bf(v - bf2f(hh));
    }
}

extern "C" void kernel_launch(void* const* d_in, const int* in_sizes, int n_in,
                              void* d_out, int out_size, void* d_ws, size_t ws_size,
                              hipStream_t stream) {
    (void)in_sizes; (void)n_in; (void)out_size; (void)ws_size;
    const float* video  = (const float*)d_in[0];
    const float* ec1_w  = (const float*)d_in[2];  const float* ec1_b = (const float*)d_in[3];
    const float* ec2_w  = (const float*)d_in[4];  const float* ec2_b = (const float*)d_in[5];
    const float* ec3_w  = (const float*)d_in[6];  const float* ec3_b = (const float*)d_in[7];
    const float* ec4_w  = (const float*)d_in[8];  const float* ec4_b = (const float*)d_in[9];
    const float* fcmu_w = (const float*)d_in[10]; const float* fcmu_b = (const float*)d_in[11];
    const float* dfc_w  = (const float*)d_in[12]; const float* dfc_b = (const float*)d_in[13];
    const float* dt1_w  = (const float*)d_in[14]; const float* dt1_b = (const float*)d_in[15];
    const float* dt2_w  = (const float*)d_in[16]; const float* dt2_b = (const float*)d_in[17];
    const float* dt3_w  = (const float*)d_in[18]; const float* dt3_b = (const float*)d_in[19];
    const float* dt4_w  = (const float*)d_in[20]; const float* dt4_b = (const float*)d_in[21];
    const float* wih_e  = (const float*)d_in[22]; const float* whh_e = (const float*)d_in[23];
    const float* bih_e  = (const float*)d_in[24]; const float* bhh_e = (const float*)d_in[25];
    const float* wih_d  = (const float*)d_in[26]; const float* whh_d = (const float*)d_in[27];
    const float* bih_d  = (const float*)d_in[28]; const float* bhh_d = (const float*)d_in[29];
    const float* fc_w   = (const float*)d_in[30]; const float* fc_b  = (const float*)d_in[31];

    char* wsb = (char*)d_ws;
    // ---- activation plane pairs (bf16 hi/lo) ----
    unsigned short* B1h = (unsigned short*)wsb;             // 8,388,608 e each
    unsigned short* B1l = B1h + 8388608;                    // R1 = [0, 33.5MB)
    float*          X0f = (float*)(wsb + 33554432);         // fp32 NHWC4 (ec1 in)
    unsigned short* B2h = (unsigned short*)(wsb + 33554432);// after ec1: B2 pair
    unsigned short* B2l = B2h + 4194304;
    unsigned short* B3h = (unsigned short*)(wsb + 50331648);
    unsigned short* B3l = B3h + 2097152;
    unsigned short* B4h = (unsigned short*)(wsb + 58720256);
    unsigned short* B4l = B4h + 1048576;
    // ---- R1 interior (valid after ec2, dead before dt3 writes B1) ----
    float* R1f    = (float*)wsb;
    float* WH4_E  = R1f;                  // 1,048,576 f
    float* WH4_DC = R1f + 1048576;        // 1,048,576
    float* WIHP_E = R1f + 2097152;        // 262,144
    float* WIHP_D = R1f + 2359296;        // 262,144
    float* GX_E   = R1f + 2621440;        // 524,288
    float* GX_D0  = R1f + 3145728;        // 32,768
    float* BIASDC = R1f + 3178496;        // 2,048
    float* HA     = R1f + 3180544;        // 8,192
    float* HB     = R1f + 3188736;        // 8,192
    float* CB     = R1f + 3196928;        // 8,192
    float* HALL   = R1f + 3205120;        // 131,072
    float* FCMUP  = R1f + 3336192;        // 524,288
    float* ZPART  = R1f + 3860480;        // 262,144
    float* FCP    = R1f + 4122624;        // 65,536
    float* DFCP   = R1f + 4188160;        // 524,288
    float* DFCB   = R1f + 4712448;        // 4,096
    float* Z      = R1f + 4716544;        // 32,768
    float* ZS     = R1f + 4749312;        // 32,768
    unsigned short* WBe3 = (unsigned short*)(R1f + 4782080); // 262,144 e
    unsigned short* WBe4 = (unsigned short*)(R1f + 4913152); // 1,048,576 e
    unsigned short* WBd1 = (unsigned short*)(R1f + 5437440); // 1,048,576 e
    unsigned short* WBd2 = (unsigned short*)(R1f + 5961728); // 262,144 e
    // ---- persistent tail ----
    unsigned short* WBe1 = (unsigned short*)(wsb + 62914560); // 4,096 e
    unsigned short* WBe2 = (unsigned short*)(wsb + 62922752); // 65,536 e
    unsigned short* WBd3 = (unsigned short*)(wsb + 63053824); // 65,536 e
    float*          WTd4 = (float*)(wsb + 63184896);          // 1,536 f

    // ---- tables needed while B1/B2 live (tail) ----
    pack_wb_conv<3, 4, 32><<<8, 256, 0, stream>>>(ec1_w, WBe1);
    pack_wb_conv<32, 32, 64><<<128, 256, 0, stream>>>(ec2_w, WBe2);
    pack_wb_convt<64, 32><<<128, 256, 0, stream>>>(dt3_w, WBd3);
    perm_dirwT<32, 3><<<2, 256, 0, stream>>>(dt4_w, (float4*)WTd4);

    // ---- encoder ec1/ec2 ----
    to_nhwc4<<<16384, 256, 0, stream>>>(video, X0f);
    conv_mfma<4, 64, 64, 32, 4, 1, 0, 1><<<2048, 256, 0, stream>>>(
        nullptr, nullptr, X0f, WBe1, ec1_b, B1h, B1l);
    conv_mfma<32, 32, 32, 64, 2, 2, 0, 0><<<1024, 256, 0, stream>>>(
        B1h, B1l, nullptr, WBe2, ec2_b, B2h, B2l);

    // ---- R1 free: all remaining prep ----
    pack_wb_conv<64, 64, 128><<<512, 256, 0, stream>>>(ec3_w, WBe3);
    pack_wb_conv<128, 128, 256><<<2048, 256, 0, stream>>>(ec4_w, WBe4);
    pack_wb_convt<256, 128><<<2048, 256, 0, stream>>>(dt1_w, WBd1);
    pack_wb_convt<128, 64><<<512, 256, 0, stream>>>(dt2_w, WBd2);
    perm_fcmu<<<2048, 256, 0, stream>>>(fcmu_w, FCMUP);
    perm_dfc<<<2048, 256, 0, stream>>>(dfc_w, dfc_b, DFCP, DFCB);
    transp<<<256, 256, 0, stream>>>(fc_w, FCP, 128, 512);
    perm_wih<<<1024, 256, 0, stream>>>(wih_e, WIHP_E);
    perm_wih<<<1024, 256, 0, stream>>>(wih_d, WIHP_D);
    pack_whh<<<1024, 256, 0, stream>>>(whh_e, (float4*)WH4_E);
    merge_dc<<<256, 256, 0, stream>>>(wih_d, fc_w, whh_d, WH4_DC);
    biasdc_k<<<8, 256, 0, stream>>>(bih_d, bhh_d, wih_d, fc_b, BIASDC);
    hipMemsetAsync(HA, 0, 3 * 8192 * sizeof(float), stream);

    // ---- encoder ec3/ec4 + fcmu ----
    conv_mfma<64, 16, 16, 128, 2, 2, 0, 0><<<512, 256, 0, stream>>>(
        B2h, B2l, nullptr, WBe3, ec3_b, B3h, B3l);
    conv_mfma<128, 8, 8, 256, 2, 2, 0, 0><<<256, 256, 0, stream>>>(
        B3h, B3l, nullptr, WBe4, ec4_b, B4h, B4l);
    fcmu_part<<<128, 512, 0, stream>>>(B4h, B4l, FCMUP, ZPART);
    fcmu_red<<<128, 256, 0, stream>>>(ZPART, fcmu_b, Z);

    // ---- x projections ----
    gx_kernel<<<64, 512, 0, stream>>>(Z, 128, WIHP_E, bih_e, bhh_e, GX_E);
    gx_kernel<<<4, 512, 0, stream>>>(Z + 15 * 128, 2048, WIHP_D, bih_d, bhh_d, GX_D0);

    // ---- LSTM chains (per-step launches; coop grid-sync measured 5x slower) ----
    float* hin = HA; float* hout = HB;
    for (int t = 0; t < 16; ++t) {
        lstm_step<<<64, 512, 0, stream>>>((const float4*)WH4_E, GX_E + t * 2048, 32768,
                                          hin, hout, CB, (float*)nullptr);
        float* tmp = hin; hin = hout; hout = tmp;
    }
    pack_whh<<<1024, 256, 0, stream>>>(whh_d, (float4*)WH4_E);  // reuse slot for dec step 0
    lstm_step<<<64, 512, 0, stream>>>((const float4*)WH4_E, GX_D0, 2048,
                                      hin, hout, CB, HALL);
    { float* tmp = hin; hin = hout; hout = tmp; }
    for (int t = 1; t < 16; ++t) {
        lstm_step<<<64, 512, 0, stream>>>((const float4*)WH4_DC, BIASDC, 0,
                                          hin, hout, CB, HALL + t * 8192);
        float* tmp = hin; hin = hout; hout = tmp;
    }
    zs_k<<<16, 512, 0, stream>>>(HALL, FCP, fc_b, ZS);

    // ---- decoder ----
    dfc_k<<<128, 512, 0, stream>>>(ZS, DFCP, DFCB, B4h, B4l);
    conv_mfma<256, 4, 4, 128, 2, 2, 1, 0><<<512, 256, 0, stream>>>(
        B4h, B4l, nullptr, WBd1, dt1_b, B3h, B3l);
    conv_mfma<128, 8, 8, 64, 2, 2, 1, 0><<<1024, 256, 0, stream>>>(
        B3h, B3l, nullptr, WBd2, dt2_b, B2h, B2l);
    conv_mfma<64, 16, 16, 32, 4, 1, 1, 0><<<2048, 256, 0, stream>>>(
        B2h, B2l, nullptr, WBd3, dt3_b, B1h, B1l);
    dt4_direct<<<1024, 256, 0, stream>>>(B1h, B1l, (const float4*)WTd4, dt4_b, (float*)d_out);
}

// Round 8
// 787.667 us; speedup vs baseline: 3.1804x; 1.1415x over previous
//
#include <hip/hip_runtime.h>
#include <math.h>

// ---------------------------------------------------------------------------
// CNN-LSTM video predictor, round 8: round-7 MFMA split-bf16 convs +
// LDS-tiled dt4 (kills the 155MB over-fetch) + merged prep launches.
// ---------------------------------------------------------------------------

typedef float f32x4 __attribute__((ext_vector_type(4)));
typedef short bf16x8 __attribute__((ext_vector_type(8)));

__device__ __forceinline__ float sig_(float x) { return 1.f / (1.f + expf(-x)); }
__device__ __forceinline__ float dot4(float4 a, float4 b) {
    return a.x * b.x + a.y * b.y + a.z * b.z + a.w * b.w;
}
__device__ __forceinline__ int orig_row(int c) {
    return ((c >> 3) & 3) * 512 + (c >> 5) * 8 + (c & 7);
}
__device__ __forceinline__ unsigned short f2bf(float f) {
    unsigned int b = __float_as_uint(f);
    return (unsigned short)((b + 0x7fffu + ((b >> 16) & 1u)) >> 16);
}
__device__ __forceinline__ float bf2f(unsigned short h) {
    return __uint_as_float(((unsigned int)h) << 16);
}
__device__ __forceinline__ float4 ld4bf(const unsigned short* hp, const unsigned short* lp, long off) {
    uint2 h = *(const uint2*)(hp + off);
    uint2 l = *(const uint2*)(lp + off);
    float4 r;
    r.x = __uint_as_float((h.x & 0xffffu) << 16) + __uint_as_float((l.x & 0xffffu) << 16);
    r.y = __uint_as_float(h.x & 0xffff0000u)     + __uint_as_float(l.x & 0xffff0000u);
    r.z = __uint_as_float((h.y & 0xffffu) << 16) + __uint_as_float((l.y & 0xffffu) << 16);
    r.w = __uint_as_float(h.y & 0xffff0000u)     + __uint_as_float(l.y & 0xffff0000u);
    return r;
}

// =================== MFMA conv / convT (split bf16) ========================
template<int CIP, int HI, int WI, int CO, int WM, int WN, int MODE, int SRCF32>
__global__ __launch_bounds__(64 * WM * WN)
void conv_mfma(const unsigned short* __restrict__ Ahi, const unsigned short* __restrict__ Alo,
               const float* __restrict__ Af,
               const unsigned short* __restrict__ WB, const float* __restrict__ bias,
               unsigned short* __restrict__ Yhi, unsigned short* __restrict__ Ylo) {
    constexpr int K   = CIP * (MODE ? 4 : 16);
    constexpr int K32 = K / 32;
    constexpr int HO  = MODE ? HI * 2 : HI / 2;
    constexpr int WO  = MODE ? WI * 2 : WI / 2;
    constexpr int SH  = MODE ? HI : HI / 2;
    constexpr int SW  = MODE ? WI : WI / 2;
    constexpr int HWS = SH * SW;
    constexpr int MT  = (256 * HWS) / (32 * WM);
    constexpr int NT  = CO / (32 * WN);
    constexpr int PLANE = CO * K;

    int bid = blockIdx.x;
    int mt = bid % MT; bid /= MT;
    int nt = bid % NT; int par = bid / NT;
    int p = par >> 1, q = par & 1;

    int tid = threadIdx.x;
    int lane = tid & 63, wid = tid >> 6;
    int wm = wid % WM, wn = wid / WM;
    int mbase = mt * (32 * WM) + wm * 32;
    int nbase = nt * (32 * WN) + wn * 32;
    int lm = lane & 15, lg = lane >> 4;

    int ani[2], asy[2], asx[2];
#pragma unroll
    for (int i = 0; i < 2; ++i) {
        int m = mbase + 16 * i + lm;
        ani[i] = m / HWS; int r = m % HWS; asy[i] = r / SW; asx[i] = r % SW;
    }

    f32x4 acc[2][2];
#pragma unroll
    for (int i = 0; i < 2; ++i)
#pragma unroll
        for (int j = 0; j < 2; ++j)
#pragma unroll
            for (int e = 0; e < 4; ++e) acc[i][j][e] = 0.f;

    const unsigned short* WBp = WB + (long)par * 2 * PLANE;

    for (int kb = 0; kb < K; kb += 32) {
        int k0 = kb + lg * 8;
        bf16x8 ah[2], al[2];
        if constexpr (SRCF32) {
            int t0 = k0 >> 2;
#pragma unroll
            for (int i = 0; i < 2; ++i) {
                float f[8];
#pragma unroll
                for (int h = 0; h < 2; ++h) {
                    int tap = t0 + h;
                    int ih = 2 * asy[i] + (tap >> 2) - 1;
                    int iw = 2 * asx[i] + (tap & 3) - 1;
                    float4 v = {0.f, 0.f, 0.f, 0.f};
                    if ((unsigned)ih < (unsigned)HI && (unsigned)iw < (unsigned)WI)
                        v = *(const float4*)(Af + (((long)ani[i] * HI + ih) * WI + iw) * 4);
                    f[h * 4 + 0] = v.x; f[h * 4 + 1] = v.y;
                    f[h * 4 + 2] = v.z; f[h * 4 + 3] = v.w;
                }
#pragma unroll
                for (int e = 0; e < 8; ++e) {
                    unsigned short hh = f2bf(f[e]);
                    ah[i][e] = (short)hh;
                    al[i][e] = (short)f2bf(f[e] - bf2f(hh));
                }
            }
        } else {
            int tap = k0 / CIP;
            int ci  = k0 & (CIP - 1);
#pragma unroll
            for (int i = 0; i < 2; ++i) {
                int ih, iw;
                if constexpr (MODE == 0) {
                    ih = 2 * asy[i] + (tap >> 2) - 1;
                    iw = 2 * asx[i] + (tap & 3) - 1;
                } else {
                    ih = asy[i] + p + (tap >> 1) - 1;
                    iw = asx[i] + q + (tap & 1) - 1;
                }
                bf16x8 zh, zl;
#pragma unroll
                for (int e = 0; e < 8; ++e) { zh[e] = 0; zl[e] = 0; }
                if ((unsigned)ih < (unsigned)HI && (unsigned)iw < (unsigned)WI) {
                    long off = (((long)ani[i] * HI + ih) * WI + iw) * CIP + ci;
                    zh = *(const bf16x8*)(Ahi + off);
                    zl = *(const bf16x8*)(Alo + off);
                }
                ah[i] = zh; al[i] = zl;
            }
        }
        bf16x8 bh[2], bl[2];
#pragma unroll
        for (int j = 0; j < 2; ++j) {
            long bidx = ((long)((nbase >> 4) + j) * K32 + (kb >> 5)) * 512 + lane * 8;
            bh[j] = *(const bf16x8*)(WBp + bidx);
            bl[j] = *(const bf16x8*)(WBp + PLANE + bidx);
        }
#pragma unroll
        for (int i = 0; i < 2; ++i)
#pragma unroll
            for (int j = 0; j < 2; ++j) {
                acc[i][j] = __builtin_amdgcn_mfma_f32_16x16x32_bf16(ah[i], bh[j], acc[i][j], 0, 0, 0);
                acc[i][j] = __builtin_amdgcn_mfma_f32_16x16x32_bf16(ah[i], bl[j], acc[i][j], 0, 0, 0);
                acc[i][j] = __builtin_amdgcn_mfma_f32_16x16x32_bf16(al[i], bh[j], acc[i][j], 0, 0, 0);
            }
    }

#pragma unroll
    for (int i = 0; i < 2; ++i)
#pragma unroll
        for (int j = 0; j < 2; ++j)
#pragma unroll
            for (int r = 0; r < 4; ++r) {
                int m = mbase + 16 * i + lg * 4 + r;
                int co = nbase + 16 * j + lm;
                float v = acc[i][j][r] + bias[co];
                v = fmaxf(v, 0.f);
                long off;
                if constexpr (MODE == 0) {
                    off = (long)m * CO + co;
                } else {
                    int ni = m / HWS; int rm = m % HWS;
                    int oy = 2 * (rm / SW) + p, ox = 2 * (rm % SW) + q;
                    off = (((long)ni * HO + oy) * WO + ox) * CO + co;
                }
                unsigned short hh = f2bf(v);
                Yhi[off] = hh;
                Ylo[off] = f2bf(v - bf2f(hh));
            }
}

// ====== dt4: LDS-tiled, CO=3, sigmoid, NCHW out (one block = n x 8 rows) ====
__global__ __launch_bounds__(256)
void dt4_tiled(const unsigned short* __restrict__ Xh, const unsigned short* __restrict__ Xl,
               const float4* __restrict__ Wd, const float* __restrict__ bias,
               float* __restrict__ out) {
    __shared__ float4 xt[8 * 341];  // [c4][341 padded], pos=(r*34+cc) in [0,340)
    int bid = blockIdx.x;
    int n = bid >> 2, yg = bid & 3;
    int y0 = yg * 8;
    int tid = threadIdx.x;
    long nb = (long)n * 32768;  // 32*32*32 channels-last
    for (int j = tid; j < 2720; j += 256) {   // 10 rows x 34 cols x 8 c4
        int c4 = j & 7; int pos = j >> 3;
        int r = pos / 34, cc = pos % 34;
        int ih = y0 - 1 + r, iw = cc - 1;
        float4 v = {0.f, 0.f, 0.f, 0.f};
        if ((unsigned)ih < 32u && (unsigned)iw < 32u)
            v = ld4bf(Xh, Xl, nb + ((long)ih * 32 + iw) * 32 + c4 * 4);
        xt[c4 * 341 + pos] = v;
    }
    __syncthreads();
    int ly = tid >> 5, lx = tid & 31;
    float acc[3][4];
#pragma unroll
    for (int j = 0; j < 3; ++j) {
        float b = bias[j];
#pragma unroll
        for (int par = 0; par < 4; ++par) acc[j][par] = b;
    }
#pragma unroll
    for (int ci4 = 0; ci4 < 8; ++ci4) {
        float4 xv[9];
        int base = ci4 * 341 + ly * 34 + lx;
#pragma unroll
        for (int r = 0; r < 3; ++r)
#pragma unroll
            for (int c = 0; c < 3; ++c)
                xv[r * 3 + c] = xt[base + r * 34 + c];
        const float4* wp = Wd + ci4 * 48;
#pragma unroll
        for (int j = 0; j < 3; ++j)
#pragma unroll
            for (int par = 0; par < 4; ++par) {
                int p = par >> 1, q = par & 1;
#pragma unroll
                for (int t4 = 0; t4 < 4; ++t4) {
                    int dh = t4 >> 1, dw = t4 & 1;
                    acc[j][par] += dot4(xv[(p + dh) * 3 + (q + dw)],
                                        wp[(j * 4 + par) * 4 + t4]);
                }
            }
    }
    int yy = y0 + ly, xx = lx;
#pragma unroll
    for (int j = 0; j < 3; ++j)
#pragma unroll
        for (int p = 0; p < 2; ++p) {
            float2 v;
            v.x = sig_(acc[j][p * 2 + 0]);
            v.y = sig_(acc[j][p * 2 + 1]);
            *(float2*)(out + (((long)n * 3 + j) * 64 + 2 * yy + p) * 64 + 2 * xx) = v;
        }
}

// ========================= weight / layout prep =============================
// conv OIHW -> fragment-packed hi/lo: [2][CO/16][K/32][64][8], k=tap*CIP+ci
template<int CIS, int CIP, int CO>
__global__ void pack_wb_conv(const float* __restrict__ w, unsigned short* __restrict__ out) {
    constexpr int K = CIP * 16;
    int idx = blockIdx.x * 256 + threadIdx.x;
    if (idx >= CO * K) return;
    int j = idx & 7, lane = (idx >> 3) & 63;
    int kb = (idx >> 9) % (K / 32), nt = idx / (512 * (K / 32));
    int k = kb * 32 + (lane >> 4) * 8 + j;
    int tap = k / CIP, ci = k & (CIP - 1);
    int co = nt * 16 + (lane & 15);
    float f = (ci < CIS) ? w[((long)co * CIS + ci) * 16 + tap] : 0.f;
    unsigned short hi = f2bf(f);
    out[idx] = hi;
    out[CO * K + idx] = f2bf(f - bf2f(hi));
}

// convT OIHW -> [par][2][CO/16][Kp/32][64][8], k=t4*CI+ci, tap=(p+2dh)*4+(q+2dw)
template<int CI, int CO>
__global__ void pack_wb_convt(const float* __restrict__ w, unsigned short* __restrict__ out) {
    constexpr int Kp = CI * 4;
    int idx = blockIdx.x * 256 + threadIdx.x;
    if (idx >= 4 * CO * Kp) return;
    int par = idx / (CO * Kp); int rem = idx % (CO * Kp);
    int j = rem & 7, lane = (rem >> 3) & 63;
    int kb = (rem >> 9) % (Kp / 32), nt = rem / (512 * (Kp / 32));
    int k = kb * 32 + (lane >> 4) * 8 + j;
    int t4 = k / CI, ci = k & (CI - 1);
    int p = par >> 1, q = par & 1, dh = t4 >> 1, dw = t4 & 1;
    int tap = (p + 2 * dh) * 4 + (q + 2 * dw);
    int co = nt * 16 + (lane & 15);
    float f = w[((long)co * CI + ci) * 16 + tap];
    unsigned short hi = f2bf(f);
    out[(long)par * 2 * CO * Kp + rem] = hi;
    out[(long)par * 2 * CO * Kp + CO * Kp + rem] = f2bf(f - bf2f(hi));
}

// merged tail prep: WBe1 pack + WBe2 pack + WBd3 pack + WTd4 perm (266 blocks)
__global__ void prep_tail(const float* __restrict__ ec1_w, const float* __restrict__ ec2_w,
                          const float* __restrict__ dt3_w, const float* __restrict__ dt4_w,
                          unsigned short* __restrict__ WBe1, unsigned short* __restrict__ WBe2,
                          unsigned short* __restrict__ WBd3, float4* __restrict__ WTd4) {
    int idx = blockIdx.x * 256 + threadIdx.x;
    if (idx < 2048) {  // ec1: CIS=3 CIP=4 CO=32 K=64
        int li = idx;
        int j = li & 7, lane = (li >> 3) & 63;
        int kb = (li >> 9) & 1, nt = li / 1024;
        int k = kb * 32 + (lane >> 4) * 8 + j;
        int tap = k >> 2, ci = k & 3;
        int co = nt * 16 + (lane & 15);
        float f = (ci < 3) ? ec1_w[((long)co * 3 + ci) * 16 + tap] : 0.f;
        unsigned short hi = f2bf(f);
        WBe1[li] = hi; WBe1[2048 + li] = f2bf(f - bf2f(hi));
    } else if (idx < 34816) {  // ec2: CI=32 CO=64 K=512
        int li = idx - 2048;
        int j = li & 7, lane = (li >> 3) & 63;
        int kb = (li >> 9) & 15, nt = li / 8192;
        int k = kb * 32 + (lane >> 4) * 8 + j;
        int tap = k >> 5, ci = k & 31;
        int co = nt * 16 + (lane & 15);
        float f = ec2_w[((long)co * 32 + ci) * 16 + tap];
        unsigned short hi = f2bf(f);
        WBe2[li] = hi; WBe2[32768 + li] = f2bf(f - bf2f(hi));
    } else if (idx < 67584) {  // dt3 convT: CI=64 CO=32 Kp=256
        int li = idx - 34816;
        int par = li >> 13; int rem = li & 8191;
        int j = rem & 7, lane = (rem >> 3) & 63;
        int kb = (rem >> 9) & 7, nt = rem >> 12;
        int k = kb * 32 + (lane >> 4) * 8 + j;
        int t4 = k >> 6, ci = k & 63;
        int p = par >> 1, q = par & 1, dh = t4 >> 1, dw = t4 & 1;
        int tap = (p + 2 * dh) * 4 + (q + 2 * dw);
        int co = nt * 16 + (lane & 15);
        float f = dt3_w[((long)co * 64 + ci) * 16 + tap];
        unsigned short hi = f2bf(f);
        WBd3[par * 16384 + rem] = hi;
        WBd3[par * 16384 + 8192 + rem] = f2bf(f - bf2f(hi));
    } else if (idx < 67968) {  // dt4 dirwT: CI=32 CO=3 -> 384 float4
        int li = idx - 67584;
        int t4 = li & 3, par = (li >> 2) & 3;
        int co = (li >> 4) % 3, ci4 = (li >> 4) / 3;
        int p = par >> 1, q = par & 1, dh = t4 >> 1, dw = t4 & 1;
        int tap = (p + 2 * dh) * 4 + (q + 2 * dw);
        float4 v; float* pv = (float*)&v;
#pragma unroll
        for (int l = 0; l < 4; ++l)
            pv[l] = dt4_w[((long)co * 32 + ci4 * 4 + l) * 16 + tap];
        WTd4[li] = v;
    }
}

// merged R1 prep: wihE/wihD perms + fc transp + biasdc + fcmu/dfc perms
__global__ void prep_r1(const float* __restrict__ wih_e, const float* __restrict__ wih_d,
                        const float* __restrict__ fc_w,
                        const float* __restrict__ bih_d, const float* __restrict__ bhh_d,
                        const float* __restrict__ fc_b,
                        const float* __restrict__ fcmu_w, const float* __restrict__ dfc_w,
                        const float* __restrict__ dfc_b,
                        float* __restrict__ WIHP_E, float* __restrict__ WIHP_D,
                        float* __restrict__ FCP, float* __restrict__ BIASDC,
                        float* __restrict__ FCMUP, float* __restrict__ DFCP,
                        float* __restrict__ DFCB) {
    int idx = blockIdx.x * 256 + threadIdx.x;
    if (idx < 262144) {
        int c = idx & 2047, m = idx >> 11;
        WIHP_E[idx] = wih_e[orig_row(c) * 128 + m];
    } else if (idx < 524288) {
        int li = idx - 262144;
        int c = li & 2047, m = li >> 11;
        WIHP_D[li] = wih_d[orig_row(c) * 128 + m];
    } else if (idx < 589824) {
        int li = idx - 524288;
        int r = li & 127, c = li >> 7;
        FCP[li] = fc_w[(long)r * 512 + c];
    } else if (idx < 591872) {
        int c = idx - 589824;
        int orow = orig_row(c);
        float s = bih_d[orow] + bhh_d[orow];
        for (int m = 0; m < 128; ++m) s += fc_b[m] * wih_d[orow * 128 + m];
        BIASDC[c] = s;
    } else if (idx < 1116160) {
        int li = idx - 591872;
        int j = li & 127, k = li >> 7;
        FCMUP[li] = fcmu_w[(long)j * 4096 + (k & 255) * 16 + (k >> 8)];
    } else {
        int li = idx - 1116160;
        int j = li & 4095, m = li >> 12;
        int jc = (j & 255) * 16 + (j >> 8);
        DFCP[li] = dfc_w[(long)jc * 128 + m];
        if (li < 4096) DFCB[li] = dfc_b[(li & 255) * 16 + (li >> 8)];
    }
}

// video NCHW -> NHWC4 fp32 (float4 stores)
__global__ void to_nhwc4v(const float* __restrict__ v, float4* __restrict__ out) {
    int idx = blockIdx.x * 256 + threadIdx.x;  // 1,048,576
    int w = idx & 63, h = (idx >> 6) & 63, n = idx >> 12;
    long base = (long)n * 12288 + h * 64 + w;
    float4 o;
    o.x = v[base];
    o.y = v[base + 4096];
    o.z = v[base + 8192];
    o.w = 0.f;
    out[idx] = o;
}

__global__ void pack_whh(const float* __restrict__ whh, float4* __restrict__ out) {
    int idx = blockIdx.x * 256 + threadIdx.x;  // 262144
    int c = idx & 2047, k4 = idx >> 11;
    const float4* src = (const float4*)(whh + orig_row(c) * 512);
    out[idx] = src[k4];
}

__global__ __launch_bounds__(256)
void merge_dc(const float* __restrict__ wih_d, const float* __restrict__ fc_w,
              const float* __restrict__ whh_d, float* __restrict__ out) {
    int cb = (blockIdx.x >> 3) * 64, kb = (blockIdx.x & 7) * 64;
    int tid = threadIdx.x;
    int cgl = (tid & 15) * 4, kgl = (tid >> 4) * 4;
    __shared__ float At[64][65];
    __shared__ float Bt[64][65];
    float acc[4][4] = {};
    for (int mc = 0; mc < 128; mc += 64) {
        __syncthreads();
        for (int i = tid; i < 4096; i += 256) {
            int cl = i >> 6, m = i & 63;
            At[cl][m] = wih_d[orig_row(cb + cl) * 128 + mc + m];
            Bt[cl][m] = fc_w[(mc + cl) * 512 + kb + m];
        }
        __syncthreads();
        for (int m = 0; m < 64; ++m) {
            float a[4], b[4];
#pragma unroll
            for (int i = 0; i < 4; ++i) { a[i] = At[cgl + i][m]; b[i] = Bt[m][kgl + i]; }
#pragma unroll
            for (int i = 0; i < 4; ++i)
#pragma unroll
                for (int j = 0; j < 4; ++j) acc[i][j] += a[i] * b[j];
        }
    }
    for (int i = 0; i < 4; ++i) {
        int c = cb + cgl + i; int orow = orig_row(c);
        for (int j = 0; j < 4; ++j) {
            int k = kb + kgl + j;
            out[((k >> 2) * 2048 + c) * 4 + (k & 3)] = acc[i][j] + whh_d[orow * 512 + k];
        }
    }
}

// ============================ LSTM / FC path ================================
// merged gx: blocks 0-63 encoder (all 16 t), blocks 64-67 decoder step-0 x
__global__ __launch_bounds__(512)
void gx2_kernel(const float* __restrict__ Z,
                const float* __restrict__ wE, const float* __restrict__ biE,
                const float* __restrict__ bhE,
                const float* __restrict__ wD, const float* __restrict__ biD,
                const float* __restrict__ bhD,
                float* __restrict__ gxe, float* __restrict__ gxd0) {
    __shared__ float zl[2048];
    int bid = blockIdx.x, tid = threadIdx.x;
    if (bid < 64) {
        int rg = bid >> 2, cch = bid & 3;
        for (int i = tid; i < 2048; i += 512)
            zl[i] = Z[(long)(rg * 16 + (i >> 7)) * 128 + (i & 127)];
        __syncthreads();
        int c = cch * 512 + tid;
        int orow = orig_row(c);
        float bsum = biE[orow] + bhE[orow];
        float acc[16];
#pragma unroll
        for (int r = 0; r < 16; ++r) acc[r] = bsum;
        for (int m = 0; m < 128; ++m) {
            float wv = wE[m * 2048 + c];
#pragma unroll
            for (int r = 0; r < 16; ++r) acc[r] += zl[r * 128 + m] * wv;
        }
        for (int r = 0; r < 16; ++r) gxe[(long)(rg * 16 + r) * 2048 + c] = acc[r];
    } else {
        int cch = bid - 64;
        for (int i = tid; i < 2048; i += 512)
            zl[i] = Z[(long)((i >> 7) * 16 + 15) * 128 + (i & 127)];
        __syncthreads();
        int c = cch * 512 + tid;
        int orow = orig_row(c);
        float bsum = biD[orow] + bhD[orow];
        float acc[16];
#pragma unroll
        for (int r = 0; r < 16; ++r) acc[r] = bsum;
        for (int m = 0; m < 128; ++m) {
            float wv = wD[m * 2048 + c];
#pragma unroll
            for (int r = 0; r < 16; ++r) acc[r] += zl[r * 128 + m] * wv;
        }
        for (int r = 0; r < 16; ++r) gxd0[(long)r * 2048 + c] = acc[r];
    }
}

__global__ __launch_bounds__(512)
void lstm_step(const float4* __restrict__ wh4, const float* __restrict__ gadd,
               int gstride, const float* __restrict__ h_in, float* __restrict__ h_out,
               float* __restrict__ cst, float* __restrict__ hall) {
    __shared__ float hs[8192];
    __shared__ float gb[16][32];
    int tid = threadIdx.x;
    float4* hs4 = (float4*)hs;
    const float4* hi4 = (const float4*)h_in;
#pragma unroll
    for (int i = 0; i < 4; ++i) hs4[tid + 512 * i] = hi4[tid + 512 * i];
    __syncthreads();
    int col = tid & 31, n = tid >> 5;
    int cg = blockIdx.x * 32 + col;
    float acc = gadd[n * gstride + cg];
    const float4* wp = wh4 + cg;
    const float4* hv = (const float4*)(hs + n * 512);
#pragma unroll 8
    for (int k4 = 0; k4 < 128; ++k4) {
        float4 wv = wp[(long)k4 * 2048];
        float4 h4 = hv[k4];
        acc += wv.x * h4.x + wv.y * h4.y + wv.z * h4.z + wv.w * h4.w;
    }
    gb[n][col] = acc;
    __syncthreads();
    if (col < 8) {
        int j = blockIdx.x * 8 + col;
        float gi = sig_(gb[n][col]);
        float gf = sig_(gb[n][col + 8]);
        float gg = tanhf(gb[n][col + 16]);
        float go = sig_(gb[n][col + 24]);
        int idx = n * 512 + j;
        float cv = gf * cst[idx] + gi * gg;
        cst[idx] = cv;
        float hvv = go * tanhf(cv);
        h_out[idx] = hvv;
        if (hall) hall[idx] = hvv;
    }
}

__global__ __launch_bounds__(512)
void fcmu_part(const unsigned short* __restrict__ xh, const unsigned short* __restrict__ xl,
               const float* __restrict__ wP, float* __restrict__ part) {
    int rg = blockIdx.x >> 3, ks = blockIdx.x & 7;
    int tid = threadIdx.x;
    __shared__ float xls[16 * 512];
    for (int i = tid; i < 8192; i += 512) {
        long gi = (long)(rg * 16 + (i >> 9)) * 4096 + ks * 512 + (i & 511);
        xls[i] = bf2f(xh[gi]) + bf2f(xl[gi]);
    }
    __syncthreads();
    int j = tid & 127, rq = tid >> 7;
    float acc[4] = {0, 0, 0, 0};
    for (int k = 0; k < 512; ++k) {
        float wv = wP[(ks * 512 + k) * 128 + j];
#pragma unroll
        for (int i = 0; i < 4; ++i) acc[i] += xls[(rq + 4 * i) * 512 + k] * wv;
    }
    for (int i = 0; i < 4; ++i)
        part[((long)ks * 256 + rg * 16 + rq + 4 * i) * 128 + j] = acc[i];
}

__global__ void fcmu_red(const float* __restrict__ part, const float* __restrict__ b,
                         float* __restrict__ z) {
    int idx = blockIdx.x * 256 + threadIdx.x;  // 32768
    float s = b[idx & 127];
    for (int k = 0; k < 8; ++k) s += part[k * 32768 + idx];
    z[idx] = s;
}

__global__ __launch_bounds__(512)
void zs_k(const float* __restrict__ hall, const float* __restrict__ fcP,
          const float* __restrict__ fcb, float* __restrict__ zs) {
    int t = blockIdx.x;
    int tid = threadIdx.x;
    __shared__ float hs[8192];
    const float* h = hall + t * 8192;
    for (int i = tid; i < 8192; i += 512) hs[i] = h[i];
    __syncthreads();
    int j = tid & 127, ng = tid >> 7;
    float acc[4] = {0, 0, 0, 0};
    for (int k = 0; k < 512; ++k) {
        float wv = fcP[k * 128 + j];
#pragma unroll
        for (int i = 0; i < 4; ++i) acc[i] += hs[(ng + 4 * i) * 512 + k] * wv;
    }
    float bv = fcb[j];
    for (int i = 0; i < 4; ++i)
        zs[((ng + 4 * i) * 16 + t) * 128 + j] = acc[i] + bv;
}

__global__ __launch_bounds__(512)
void dfc_k(const float* __restrict__ zs, const float* __restrict__ dP,
           const float* __restrict__ db,
           unsigned short* __restrict__ outh, unsigned short* __restrict__ outl) {
    int rg = blockIdx.x >> 3, jc = blockIdx.x & 7;
    int tid = threadIdx.x;
    __shared__ float zl[16 * 128];
    for (int i = tid; i < 2048; i += 512) zl[i] = zs[(long)rg * 2048 + i];
    __syncthreads();
    int j = jc * 512 + tid;
    float acc[16];
#pragma unroll
    for (int r = 0; r < 16; ++r) acc[r] = 0.f;
    for (int m = 0; m < 128; ++m) {
        float wv = dP[(long)m * 4096 + j];
#pragma unroll
        for (int r = 0; r < 16; ++r) acc[r] += zl[r * 128 + m] * wv;
    }
    float bv = db[j];
    for (int r = 0; r < 16; ++r) {
        float v = fmaxf(acc[r] + bv, 0.f);
        long idx = (long)(rg * 16 + r) * 4096 + j;
        unsigned short hh = f2bf(v);
        outh[idx] = hh;
        outl[idx] = f2bf(v - bf2f(hh));
    }
}

extern "C" void kernel_launch(void* const* d_in, const int* in_sizes, int n_in,
                              void* d_out, int out_size, void* d_ws, size_t ws_size,
                              hipStream_t stream) {
    (void)in_sizes; (void)n_in; (void)out_size; (void)ws_size;
    const float* video  = (const float*)d_in[0];
    const float* ec1_w  = (const float*)d_in[2];  const float* ec1_b = (const float*)d_in[3];
    const float* ec2_w  = (const float*)d_in[4];  const float* ec2_b = (const float*)d_in[5];
    const float* ec3_w  = (const float*)d_in[6];  const float* ec3_b = (const float*)d_in[7];
    const float* ec4_w  = (const float*)d_in[8];  const float* ec4_b = (const float*)d_in[9];
    const float* fcmu_w = (const float*)d_in[10]; const float* fcmu_b = (const float*)d_in[11];
    const float* dfc_w  = (const float*)d_in[12]; const float* dfc_b = (const float*)d_in[13];
    const float* dt1_w  = (const float*)d_in[14]; const float* dt1_b = (const float*)d_in[15];
    const float* dt2_w  = (const float*)d_in[16]; const float* dt2_b = (const float*)d_in[17];
    const float* dt3_w  = (const float*)d_in[18]; const float* dt3_b = (const float*)d_in[19];
    const float* dt4_w  = (const float*)d_in[20]; const float* dt4_b = (const float*)d_in[21];
    const float* wih_e  = (const float*)d_in[22]; const float* whh_e = (const float*)d_in[23];
    const float* bih_e  = (const float*)d_in[24]; const float* bhh_e = (const float*)d_in[25];
    const float* wih_d  = (const float*)d_in[26]; const float* whh_d = (const float*)d_in[27];
    const float* bih_d  = (const float*)d_in[28]; const float* bhh_d = (const float*)d_in[29];
    const float* fc_w   = (const float*)d_in[30]; const float* fc_b  = (const float*)d_in[31];

    char* wsb = (char*)d_ws;
    unsigned short* B1h = (unsigned short*)wsb;
    unsigned short* B1l = B1h + 8388608;
    float*          X0f = (float*)(wsb + 33554432);
    unsigned short* B2h = (unsigned short*)(wsb + 33554432);
    unsigned short* B2l = B2h + 4194304;
    unsigned short* B3h = (unsigned short*)(wsb + 50331648);
    unsigned short* B3l = B3h + 2097152;
    unsigned short* B4h = (unsigned short*)(wsb + 58720256);
    unsigned short* B4l = B4h + 1048576;
    float* R1f    = (float*)wsb;
    float* WH4_E  = R1f;
    float* WH4_DC = R1f + 1048576;
    float* WIHP_E = R1f + 2097152;
    float* WIHP_D = R1f + 2359296;
    float* GX_E   = R1f + 2621440;
    float* GX_D0  = R1f + 3145728;
    float* BIASDC = R1f + 3178496;
    float* HA     = R1f + 3180544;
    float* HB     = R1f + 3188736;
    float* CB     = R1f + 3196928;
    float* HALL   = R1f + 3205120;
    float* FCMUP  = R1f + 3336192;
    float* ZPART  = R1f + 3860480;
    float* FCP    = R1f + 4122624;
    float* DFCP   = R1f + 4188160;
    float* DFCB   = R1f + 4712448;
    float* Z      = R1f + 4716544;
    float* ZS     = R1f + 4749312;
    unsigned short* WBe3 = (unsigned short*)(R1f + 4782080);
    unsigned short* WBe4 = (unsigned short*)(R1f + 4913152);
    unsigned short* WBd1 = (unsigned short*)(R1f + 5437440);
    unsigned short* WBd2 = (unsigned short*)(R1f + 5961728);
    unsigned short* WBe1 = (unsigned short*)(wsb + 62914560);
    unsigned short* WBe2 = (unsigned short*)(wsb + 62922752);
    unsigned short* WBd3 = (unsigned short*)(wsb + 63053824);
    float*          WTd4 = (float*)(wsb + 63184896);

    // ---- merged tail prep + encoder ec1/ec2 ----
    prep_tail<<<266, 256, 0, stream>>>(ec1_w, ec2_w, dt3_w, dt4_w,
                                       WBe1, WBe2, WBd3, (float4*)WTd4);
    to_nhwc4v<<<4096, 256, 0, stream>>>(video, (float4*)X0f);
    conv_mfma<4, 64, 64, 32, 4, 1, 0, 1><<<2048, 256, 0, stream>>>(
        nullptr, nullptr, X0f, WBe1, ec1_b, B1h, B1l);
    conv_mfma<32, 32, 32, 64, 2, 2, 0, 0><<<1024, 256, 0, stream>>>(
        B1h, B1l, nullptr, WBe2, ec2_b, B2h, B2l);

    // ---- R1 free: merged prep + big packs ----
    prep_r1<<<6408, 256, 0, stream>>>(wih_e, wih_d, fc_w, bih_d, bhh_d, fc_b,
                                      fcmu_w, dfc_w, dfc_b,
                                      WIHP_E, WIHP_D, FCP, BIASDC, FCMUP, DFCP, DFCB);
    pack_wb_conv<64, 64, 128><<<512, 256, 0, stream>>>(ec3_w, WBe3);
    pack_wb_conv<128, 128, 256><<<2048, 256, 0, stream>>>(ec4_w, WBe4);
    pack_wb_convt<256, 128><<<2048, 256, 0, stream>>>(dt1_w, WBd1);
    pack_wb_convt<128, 64><<<512, 256, 0, stream>>>(dt2_w, WBd2);
    pack_whh<<<1024, 256, 0, stream>>>(whh_e, (float4*)WH4_E);
    merge_dc<<<256, 256, 0, stream>>>(wih_d, fc_w, whh_d, WH4_DC);
    hipMemsetAsync(HA, 0, 3 * 8192 * sizeof(float), stream);

    // ---- encoder ec3/ec4 + fcmu ----
    conv_mfma<64, 16, 16, 128, 2, 2, 0, 0><<<512, 256, 0, stream>>>(
        B2h, B2l, nullptr, WBe3, ec3_b, B3h, B3l);
    conv_mfma<128, 8, 8, 256, 2, 2, 0, 0><<<256, 256, 0, stream>>>(
        B3h, B3l, nullptr, WBe4, ec4_b, B4h, B4l);
    fcmu_part<<<128, 512, 0, stream>>>(B4h, B4l, FCMUP, ZPART);
    fcmu_red<<<128, 256, 0, stream>>>(ZPART, fcmu_b, Z);

    // ---- merged x projections ----
    gx2_kernel<<<68, 512, 0, stream>>>(Z, WIHP_E, bih_e, bhh_e,
                                       WIHP_D, bih_d, bhh_d, GX_E, GX_D0);

    // ---- LSTM chains (per-step launches; coop grid-sync measured 5x slower) ----
    float* hin = HA; float* hout = HB;
    for (int t = 0; t < 16; ++t) {
        lstm_step<<<64, 512, 0, stream>>>((const float4*)WH4_E, GX_E + t * 2048, 32768,
                                          hin, hout, CB, (float*)nullptr);
        float* tmp = hin; hin = hout; hout = tmp;
    }
    pack_whh<<<1024, 256, 0, stream>>>(whh_d, (float4*)WH4_E);  // reuse for dec step 0
    lstm_step<<<64, 512, 0, stream>>>((const float4*)WH4_E, GX_D0, 2048,
                                      hin, hout, CB, HALL);
    { float* tmp = hin; hin = hout; hout = tmp; }
    for (int t = 1; t < 16; ++t) {
        lstm_step<<<64, 512, 0, stream>>>((const float4*)WH4_DC, BIASDC, 0,
                                          hin, hout, CB, HALL + t * 8192);
        float* tmp = hin; hin = hout; hout = tmp;
    }
    zs_k<<<16, 512, 0, stream>>>(HALL, FCP, fc_b, ZS);

    // ---- decoder ----
    dfc_k<<<128, 512, 0, stream>>>(ZS, DFCP, DFCB, B4h, B4l);
    conv_mfma<256, 4, 4, 128, 2, 2, 1, 0><<<512, 256, 0, stream>>>(
        B4h, B4l, nullptr, WBd1, dt1_b, B3h, B3l);
    conv_mfma<128, 8, 8, 64, 2, 2, 1, 0><<<1024, 256, 0, stream>>>(
        B3h, B3l, nullptr, WBd2, dt2_b, B2h, B2l);
    conv_mfma<64, 16, 16, 32, 4, 1, 1, 0><<<2048, 256, 0, stream>>>(
        B2h, B2l, nullptr, WBd3, dt3_b, B1h, B1l);
    dt4_tiled<<<1024, 256, 0, stream>>>(B1h, B1l, (const float4*)WTd4, dt4_b, (float*)d_out);
}

// Round 9
// 705.254 us; speedup vs baseline: 3.5521x; 1.1169x over previous
//
#include <hip/hip_runtime.h>
#include <math.h>

// ---------------------------------------------------------------------------
// CNN-LSTM video predictor, round 9: conv activations single-bf16 (lo plane
// dropped; weights stay hi+lo split => 2 MFMAs/tile), MREP=2 wave tiles.
// LSTM/FC recurrent path stays fp32. dt4 LDS-tiled.
// ---------------------------------------------------------------------------

typedef float f32x4 __attribute__((ext_vector_type(4)));
typedef short bf16x8 __attribute__((ext_vector_type(8)));

__device__ __forceinline__ float sig_(float x) { return 1.f / (1.f + expf(-x)); }
__device__ __forceinline__ float dot4(float4 a, float4 b) {
    return a.x * b.x + a.y * b.y + a.z * b.z + a.w * b.w;
}
__device__ __forceinline__ int orig_row(int c) {
    return ((c >> 3) & 3) * 512 + (c >> 5) * 8 + (c & 7);
}
__device__ __forceinline__ unsigned short f2bf(float f) {
    unsigned int b = __float_as_uint(f);
    return (unsigned short)((b + 0x7fffu + ((b >> 16) & 1u)) >> 16);
}
__device__ __forceinline__ float bf2f(unsigned short h) {
    return __uint_as_float(((unsigned int)h) << 16);
}
// load 4 fp32 from single bf16 plane (8B aligned)
__device__ __forceinline__ float4 ld4bf1(const unsigned short* hp, long off) {
    uint2 h = *(const uint2*)(hp + off);
    float4 r;
    r.x = __uint_as_float((h.x & 0xffffu) << 16);
    r.y = __uint_as_float(h.x & 0xffff0000u);
    r.z = __uint_as_float((h.y & 0xffffu) << 16);
    r.w = __uint_as_float(h.y & 0xffff0000u);
    return r;
}

// =================== MFMA conv / convT (A bf16, W split) ====================
// MODE 0: conv s2 k4 p1 (K = CIP*16). MODE 1: convT parity (K = CIP*4).
// SRCF32=1 (ec1): A from fp32 NHWC4 with on-the-fly bf16 round.
// Wave tile: (32*MREP) x 32. 2 MFMAs per 16x16 subtile (ah*bh + ah*bl).
template<int CIP, int HI, int WI, int CO, int MREP, int WM, int WN, int MODE, int SRCF32>
__global__ __launch_bounds__(64 * WM * WN)
void conv_mfma(const unsigned short* __restrict__ Ahi, const float* __restrict__ Af,
               const unsigned short* __restrict__ WB, const float* __restrict__ bias,
               unsigned short* __restrict__ Yhi) {
    constexpr int K   = CIP * (MODE ? 4 : 16);
    constexpr int K32 = K / 32;
    constexpr int NI  = 2 * MREP;
    constexpr int HO  = MODE ? HI * 2 : HI / 2;
    constexpr int WO  = MODE ? WI * 2 : WI / 2;
    constexpr int SH  = MODE ? HI : HI / 2;
    constexpr int SW  = MODE ? WI : WI / 2;
    constexpr int HWS = SH * SW;
    constexpr int MT  = (256 * HWS) / (32 * MREP * WM);
    constexpr int NT  = CO / (32 * WN);
    constexpr int PLANE = CO * K;

    int bid = blockIdx.x;
    int mt = bid % MT; bid /= MT;
    int nt = bid % NT; int par = bid / NT;
    int p = par >> 1, q = par & 1;

    int tid = threadIdx.x;
    int lane = tid & 63, wid = tid >> 6;
    int wm = wid % WM, wn = wid / WM;
    int mbase = mt * (32 * MREP * WM) + wm * (32 * MREP);
    int nbase = nt * (32 * WN) + wn * 32;
    int lm = lane & 15, lg = lane >> 4;

    int ani[NI], asy[NI], asx[NI];
#pragma unroll
    for (int i = 0; i < NI; ++i) {
        int m = mbase + 16 * i + lm;
        ani[i] = m / HWS; int r = m % HWS; asy[i] = r / SW; asx[i] = r % SW;
    }

    f32x4 acc[NI][2];
#pragma unroll
    for (int i = 0; i < NI; ++i)
#pragma unroll
        for (int j = 0; j < 2; ++j)
#pragma unroll
            for (int e = 0; e < 4; ++e) acc[i][j][e] = 0.f;

    const unsigned short* WBp = WB + (long)par * 2 * PLANE;

    for (int kb = 0; kb < K; kb += 32) {
        int k0 = kb + lg * 8;
        bf16x8 ah[NI];
        if constexpr (SRCF32) {
            int t0 = k0 >> 2;
#pragma unroll
            for (int i = 0; i < NI; ++i) {
                float f[8];
#pragma unroll
                for (int h = 0; h < 2; ++h) {
                    int tap = t0 + h;
                    int ih = 2 * asy[i] + (tap >> 2) - 1;
                    int iw = 2 * asx[i] + (tap & 3) - 1;
                    float4 v = {0.f, 0.f, 0.f, 0.f};
                    if ((unsigned)ih < (unsigned)HI && (unsigned)iw < (unsigned)WI)
                        v = *(const float4*)(Af + (((long)ani[i] * HI + ih) * WI + iw) * 4);
                    f[h * 4 + 0] = v.x; f[h * 4 + 1] = v.y;
                    f[h * 4 + 2] = v.z; f[h * 4 + 3] = v.w;
                }
#pragma unroll
                for (int e = 0; e < 8; ++e) ah[i][e] = (short)f2bf(f[e]);
            }
        } else {
            int tap = k0 / CIP;
            int ci  = k0 & (CIP - 1);
#pragma unroll
            for (int i = 0; i < NI; ++i) {
                int ih, iw;
                if constexpr (MODE == 0) {
                    ih = 2 * asy[i] + (tap >> 2) - 1;
                    iw = 2 * asx[i] + (tap & 3) - 1;
                } else {
                    ih = asy[i] + p + (tap >> 1) - 1;
                    iw = asx[i] + q + (tap & 1) - 1;
                }
                bf16x8 zh;
#pragma unroll
                for (int e = 0; e < 8; ++e) zh[e] = 0;
                if ((unsigned)ih < (unsigned)HI && (unsigned)iw < (unsigned)WI) {
                    long off = (((long)ani[i] * HI + ih) * WI + iw) * CIP + ci;
                    zh = *(const bf16x8*)(Ahi + off);
                }
                ah[i] = zh;
            }
        }
        bf16x8 bh[2], bl[2];
#pragma unroll
        for (int j = 0; j < 2; ++j) {
            long bidx = ((long)((nbase >> 4) + j) * K32 + (kb >> 5)) * 512 + lane * 8;
            bh[j] = *(const bf16x8*)(WBp + bidx);
            bl[j] = *(const bf16x8*)(WBp + PLANE + bidx);
        }
#pragma unroll
        for (int i = 0; i < NI; ++i)
#pragma unroll
            for (int j = 0; j < 2; ++j) {
                acc[i][j] = __builtin_amdgcn_mfma_f32_16x16x32_bf16(ah[i], bh[j], acc[i][j], 0, 0, 0);
                acc[i][j] = __builtin_amdgcn_mfma_f32_16x16x32_bf16(ah[i], bl[j], acc[i][j], 0, 0, 0);
            }
    }

#pragma unroll
    for (int i = 0; i < NI; ++i)
#pragma unroll
        for (int j = 0; j < 2; ++j)
#pragma unroll
            for (int r = 0; r < 4; ++r) {
                int m = mbase + 16 * i + lg * 4 + r;
                int co = nbase + 16 * j + lm;
                float v = fmaxf(acc[i][j][r] + bias[co], 0.f);
                long off;
                if constexpr (MODE == 0) {
                    off = (long)m * CO + co;
                } else {
                    int ni = m / HWS; int rm = m % HWS;
                    int oy = 2 * (rm / SW) + p, ox = 2 * (rm % SW) + q;
                    off = (((long)ni * HO + oy) * WO + ox) * CO + co;
                }
                Yhi[off] = f2bf(v);
            }
}

// ====== dt4: LDS-tiled, CO=3, sigmoid, NCHW out (one block = n x 8 rows) ====
__global__ __launch_bounds__(256)
void dt4_tiled(const unsigned short* __restrict__ Xh,
               const float4* __restrict__ Wd, const float* __restrict__ bias,
               float* __restrict__ out) {
    __shared__ float4 xt[8 * 341];
    int bid = blockIdx.x;
    int n = bid >> 2, yg = bid & 3;
    int y0 = yg * 8;
    int tid = threadIdx.x;
    long nb = (long)n * 32768;
    for (int j = tid; j < 2720; j += 256) {
        int c4 = j & 7; int pos = j >> 3;
        int r = pos / 34, cc = pos % 34;
        int ih = y0 - 1 + r, iw = cc - 1;
        float4 v = {0.f, 0.f, 0.f, 0.f};
        if ((unsigned)ih < 32u && (unsigned)iw < 32u)
            v = ld4bf1(Xh, nb + ((long)ih * 32 + iw) * 32 + c4 * 4);
        xt[c4 * 341 + pos] = v;
    }
    __syncthreads();
    int ly = tid >> 5, lx = tid & 31;
    float acc[3][4];
#pragma unroll
    for (int j = 0; j < 3; ++j) {
        float b = bias[j];
#pragma unroll
        for (int par = 0; par < 4; ++par) acc[j][par] = b;
    }
#pragma unroll
    for (int ci4 = 0; ci4 < 8; ++ci4) {
        float4 xv[9];
        int base = ci4 * 341 + ly * 34 + lx;
#pragma unroll
        for (int r = 0; r < 3; ++r)
#pragma unroll
            for (int c = 0; c < 3; ++c)
                xv[r * 3 + c] = xt[base + r * 34 + c];
        const float4* wp = Wd + ci4 * 48;
#pragma unroll
        for (int j = 0; j < 3; ++j)
#pragma unroll
            for (int par = 0; par < 4; ++par) {
                int p = par >> 1, q = par & 1;
#pragma unroll
                for (int t4 = 0; t4 < 4; ++t4) {
                    int dh = t4 >> 1, dw = t4 & 1;
                    acc[j][par] += dot4(xv[(p + dh) * 3 + (q + dw)],
                                        wp[(j * 4 + par) * 4 + t4]);
                }
            }
    }
    int yy = y0 + ly, xx = lx;
#pragma unroll
    for (int j = 0; j < 3; ++j)
#pragma unroll
        for (int p = 0; p < 2; ++p) {
            float2 v;
            v.x = sig_(acc[j][p * 2 + 0]);
            v.y = sig_(acc[j][p * 2 + 1]);
            *(float2*)(out + (((long)n * 3 + j) * 64 + 2 * yy + p) * 64 + 2 * xx) = v;
        }
}

// ========================= weight / layout prep =============================
template<int CIS, int CIP, int CO>
__global__ void pack_wb_conv(const float* __restrict__ w, unsigned short* __restrict__ out) {
    constexpr int K = CIP * 16;
    int idx = blockIdx.x * 256 + threadIdx.x;
    if (idx >= CO * K) return;
    int j = idx & 7, lane = (idx >> 3) & 63;
    int kb = (idx >> 9) % (K / 32), nt = idx / (512 * (K / 32));
    int k = kb * 32 + (lane >> 4) * 8 + j;
    int tap = k / CIP, ci = k & (CIP - 1);
    int co = nt * 16 + (lane & 15);
    float f = (ci < CIS) ? w[((long)co * CIS + ci) * 16 + tap] : 0.f;
    unsigned short hi = f2bf(f);
    out[idx] = hi;
    out[CO * K + idx] = f2bf(f - bf2f(hi));
}

template<int CI, int CO>
__global__ void pack_wb_convt(const float* __restrict__ w, unsigned short* __restrict__ out) {
    constexpr int Kp = CI * 4;
    int idx = blockIdx.x * 256 + threadIdx.x;
    if (idx >= 4 * CO * Kp) return;
    int par = idx / (CO * Kp); int rem = idx % (CO * Kp);
    int j = rem & 7, lane = (rem >> 3) & 63;
    int kb = (rem >> 9) % (Kp / 32), nt = rem / (512 * (Kp / 32));
    int k = kb * 32 + (lane >> 4) * 8 + j;
    int t4 = k / CI, ci = k & (CI - 1);
    int p = par >> 1, q = par & 1, dh = t4 >> 1, dw = t4 & 1;
    int tap = (p + 2 * dh) * 4 + (q + 2 * dw);
    int co = nt * 16 + (lane & 15);
    float f = w[((long)co * CI + ci) * 16 + tap];
    unsigned short hi = f2bf(f);
    out[(long)par * 2 * CO * Kp + rem] = hi;
    out[(long)par * 2 * CO * Kp + CO * Kp + rem] = f2bf(f - bf2f(hi));
}

__global__ void prep_tail(const float* __restrict__ ec1_w, const float* __restrict__ ec2_w,
                          const float* __restrict__ dt3_w, const float* __restrict__ dt4_w,
                          unsigned short* __restrict__ WBe1, unsigned short* __restrict__ WBe2,
                          unsigned short* __restrict__ WBd3, float4* __restrict__ WTd4) {
    int idx = blockIdx.x * 256 + threadIdx.x;
    if (idx < 2048) {
        int li = idx;
        int j = li & 7, lane = (li >> 3) & 63;
        int kb = (li >> 9) & 1, nt = li / 1024;
        int k = kb * 32 + (lane >> 4) * 8 + j;
        int tap = k >> 2, ci = k & 3;
        int co = nt * 16 + (lane & 15);
        float f = (ci < 3) ? ec1_w[((long)co * 3 + ci) * 16 + tap] : 0.f;
        unsigned short hi = f2bf(f);
        WBe1[li] = hi; WBe1[2048 + li] = f2bf(f - bf2f(hi));
    } else if (idx < 34816) {
        int li = idx - 2048;
        int j = li & 7, lane = (li >> 3) & 63;
        int kb = (li >> 9) & 15, nt = li / 8192;
        int k = kb * 32 + (lane >> 4) * 8 + j;
        int tap = k >> 5, ci = k & 31;
        int co = nt * 16 + (lane & 15);
        float f = ec2_w[((long)co * 32 + ci) * 16 + tap];
        unsigned short hi = f2bf(f);
        WBe2[li] = hi; WBe2[32768 + li] = f2bf(f - bf2f(hi));
    } else if (idx < 67584) {
        int li = idx - 34816;
        int par = li >> 13; int rem = li & 8191;
        int j = rem & 7, lane = (rem >> 3) & 63;
        int kb = (rem >> 9) & 7, nt = rem >> 12;
        int k = kb * 32 + (lane >> 4) * 8 + j;
        int t4 = k >> 6, ci = k & 63;
        int p = par >> 1, q = par & 1, dh = t4 >> 1, dw = t4 & 1;
        int tap = (p + 2 * dh) * 4 + (q + 2 * dw);
        int co = nt * 16 + (lane & 15);
        float f = dt3_w[((long)co * 64 + ci) * 16 + tap];
        unsigned short hi = f2bf(f);
        WBd3[par * 16384 + rem] = hi;
        WBd3[par * 16384 + 8192 + rem] = f2bf(f - bf2f(hi));
    } else if (idx < 67968) {
        int li = idx - 67584;
        int t4 = li & 3, par = (li >> 2) & 3;
        int co = (li >> 4) % 3, ci4 = (li >> 4) / 3;
        int p = par >> 1, q = par & 1, dh = t4 >> 1, dw = t4 & 1;
        int tap = (p + 2 * dh) * 4 + (q + 2 * dw);
        float4 v; float* pv = (float*)&v;
#pragma unroll
        for (int l = 0; l < 4; ++l)
            pv[l] = dt4_w[((long)co * 32 + ci4 * 4 + l) * 16 + tap];
        WTd4[li] = v;
    }
}

__global__ void prep_r1(const float* __restrict__ wih_e, const float* __restrict__ wih_d,
                        const float* __restrict__ fc_w,
                        const float* __restrict__ bih_d, const float* __restrict__ bhh_d,
                        const float* __restrict__ fc_b,
                        const float* __restrict__ fcmu_w, const float* __restrict__ dfc_w,
                        const float* __restrict__ dfc_b,
                        float* __restrict__ WIHP_E, float* __restrict__ WIHP_D,
                        float* __restrict__ FCP, float* __restrict__ BIASDC,
                        float* __restrict__ FCMUP, float* __restrict__ DFCP,
                        float* __restrict__ DFCB) {
    int idx = blockIdx.x * 256 + threadIdx.x;
    if (idx < 262144) {
        int c = idx & 2047, m = idx >> 11;
        WIHP_E[idx] = wih_e[orig_row(c) * 128 + m];
    } else if (idx < 524288) {
        int li = idx - 262144;
        int c = li & 2047, m = li >> 11;
        WIHP_D[li] = wih_d[orig_row(c) * 128 + m];
    } else if (idx < 589824) {
        int li = idx - 524288;
        int r = li & 127, c = li >> 7;
        FCP[li] = fc_w[(long)r * 512 + c];
    } else if (idx < 591872) {
        int c = idx - 589824;
        int orow = orig_row(c);
        float s = bih_d[orow] + bhh_d[orow];
        for (int m = 0; m < 128; ++m) s += fc_b[m] * wih_d[orow * 128 + m];
        BIASDC[c] = s;
    } else if (idx < 1116160) {
        int li = idx - 591872;
        int j = li & 127, k = li >> 7;
        FCMUP[li] = fcmu_w[(long)j * 4096 + (k & 255) * 16 + (k >> 8)];
    } else {
        int li = idx - 1116160;
        int j = li & 4095, m = li >> 12;
        int jc = (j & 255) * 16 + (j >> 8);
        DFCP[li] = dfc_w[(long)jc * 128 + m];
        if (li < 4096) DFCB[li] = dfc_b[(li & 255) * 16 + (li >> 8)];
    }
}

__global__ void to_nhwc4v(const float* __restrict__ v, float4* __restrict__ out) {
    int idx = blockIdx.x * 256 + threadIdx.x;  // 1,048,576
    int w = idx & 63, h = (idx >> 6) & 63, n = idx >> 12;
    long base = (long)n * 12288 + h * 64 + w;
    float4 o;
    o.x = v[base];
    o.y = v[base + 4096];
    o.z = v[base + 8192];
    o.w = 0.f;
    out[idx] = o;
}

__global__ void pack_whh(const float* __restrict__ whh, float4* __restrict__ out) {
    int idx = blockIdx.x * 256 + threadIdx.x;  // 262144
    int c = idx & 2047, k4 = idx >> 11;
    const float4* src = (const float4*)(whh + orig_row(c) * 512);
    out[idx] = src[k4];
}

__global__ __launch_bounds__(256)
void merge_dc(const float* __restrict__ wih_d, const float* __restrict__ fc_w,
              const float* __restrict__ whh_d, float* __restrict__ out) {
    int cb = (blockIdx.x >> 3) * 64, kb = (blockIdx.x & 7) * 64;
    int tid = threadIdx.x;
    int cgl = (tid & 15) * 4, kgl = (tid >> 4) * 4;
    __shared__ float At[64][65];
    __shared__ float Bt[64][65];
    float acc[4][4] = {};
    for (int mc = 0; mc < 128; mc += 64) {
        __syncthreads();
        for (int i = tid; i < 4096; i += 256) {
            int cl = i >> 6, m = i & 63;
            At[cl][m] = wih_d[orig_row(cb + cl) * 128 + mc + m];
            Bt[cl][m] = fc_w[(mc + cl) * 512 + kb + m];
        }
        __syncthreads();
        for (int m = 0; m < 64; ++m) {
            float a[4], b[4];
#pragma unroll
            for (int i = 0; i < 4; ++i) { a[i] = At[cgl + i][m]; b[i] = Bt[m][kgl + i]; }
#pragma unroll
            for (int i = 0; i < 4; ++i)
#pragma unroll
                for (int j = 0; j < 4; ++j) acc[i][j] += a[i] * b[j];
        }
    }
    for (int i = 0; i < 4; ++i) {
        int c = cb + cgl + i; int orow = orig_row(c);
        for (int j = 0; j < 4; ++j) {
            int k = kb + kgl + j;
            out[((k >> 2) * 2048 + c) * 4 + (k & 3)] = acc[i][j] + whh_d[orow * 512 + k];
        }
    }
}

// ============================ LSTM / FC path ================================
__global__ __launch_bounds__(512)
void gx2_kernel(const float* __restrict__ Z,
                const float* __restrict__ wE, const float* __restrict__ biE,
                const float* __restrict__ bhE,
                const float* __restrict__ wD, const float* __restrict__ biD,
                const float* __restrict__ bhD,
                float* __restrict__ gxe, float* __restrict__ gxd0) {
    __shared__ float zl[2048];
    int bid = blockIdx.x, tid = threadIdx.x;
    if (bid < 64) {
        int rg = bid >> 2, cch = bid & 3;
        for (int i = tid; i < 2048; i += 512)
            zl[i] = Z[(long)(rg * 16 + (i >> 7)) * 128 + (i & 127)];
        __syncthreads();
        int c = cch * 512 + tid;
        int orow = orig_row(c);
        float bsum = biE[orow] + bhE[orow];
        float acc[16];
#pragma unroll
        for (int r = 0; r < 16; ++r) acc[r] = bsum;
        for (int m = 0; m < 128; ++m) {
            float wv = wE[m * 2048 + c];
#pragma unroll
            for (int r = 0; r < 16; ++r) acc[r] += zl[r * 128 + m] * wv;
        }
        for (int r = 0; r < 16; ++r) gxe[(long)(rg * 16 + r) * 2048 + c] = acc[r];
    } else {
        int cch = bid - 64;
        for (int i = tid; i < 2048; i += 512)
            zl[i] = Z[(long)((i >> 7) * 16 + 15) * 128 + (i & 127)];
        __syncthreads();
        int c = cch * 512 + tid;
        int orow = orig_row(c);
        float bsum = biD[orow] + bhD[orow];
        float acc[16];
#pragma unroll
        for (int r = 0; r < 16; ++r) acc[r] = bsum;
        for (int m = 0; m < 128; ++m) {
            float wv = wD[m * 2048 + c];
#pragma unroll
            for (int r = 0; r < 16; ++r) acc[r] += zl[r * 128 + m] * wv;
        }
        for (int r = 0; r < 16; ++r) gxd0[(long)r * 2048 + c] = acc[r];
    }
}

__global__ __launch_bounds__(512)
void lstm_step(const float4* __restrict__ wh4, const float* __restrict__ gadd,
               int gstride, const float* __restrict__ h_in, float* __restrict__ h_out,
               float* __restrict__ cst, float* __restrict__ hall) {
    __shared__ float hs[8192];
    __shared__ float gb[16][32];
    int tid = threadIdx.x;
    float4* hs4 = (float4*)hs;
    const float4* hi4 = (const float4*)h_in;
#pragma unroll
    for (int i = 0; i < 4; ++i) hs4[tid + 512 * i] = hi4[tid + 512 * i];
    __syncthreads();
    int col = tid & 31, n = tid >> 5;
    int cg = blockIdx.x * 32 + col;
    float acc = gadd[n * gstride + cg];
    const float4* wp = wh4 + cg;
    const float4* hv = (const float4*)(hs + n * 512);
#pragma unroll 8
    for (int k4 = 0; k4 < 128; ++k4) {
        float4 wv = wp[(long)k4 * 2048];
        float4 h4 = hv[k4];
        acc += wv.x * h4.x + wv.y * h4.y + wv.z * h4.z + wv.w * h4.w;
    }
    gb[n][col] = acc;
    __syncthreads();
    if (col < 8) {
        int j = blockIdx.x * 8 + col;
        float gi = sig_(gb[n][col]);
        float gf = sig_(gb[n][col + 8]);
        float gg = tanhf(gb[n][col + 16]);
        float go = sig_(gb[n][col + 24]);
        int idx = n * 512 + j;
        float cv = gf * cst[idx] + gi * gg;
        cst[idx] = cv;
        float hvv = go * tanhf(cv);
        h_out[idx] = hvv;
        if (hall) hall[idx] = hvv;
    }
}

__global__ __launch_bounds__(512)
void fcmu_part(const unsigned short* __restrict__ xh,
               const float* __restrict__ wP, float* __restrict__ part) {
    int rg = blockIdx.x >> 3, ks = blockIdx.x & 7;
    int tid = threadIdx.x;
    __shared__ float xls[16 * 512];
    for (int i = tid; i < 8192; i += 512) {
        long gi = (long)(rg * 16 + (i >> 9)) * 4096 + ks * 512 + (i & 511);
        xls[i] = bf2f(xh[gi]);
    }
    __syncthreads();
    int j = tid & 127, rq = tid >> 7;
    float acc[4] = {0, 0, 0, 0};
    for (int k = 0; k < 512; ++k) {
        float wv = wP[(ks * 512 + k) * 128 + j];
#pragma unroll
        for (int i = 0; i < 4; ++i) acc[i] += xls[(rq + 4 * i) * 512 + k] * wv;
    }
    for (int i = 0; i < 4; ++i)
        part[((long)ks * 256 + rg * 16 + rq + 4 * i) * 128 + j] = acc[i];
}

__global__ void fcmu_red(const float* __restrict__ part, const float* __restrict__ b,
                         float* __restrict__ z) {
    int idx = blockIdx.x * 256 + threadIdx.x;  // 32768
    float s = b[idx & 127];
    for (int k = 0; k < 8; ++k) s += part[k * 32768 + idx];
    z[idx] = s;
}

__global__ __launch_bounds__(512)
void zs_k(const float* __restrict__ hall, const float* __restrict__ fcP,
          const float* __restrict__ fcb, float* __restrict__ zs) {
    int t = blockIdx.x;
    int tid = threadIdx.x;
    __shared__ float hs[8192];
    const float* h = hall + t * 8192;
    for (int i = tid; i < 8192; i += 512) hs[i] = h[i];
    __syncthreads();
    int j = tid & 127, ng = tid >> 7;
    float acc[4] = {0, 0, 0, 0};
    for (int k = 0; k < 512; ++k) {
        float wv = fcP[k * 128 + j];
#pragma unroll
        for (int i = 0; i < 4; ++i) acc[i] += hs[(ng + 4 * i) * 512 + k] * wv;
    }
    float bv = fcb[j];
    for (int i = 0; i < 4; ++i)
        zs[((ng + 4 * i) * 16 + t) * 128 + j] = acc[i] + bv;
}

__global__ __launch_bounds__(512)
void dfc_k(const float* __restrict__ zs, const float* __restrict__ dP,
           const float* __restrict__ db, unsigned short* __restrict__ outh) {
    int rg = blockIdx.x >> 3, jc = blockIdx.x & 7;
    int tid = threadIdx.x;
    __shared__ float zl[16 * 128];
    for (int i = tid; i < 2048; i += 512) zl[i] = zs[(long)rg * 2048 + i];
    __syncthreads();
    int j = jc * 512 + tid;
    float acc[16];
#pragma unroll
    for (int r = 0; r < 16; ++r) acc[r] = 0.f;
    for (int m = 0; m < 128; ++m) {
        float wv = dP[(long)m * 4096 + j];
#pragma unroll
        for (int r = 0; r < 16; ++r) acc[r] += zl[r * 128 + m] * wv;
    }
    float bv = db[j];
    for (int r = 0; r < 16; ++r) {
        float v = fmaxf(acc[r] + bv, 0.f);
        outh[(long)(rg * 16 + r) * 4096 + j] = f2bf(v);
    }
}

extern "C" void kernel_launch(void* const* d_in, const int* in_sizes, int n_in,
                              void* d_out, int out_size, void* d_ws, size_t ws_size,
                              hipStream_t stream) {
    (void)in_sizes; (void)n_in; (void)out_size; (void)ws_size;
    const float* video  = (const float*)d_in[0];
    const float* ec1_w  = (const float*)d_in[2];  const float* ec1_b = (const float*)d_in[3];
    const float* ec2_w  = (const float*)d_in[4];  const float* ec2_b = (const float*)d_in[5];
    const float* ec3_w  = (const float*)d_in[6];  const float* ec3_b = (const float*)d_in[7];
    const float* ec4_w  = (const float*)d_in[8];  const float* ec4_b = (const float*)d_in[9];
    const float* fcmu_w = (const float*)d_in[10]; const float* fcmu_b = (const float*)d_in[11];
    const float* dfc_w  = (const float*)d_in[12]; const float* dfc_b = (const float*)d_in[13];
    const float* dt1_w  = (const float*)d_in[14]; const float* dt1_b = (const float*)d_in[15];
    const float* dt2_w  = (const float*)d_in[16]; const float* dt2_b = (const float*)d_in[17];
    const float* dt3_w  = (const float*)d_in[18]; const float* dt3_b = (const float*)d_in[19];
    const float* dt4_w  = (const float*)d_in[20]; const float* dt4_b = (const float*)d_in[21];
    const float* wih_e  = (const float*)d_in[22]; const float* whh_e = (const float*)d_in[23];
    const float* bih_e  = (const float*)d_in[24]; const float* bhh_e = (const float*)d_in[25];
    const float* wih_d  = (const float*)d_in[26]; const float* whh_d = (const float*)d_in[27];
    const float* bih_d  = (const float*)d_in[28]; const float* bhh_d = (const float*)d_in[29];
    const float* fc_w   = (const float*)d_in[30]; const float* fc_b  = (const float*)d_in[31];

    char* wsb = (char*)d_ws;
    unsigned short* B1h = (unsigned short*)wsb;              // 8,388,608 e
    float*          X0f = (float*)(wsb + 33554432);
    unsigned short* B2h = (unsigned short*)(wsb + 33554432); // 4,194,304 e
    unsigned short* B3h = (unsigned short*)(wsb + 50331648); // 2,097,152 e
    unsigned short* B4h = (unsigned short*)(wsb + 58720256); // 1,048,576 e
    float* R1f    = (float*)wsb;
    float* WH4_E  = R1f;
    float* WH4_DC = R1f + 1048576;
    float* WIHP_E = R1f + 2097152;
    float* WIHP_D = R1f + 2359296;
    float* GX_E   = R1f + 2621440;
    float* GX_D0  = R1f + 3145728;
    float* BIASDC = R1f + 3178496;
    float* HA     = R1f + 3180544;
    float* HB     = R1f + 3188736;
    float* CB     = R1f + 3196928;
    float* HALL   = R1f + 3205120;
    float* FCMUP  = R1f + 3336192;
    float* ZPART  = R1f + 3860480;
    float* FCP    = R1f + 4122624;
    float* DFCP   = R1f + 4188160;
    float* DFCB   = R1f + 4712448;
    float* Z      = R1f + 4716544;
    float* ZS     = R1f + 4749312;
    unsigned short* WBe3 = (unsigned short*)(R1f + 4782080);
    unsigned short* WBe4 = (unsigned short*)(R1f + 4913152);
    unsigned short* WBd1 = (unsigned short*)(R1f + 5437440);
    unsigned short* WBd2 = (unsigned short*)(R1f + 5961728);
    unsigned short* WBe1 = (unsigned short*)(wsb + 62914560);
    unsigned short* WBe2 = (unsigned short*)(wsb + 62922752);
    unsigned short* WBd3 = (unsigned short*)(wsb + 63053824);
    float*          WTd4 = (float*)(wsb + 63184896);

    // ---- merged tail prep + encoder ec1/ec2 ----
    prep_tail<<<266, 256, 0, stream>>>(ec1_w, ec2_w, dt3_w, dt4_w,
                                       WBe1, WBe2, WBd3, (float4*)WTd4);
    to_nhwc4v<<<4096, 256, 0, stream>>>(video, (float4*)X0f);
    conv_mfma<4, 64, 64, 32, 2, 4, 1, 0, 1><<<1024, 256, 0, stream>>>(
        nullptr, X0f, WBe1, ec1_b, B1h);
    conv_mfma<32, 32, 32, 64, 2, 2, 2, 0, 0><<<512, 256, 0, stream>>>(
        B1h, nullptr, WBe2, ec2_b, B2h);

    // ---- R1 free: merged prep + big packs ----
    prep_r1<<<6408, 256, 0, stream>>>(wih_e, wih_d, fc_w, bih_d, bhh_d, fc_b,
                                      fcmu_w, dfc_w, dfc_b,
                                      WIHP_E, WIHP_D, FCP, BIASDC, FCMUP, DFCP, DFCB);
    pack_wb_conv<64, 64, 128><<<512, 256, 0, stream>>>(ec3_w, WBe3);
    pack_wb_conv<128, 128, 256><<<2048, 256, 0, stream>>>(ec4_w, WBe4);
    pack_wb_convt<256, 128><<<2048, 256, 0, stream>>>(dt1_w, WBd1);
    pack_wb_convt<128, 64><<<512, 256, 0, stream>>>(dt2_w, WBd2);
    pack_whh<<<1024, 256, 0, stream>>>(whh_e, (float4*)WH4_E);
    merge_dc<<<256, 256, 0, stream>>>(wih_d, fc_w, whh_d, WH4_DC);
    hipMemsetAsync(HA, 0, 3 * 8192 * sizeof(float), stream);

    // ---- encoder ec3/ec4 + fcmu ----
    conv_mfma<64, 16, 16, 128, 2, 2, 2, 0, 0><<<256, 256, 0, stream>>>(
        B2h, nullptr, WBe3, ec3_b, B3h);
    conv_mfma<128, 8, 8, 256, 1, 2, 2, 0, 0><<<256, 256, 0, stream>>>(
        B3h, nullptr, WBe4, ec4_b, B4h);
    fcmu_part<<<128, 512, 0, stream>>>(B4h, FCMUP, ZPART);
    fcmu_red<<<128, 256, 0, stream>>>(ZPART, fcmu_b, Z);

    // ---- merged x projections ----
    gx2_kernel<<<68, 512, 0, stream>>>(Z, WIHP_E, bih_e, bhh_e,
                                       WIHP_D, bih_d, bhh_d, GX_E, GX_D0);

    // ---- LSTM chains (per-step launches; coop grid-sync measured 5x slower) ----
    float* hin = HA; float* hout = HB;
    for (int t = 0; t < 16; ++t) {
        lstm_step<<<64, 512, 0, stream>>>((const float4*)WH4_E, GX_E + t * 2048, 32768,
                                          hin, hout, CB, (float*)nullptr);
        float* tmp = hin; hin = hout; hout = tmp;
    }
    pack_whh<<<1024, 256, 0, stream>>>(whh_d, (float4*)WH4_E);  // reuse for dec step 0
    lstm_step<<<64, 512, 0, stream>>>((const float4*)WH4_E, GX_D0, 2048,
                                      hin, hout, CB, HALL);
    { float* tmp = hin; hin = hout; hout = tmp; }
    for (int t = 1; t < 16; ++t) {
        lstm_step<<<64, 512, 0, stream>>>((const float4*)WH4_DC, BIASDC, 0,
                                          hin, hout, CB, HALL + t * 8192);
        float* tmp = hin; hin = hout; hout = tmp;
    }
    zs_k<<<16, 512, 0, stream>>>(HALL, FCP, fc_b, ZS);

    // ---- decoder ----
    dfc_k<<<128, 512, 0, stream>>>(ZS, DFCP, DFCB, B4h);
    conv_mfma<256, 4, 4, 128, 1, 2, 2, 1, 0><<<512, 256, 0, stream>>>(
        B4h, nullptr, WBd1, dt1_b, B3h);
    conv_mfma<128, 8, 8, 64, 2, 2, 2, 1, 0><<<512, 256, 0, stream>>>(
        B3h, nullptr, WBd2, dt2_b, B2h);
    conv_mfma<64, 16, 16, 32, 2, 4, 1, 1, 0><<<1024, 256, 0, stream>>>(
        B2h, nullptr, WBd3, dt3_b, B1h);
    dt4_tiled<<<1024, 256, 0, stream>>>(B1h, (const float4*)WTd4, dt4_b, (float*)d_out);
}

// Round 10
// 700.583 us; speedup vs baseline: 3.5758x; 1.0067x over previous
//
#include <hip/hip_runtime.h>
#include <math.h>

// ---------------------------------------------------------------------------
// CNN-LSTM video predictor, round 10: conv_mfma restructured (wave-uniform
// tap loop, branchless clamped A-loads, unroll-2 pipelining); dt4 LDS in
// bf16 (half footprint -> 4 blocks/CU). Rest = round 9 (705us, absmax 2e-3).
// ---------------------------------------------------------------------------

typedef float f32x4 __attribute__((ext_vector_type(4)));
typedef short bf16x8 __attribute__((ext_vector_type(8)));

__device__ __forceinline__ float sig_(float x) { return 1.f / (1.f + expf(-x)); }
__device__ __forceinline__ float dot4(float4 a, float4 b) {
    return a.x * b.x + a.y * b.y + a.z * b.z + a.w * b.w;
}
__device__ __forceinline__ int orig_row(int c) {
    return ((c >> 3) & 3) * 512 + (c >> 5) * 8 + (c & 7);
}
__device__ __forceinline__ unsigned short f2bf(float f) {
    unsigned int b = __float_as_uint(f);
    return (unsigned short)((b + 0x7fffu + ((b >> 16) & 1u)) >> 16);
}
__device__ __forceinline__ float bf2f(unsigned short h) {
    return __uint_as_float(((unsigned int)h) << 16);
}
__device__ __forceinline__ float4 bf4_to_f4(uint2 u) {
    float4 r;
    r.x = __uint_as_float((u.x & 0xffffu) << 16);
    r.y = __uint_as_float(u.x & 0xffff0000u);
    r.z = __uint_as_float((u.y & 0xffffu) << 16);
    r.w = __uint_as_float(u.y & 0xffff0000u);
    return r;
}

// =================== MFMA conv / convT (A bf16, W split) ====================
// MODE 0: conv s2 k4 p1 (K = CIP*16). MODE 1: convT parity (K = CIP*4).
// SRCF32=1 (ec1, CIP=4): A from fp32 NHWC4 (old kb-loop path).
// Non-SRCF32 (CIP>=32): tap-outer loop, tap wave-uniform, branchless A loads.
template<int CIP, int HI, int WI, int CO, int MREP, int WM, int WN, int MODE, int SRCF32>
__global__ __launch_bounds__(64 * WM * WN)
void conv_mfma(const unsigned short* __restrict__ Ahi, const float* __restrict__ Af,
               const unsigned short* __restrict__ WB, const float* __restrict__ bias,
               unsigned short* __restrict__ Yhi) {
    constexpr int K    = CIP * (MODE ? 4 : 16);
    constexpr int K32  = K / 32;
    constexpr int NI   = 2 * MREP;
    constexpr int TAPS = MODE ? 4 : 16;
    constexpr int CC   = (CIP >= 32) ? CIP / 32 : 1;
    constexpr int HO   = MODE ? HI * 2 : HI / 2;
    constexpr int WO   = MODE ? WI * 2 : WI / 2;
    constexpr int SH   = MODE ? HI : HI / 2;
    constexpr int SW   = MODE ? WI : WI / 2;
    constexpr int HWS  = SH * SW;
    constexpr int MT   = (256 * HWS) / (32 * MREP * WM);
    constexpr int NT   = CO / (32 * WN);
    constexpr int PLANE = CO * K;

    int bid = blockIdx.x;
    int mt = bid % MT; bid /= MT;
    int nt = bid % NT; int par = bid / NT;
    int p = par >> 1, q = par & 1;

    int tid = threadIdx.x;
    int lane = tid & 63, wid = tid >> 6;
    int wm = wid % WM, wn = wid / WM;
    int mbase = mt * (32 * MREP * WM) + wm * (32 * MREP);
    int nbase = nt * (32 * WN) + wn * 32;
    int lm = lane & 15, lg = lane >> 4;

    int ani[NI], asy[NI], asx[NI];
#pragma unroll
    for (int i = 0; i < NI; ++i) {
        int m = mbase + 16 * i + lm;
        ani[i] = m / HWS; int r = m % HWS; asy[i] = r / SW; asx[i] = r % SW;
    }

    f32x4 acc[NI][2];
#pragma unroll
    for (int i = 0; i < NI; ++i)
#pragma unroll
        for (int j = 0; j < 2; ++j)
#pragma unroll
            for (int e = 0; e < 4; ++e) acc[i][j][e] = 0.f;

    const unsigned short* WBp = WB + (long)par * 2 * PLANE;

    if constexpr (SRCF32) {
        // ec1 path: CIP==4, fp32 source, on-the-fly round (K small)
        for (int kb = 0; kb < K; kb += 32) {
            int k0 = kb + lg * 8;
            int t0 = k0 >> 2;
            bf16x8 ah[NI];
#pragma unroll
            for (int i = 0; i < NI; ++i) {
                float f[8];
#pragma unroll
                for (int h = 0; h < 2; ++h) {
                    int tap = t0 + h;
                    int ih = 2 * asy[i] + (tap >> 2) - 1;
                    int iw = 2 * asx[i] + (tap & 3) - 1;
                    float4 v = {0.f, 0.f, 0.f, 0.f};
                    if ((unsigned)ih < (unsigned)HI && (unsigned)iw < (unsigned)WI)
                        v = *(const float4*)(Af + (((long)ani[i] * HI + ih) * WI + iw) * 4);
                    f[h * 4 + 0] = v.x; f[h * 4 + 1] = v.y;
                    f[h * 4 + 2] = v.z; f[h * 4 + 3] = v.w;
                }
#pragma unroll
                for (int e = 0; e < 8; ++e) ah[i][e] = (short)f2bf(f[e]);
            }
            bf16x8 bh[2], bl[2];
#pragma unroll
            for (int j = 0; j < 2; ++j) {
                long bidx = ((long)((nbase >> 4) + j) * K32 + (kb >> 5)) * 512 + lane * 8;
                bh[j] = *(const bf16x8*)(WBp + bidx);
                bl[j] = *(const bf16x8*)(WBp + PLANE + bidx);
            }
#pragma unroll
            for (int i = 0; i < NI; ++i)
#pragma unroll
                for (int j = 0; j < 2; ++j) {
                    acc[i][j] = __builtin_amdgcn_mfma_f32_16x16x32_bf16(ah[i], bh[j], acc[i][j], 0, 0, 0);
                    acc[i][j] = __builtin_amdgcn_mfma_f32_16x16x32_bf16(ah[i], bl[j], acc[i][j], 0, 0, 0);
                }
        }
    } else {
        // precompute per-fragment base address + tap validity mask
        long abase[NI]; unsigned vmask[NI];
#pragma unroll
        for (int i = 0; i < NI; ++i) {
            abase[i] = (long)ani[i] * HI * WI * CIP;
            unsigned vm = 0;
#pragma unroll
            for (int t = 0; t < TAPS; ++t) {
                int iy, ix;
                if constexpr (MODE == 0) {
                    iy = 2 * asy[i] + (t >> 2) - 1; ix = 2 * asx[i] + (t & 3) - 1;
                } else {
                    iy = asy[i] + p + (t >> 1) - 1; ix = asx[i] + q + (t & 1) - 1;
                }
                if (iy >= 0 && iy < HI && ix >= 0 && ix < WI) vm |= (1u << t);
            }
            vmask[i] = vm;
        }
#pragma unroll 2
        for (int tap = 0; tap < TAPS; ++tap) {
            int dy, dx;
            if constexpr (MODE == 0) { dy = (tap >> 2) - 1; dx = (tap & 3) - 1; }
            else { dy = p + (tap >> 1) - 1; dx = q + (tap & 1) - 1; }
            long roff[NI]; unsigned msk[NI];
#pragma unroll
            for (int i = 0; i < NI; ++i) {
                int iy = (MODE == 0 ? 2 * asy[i] : asy[i]) + dy;
                int ix = (MODE == 0 ? 2 * asx[i] : asx[i]) + dx;
                int iyc = min(max(iy, 0), HI - 1);
                int ixc = min(max(ix, 0), WI - 1);
                roff[i] = abase[i] + ((long)iyc * WI + ixc) * CIP + lg * 8;
                msk[i] = ((vmask[i] >> tap) & 1u) ? 0xffffffffu : 0u;
            }
#pragma unroll
            for (int cc = 0; cc < CC; ++cc) {
                int kb32 = tap * CC + cc;
                bf16x8 ah[NI];
#pragma unroll
                for (int i = 0; i < NI; ++i) {
                    uint4 u = *(const uint4*)(Ahi + roff[i] + cc * 32);
                    u.x &= msk[i]; u.y &= msk[i]; u.z &= msk[i]; u.w &= msk[i];
                    ah[i] = *(bf16x8*)&u;
                }
                bf16x8 bh[2], bl[2];
#pragma unroll
                for (int j = 0; j < 2; ++j) {
                    long bidx = ((long)((nbase >> 4) + j) * K32 + kb32) * 512 + lane * 8;
                    bh[j] = *(const bf16x8*)(WBp + bidx);
                    bl[j] = *(const bf16x8*)(WBp + PLANE + bidx);
                }
#pragma unroll
                for (int i = 0; i < NI; ++i)
#pragma unroll
                    for (int j = 0; j < 2; ++j) {
                        acc[i][j] = __builtin_amdgcn_mfma_f32_16x16x32_bf16(ah[i], bh[j], acc[i][j], 0, 0, 0);
                        acc[i][j] = __builtin_amdgcn_mfma_f32_16x16x32_bf16(ah[i], bl[j], acc[i][j], 0, 0, 0);
                    }
            }
        }
    }

#pragma unroll
    for (int i = 0; i < NI; ++i)
#pragma unroll
        for (int j = 0; j < 2; ++j)
#pragma unroll
            for (int r = 0; r < 4; ++r) {
                int m = mbase + 16 * i + lg * 4 + r;
                int co = nbase + 16 * j + lm;
                float v = fmaxf(acc[i][j][r] + bias[co], 0.f);
                long off;
                if constexpr (MODE == 0) {
                    off = (long)m * CO + co;
                } else {
                    int ni = m / HWS; int rm = m % HWS;
                    int oy = 2 * (rm / SW) + p, ox = 2 * (rm % SW) + q;
                    off = (((long)ni * HO + oy) * WO + ox) * CO + co;
                }
                Yhi[off] = f2bf(v);
            }
}

// ====== dt4: LDS-tiled (bf16 LDS), CO=3, sigmoid, NCHW out ==================
__global__ __launch_bounds__(256)
void dt4_tiled(const unsigned short* __restrict__ Xh,
               const float4* __restrict__ Wd, const float* __restrict__ bias,
               float* __restrict__ out) {
    __shared__ uint2 xt[8 * 341];  // bf16x4 per entry: 21.8 KB -> 4 blocks/CU
    int bid = blockIdx.x;
    int n = bid >> 2, yg = bid & 3;
    int y0 = yg * 8;
    int tid = threadIdx.x;
    long nb = (long)n * 32768;
    for (int j = tid; j < 2720; j += 256) {
        int c4 = j & 7; int pos = j >> 3;
        int r = pos / 34, cc = pos % 34;
        int ih = y0 - 1 + r, iw = cc - 1;
        uint2 u = {0u, 0u};
        if ((unsigned)ih < 32u && (unsigned)iw < 32u)
            u = *(const uint2*)(Xh + nb + ((long)ih * 32 + iw) * 32 + c4 * 4);
        xt[c4 * 341 + pos] = u;
    }
    __syncthreads();
    int ly = tid >> 5, lx = tid & 31;
    float acc[3][4];
#pragma unroll
    for (int j = 0; j < 3; ++j) {
        float b = bias[j];
#pragma unroll
        for (int par = 0; par < 4; ++par) acc[j][par] = b;
    }
#pragma unroll
    for (int ci4 = 0; ci4 < 8; ++ci4) {
        float4 xv[9];
        int base = ci4 * 341 + ly * 34 + lx;
#pragma unroll
        for (int r = 0; r < 3; ++r)
#pragma unroll
            for (int c = 0; c < 3; ++c)
                xv[r * 3 + c] = bf4_to_f4(xt[base + r * 34 + c]);
        const float4* wp = Wd + ci4 * 48;
#pragma unroll
        for (int j = 0; j < 3; ++j)
#pragma unroll
            for (int par = 0; par < 4; ++par) {
                int p = par >> 1, q = par & 1;
#pragma unroll
                for (int t4 = 0; t4 < 4; ++t4) {
                    int dh = t4 >> 1, dw = t4 & 1;
                    acc[j][par] += dot4(xv[(p + dh) * 3 + (q + dw)],
                                        wp[(j * 4 + par) * 4 + t4]);
                }
            }
    }
    int yy = y0 + ly, xx = lx;
#pragma unroll
    for (int j = 0; j < 3; ++j)
#pragma unroll
        for (int p = 0; p < 2; ++p) {
            float2 v;
            v.x = sig_(acc[j][p * 2 + 0]);
            v.y = sig_(acc[j][p * 2 + 1]);
            *(float2*)(out + (((long)n * 3 + j) * 64 + 2 * yy + p) * 64 + 2 * xx) = v;
        }
}

// ========================= weight / layout prep =============================
template<int CIS, int CIP, int CO>
__global__ void pack_wb_conv(const float* __restrict__ w, unsigned short* __restrict__ out) {
    constexpr int K = CIP * 16;
    int idx = blockIdx.x * 256 + threadIdx.x;
    if (idx >= CO * K) return;
    int j = idx & 7, lane = (idx >> 3) & 63;
    int kb = (idx >> 9) % (K / 32), nt = idx / (512 * (K / 32));
    int k = kb * 32 + (lane >> 4) * 8 + j;
    int tap = k / CIP, ci = k & (CIP - 1);
    int co = nt * 16 + (lane & 15);
    float f = (ci < CIS) ? w[((long)co * CIS + ci) * 16 + tap] : 0.f;
    unsigned short hi = f2bf(f);
    out[idx] = hi;
    out[CO * K + idx] = f2bf(f - bf2f(hi));
}

template<int CI, int CO>
__global__ void pack_wb_convt(const float* __restrict__ w, unsigned short* __restrict__ out) {
    constexpr int Kp = CI * 4;
    int idx = blockIdx.x * 256 + threadIdx.x;
    if (idx >= 4 * CO * Kp) return;
    int par = idx / (CO * Kp); int rem = idx % (CO * Kp);
    int j = rem & 7, lane = (rem >> 3) & 63;
    int kb = (rem >> 9) % (Kp / 32), nt = rem / (512 * (Kp / 32));
    int k = kb * 32 + (lane >> 4) * 8 + j;
    int t4 = k / CI, ci = k & (CI - 1);
    int p = par >> 1, q = par & 1, dh = t4 >> 1, dw = t4 & 1;
    int tap = (p + 2 * dh) * 4 + (q + 2 * dw);
    int co = nt * 16 + (lane & 15);
    float f = w[((long)co * CI + ci) * 16 + tap];
    unsigned short hi = f2bf(f);
    out[(long)par * 2 * CO * Kp + rem] = hi;
    out[(long)par * 2 * CO * Kp + CO * Kp + rem] = f2bf(f - bf2f(hi));
}

__global__ void prep_tail(const float* __restrict__ ec1_w, const float* __restrict__ ec2_w,
                          const float* __restrict__ dt3_w, const float* __restrict__ dt4_w,
                          unsigned short* __restrict__ WBe1, unsigned short* __restrict__ WBe2,
                          unsigned short* __restrict__ WBd3, float4* __restrict__ WTd4) {
    int idx = blockIdx.x * 256 + threadIdx.x;
    if (idx < 2048) {
        int li = idx;
        int j = li & 7, lane = (li >> 3) & 63;
        int kb = (li >> 9) & 1, nt = li / 1024;
        int k = kb * 32 + (lane >> 4) * 8 + j;
        int tap = k >> 2, ci = k & 3;
        int co = nt * 16 + (lane & 15);
        float f = (ci < 3) ? ec1_w[((long)co * 3 + ci) * 16 + tap] : 0.f;
        unsigned short hi = f2bf(f);
        WBe1[li] = hi; WBe1[2048 + li] = f2bf(f - bf2f(hi));
    } else if (idx < 34816) {
        int li = idx - 2048;
        int j = li & 7, lane = (li >> 3) & 63;
        int kb = (li >> 9) & 15, nt = li / 8192;
        int k = kb * 32 + (lane >> 4) * 8 + j;
        int tap = k >> 5, ci = k & 31;
        int co = nt * 16 + (lane & 15);
        float f = ec2_w[((long)co * 32 + ci) * 16 + tap];
        unsigned short hi = f2bf(f);
        WBe2[li] = hi; WBe2[32768 + li] = f2bf(f - bf2f(hi));
    } else if (idx < 67584) {
        int li = idx - 34816;
        int par = li >> 13; int rem = li & 8191;
        int j = rem & 7, lane = (rem >> 3) & 63;
        int kb = (rem >> 9) & 7, nt = rem >> 12;
        int k = kb * 32 + (lane >> 4) * 8 + j;
        int t4 = k >> 6, ci = k & 63;
        int p = par >> 1, q = par & 1, dh = t4 >> 1, dw = t4 & 1;
        int tap = (p + 2 * dh) * 4 + (q + 2 * dw);
        int co = nt * 16 + (lane & 15);
        float f = dt3_w[((long)co * 64 + ci) * 16 + tap];
        unsigned short hi = f2bf(f);
        WBd3[par * 16384 + rem] = hi;
        WBd3[par * 16384 + 8192 + rem] = f2bf(f - bf2f(hi));
    } else if (idx < 67968) {
        int li = idx - 67584;
        int t4 = li & 3, par = (li >> 2) & 3;
        int co = (li >> 4) % 3, ci4 = (li >> 4) / 3;
        int p = par >> 1, q = par & 1, dh = t4 >> 1, dw = t4 & 1;
        int tap = (p + 2 * dh) * 4 + (q + 2 * dw);
        float4 v; float* pv = (float*)&v;
#pragma unroll
        for (int l = 0; l < 4; ++l)
            pv[l] = dt4_w[((long)co * 32 + ci4 * 4 + l) * 16 + tap];
        WTd4[li] = v;
    }
}

__global__ void prep_r1(const float* __restrict__ wih_e, const float* __restrict__ wih_d,
                        const float* __restrict__ fc_w,
                        const float* __restrict__ bih_d, const float* __restrict__ bhh_d,
                        const float* __restrict__ fc_b,
                        const float* __restrict__ fcmu_w, const float* __restrict__ dfc_w,
                        const float* __restrict__ dfc_b,
                        float* __restrict__ WIHP_E, float* __restrict__ WIHP_D,
                        float* __restrict__ FCP, float* __restrict__ BIASDC,
                        float* __restrict__ FCMUP, float* __restrict__ DFCP,
                        float* __restrict__ DFCB) {
    int idx = blockIdx.x * 256 + threadIdx.x;
    if (idx < 262144) {
        int c = idx & 2047, m = idx >> 11;
        WIHP_E[idx] = wih_e[orig_row(c) * 128 + m];
    } else if (idx < 524288) {
        int li = idx - 262144;
        int c = li & 2047, m = li >> 11;
        WIHP_D[li] = wih_d[orig_row(c) * 128 + m];
    } else if (idx < 589824) {
        int li = idx - 524288;
        int r = li & 127, c = li >> 7;
        FCP[li] = fc_w[(long)r * 512 + c];
    } else if (idx < 591872) {
        int c = idx - 589824;
        int orow = orig_row(c);
        float s = bih_d[orow] + bhh_d[orow];
        for (int m = 0; m < 128; ++m) s += fc_b[m] * wih_d[orow * 128 + m];
        BIASDC[c] = s;
    } else if (idx < 1116160) {
        int li = idx - 591872;
        int j = li & 127, k = li >> 7;
        FCMUP[li] = fcmu_w[(long)j * 4096 + (k & 255) * 16 + (k >> 8)];
    } else {
        int li = idx - 1116160;
        int j = li & 4095, m = li >> 12;
        int jc = (j & 255) * 16 + (j >> 8);
        DFCP[li] = dfc_w[(long)jc * 128 + m];
        if (li < 4096) DFCB[li] = dfc_b[(li & 255) * 16 + (li >> 8)];
    }
}

__global__ void to_nhwc4v(const float* __restrict__ v, float4* __restrict__ out) {
    int idx = blockIdx.x * 256 + threadIdx.x;  // 1,048,576
    int w = idx & 63, h = (idx >> 6) & 63, n = idx >> 12;
    long base = (long)n * 12288 + h * 64 + w;
    float4 o;
    o.x = v[base];
    o.y = v[base + 4096];
    o.z = v[base + 8192];
    o.w = 0.f;
    out[idx] = o;
}

__global__ void pack_whh(const float* __restrict__ whh, float4* __restrict__ out) {
    int idx = blockIdx.x * 256 + threadIdx.x;  // 262144
    int c = idx & 2047, k4 = idx >> 11;
    const float4* src = (const float4*)(whh + orig_row(c) * 512);
    out[idx] = src[k4];
}

__global__ __launch_bounds__(256)
void merge_dc(const float* __restrict__ wih_d, const float* __restrict__ fc_w,
              const float* __restrict__ whh_d, float* __restrict__ out) {
    int cb = (blockIdx.x >> 3) * 64, kb = (blockIdx.x & 7) * 64;
    int tid = threadIdx.x;
    int cgl = (tid & 15) * 4, kgl = (tid >> 4) * 4;
    __shared__ float At[64][65];
    __shared__ float Bt[64][65];
    float acc[4][4] = {};
    for (int mc = 0; mc < 128; mc += 64) {
        __syncthreads();
        for (int i = tid; i < 4096; i += 256) {
            int cl = i >> 6, m = i & 63;
            At[cl][m] = wih_d[orig_row(cb + cl) * 128 + mc + m];
            Bt[cl][m] = fc_w[(mc + cl) * 512 + kb + m];
        }
        __syncthreads();
        for (int m = 0; m < 64; ++m) {
            float a[4], b[4];
#pragma unroll
            for (int i = 0; i < 4; ++i) { a[i] = At[cgl + i][m]; b[i] = Bt[m][kgl + i]; }
#pragma unroll
            for (int i = 0; i < 4; ++i)
#pragma unroll
                for (int j = 0; j < 4; ++j) acc[i][j] += a[i] * b[j];
        }
    }
    for (int i = 0; i < 4; ++i) {
        int c = cb + cgl + i; int orow = orig_row(c);
        for (int j = 0; j < 4; ++j) {
            int k = kb + kgl + j;
            out[((k >> 2) * 2048 + c) * 4 + (k & 3)] = acc[i][j] + whh_d[orow * 512 + k];
        }
    }
}

// ============================ LSTM / FC path ================================
__global__ __launch_bounds__(512)
void gx2_kernel(const float* __restrict__ Z,
                const float* __restrict__ wE, const float* __restrict__ biE,
                const float* __restrict__ bhE,
                const float* __restrict__ wD, const float* __restrict__ biD,
                const float* __restrict__ bhD,
                float* __restrict__ gxe, float* __restrict__ gxd0) {
    __shared__ float zl[2048];
    int bid = blockIdx.x, tid = threadIdx.x;
    if (bid < 64) {
        int rg = bid >> 2, cch = bid & 3;
        for (int i = tid; i < 2048; i += 512)
            zl[i] = Z[(long)(rg * 16 + (i >> 7)) * 128 + (i & 127)];
        __syncthreads();
        int c = cch * 512 + tid;
        int orow = orig_row(c);
        float bsum = biE[orow] + bhE[orow];
        float acc[16];
#pragma unroll
        for (int r = 0; r < 16; ++r) acc[r] = bsum;
        for (int m = 0; m < 128; ++m) {
            float wv = wE[m * 2048 + c];
#pragma unroll
            for (int r = 0; r < 16; ++r) acc[r] += zl[r * 128 + m] * wv;
        }
        for (int r = 0; r < 16; ++r) gxe[(long)(rg * 16 + r) * 2048 + c] = acc[r];
    } else {
        int cch = bid - 64;
        for (int i = tid; i < 2048; i += 512)
            zl[i] = Z[(long)((i >> 7) * 16 + 15) * 128 + (i & 127)];
        __syncthreads();
        int c = cch * 512 + tid;
        int orow = orig_row(c);
        float bsum = biD[orow] + bhD[orow];
        float acc[16];
#pragma unroll
        for (int r = 0; r < 16; ++r) acc[r] = bsum;
        for (int m = 0; m < 128; ++m) {
            float wv = wD[m * 2048 + c];
#pragma unroll
            for (int r = 0; r < 16; ++r) acc[r] += zl[r * 128 + m] * wv;
        }
        for (int r = 0; r < 16; ++r) gxd0[(long)r * 2048 + c] = acc[r];
    }
}

__global__ __launch_bounds__(512)
void lstm_step(const float4* __restrict__ wh4, const float* __restrict__ gadd,
               int gstride, const float* __restrict__ h_in, float* __restrict__ h_out,
               float* __restrict__ cst, float* __restrict__ hall) {
    __shared__ float hs[8192];
    __shared__ float gb[16][32];
    int tid = threadIdx.x;
    float4* hs4 = (float4*)hs;
    const float4* hi4 = (const float4*)h_in;
#pragma unroll
    for (int i = 0; i < 4; ++i) hs4[tid + 512 * i] = hi4[tid + 512 * i];
    __syncthreads();
    int col = tid & 31, n = tid >> 5;
    int cg = blockIdx.x * 32 + col;
    float acc = gadd[n * gstride + cg];
    const float4* wp = wh4 + cg;
    const float4* hv = (const float4*)(hs + n * 512);
#pragma unroll 8
    for (int k4 = 0; k4 < 128; ++k4) {
        float4 wv = wp[(long)k4 * 2048];
        float4 h4 = hv[k4];
        acc += wv.x * h4.x + wv.y * h4.y + wv.z * h4.z + wv.w * h4.w;
    }
    gb[n][col] = acc;
    __syncthreads();
    if (col < 8) {
        int j = blockIdx.x * 8 + col;
        float gi = sig_(gb[n][col]);
        float gf = sig_(gb[n][col + 8]);
        float gg = tanhf(gb[n][col + 16]);
        float go = sig_(gb[n][col + 24]);
        int idx = n * 512 + j;
        float cv = gf * cst[idx] + gi * gg;
        cst[idx] = cv;
        float hvv = go * tanhf(cv);
        h_out[idx] = hvv;
        if (hall) hall[idx] = hvv;
    }
}

__global__ __launch_bounds__(512)
void fcmu_part(const unsigned short* __restrict__ xh,
               const float* __restrict__ wP, float* __restrict__ part) {
    int rg = blockIdx.x >> 3, ks = blockIdx.x & 7;
    int tid = threadIdx.x;
    __shared__ float xls[16 * 512];
    for (int i = tid; i < 8192; i += 512) {
        long gi = (long)(rg * 16 + (i >> 9)) * 4096 + ks * 512 + (i & 511);
        xls[i] = bf2f(xh[gi]);
    }
    __syncthreads();
    int j = tid & 127, rq = tid >> 7;
    float acc[4] = {0, 0, 0, 0};
    for (int k = 0; k < 512; ++k) {
        float wv = wP[(ks * 512 + k) * 128 + j];
#pragma unroll
        for (int i = 0; i < 4; ++i) acc[i] += xls[(rq + 4 * i) * 512 + k] * wv;
    }
    for (int i = 0; i < 4; ++i)
        part[((long)ks * 256 + rg * 16 + rq + 4 * i) * 128 + j] = acc[i];
}

__global__ void fcmu_red(const float* __restrict__ part, const float* __restrict__ b,
                         float* __restrict__ z) {
    int idx = blockIdx.x * 256 + threadIdx.x;  // 32768
    float s = b[idx & 127];
    for (int k = 0; k < 8; ++k) s += part[k * 32768 + idx];
    z[idx] = s;
}

__global__ __launch_bounds__(512)
void zs_k(const float* __restrict__ hall, const float* __restrict__ fcP,
          const float* __restrict__ fcb, float* __restrict__ zs) {
    int t = blockIdx.x;
    int tid = threadIdx.x;
    __shared__ float hs[8192];
    const float* h = hall + t * 8192;
    for (int i = tid; i < 8192; i += 512) hs[i] = h[i];
    __syncthreads();
    int j = tid & 127, ng = tid >> 7;
    float acc[4] = {0, 0, 0, 0};
    for (int k = 0; k < 512; ++k) {
        float wv = fcP[k * 128 + j];
#pragma unroll
        for (int i = 0; i < 4; ++i) acc[i] += hs[(ng + 4 * i) * 512 + k] * wv;
    }
    float bv = fcb[j];
    for (int i = 0; i < 4; ++i)
        zs[((ng + 4 * i) * 16 + t) * 128 + j] = acc[i] + bv;
}

__global__ __launch_bounds__(512)
void dfc_k(const float* __restrict__ zs, const float* __restrict__ dP,
           const float* __restrict__ db, unsigned short* __restrict__ outh) {
    int rg = blockIdx.x >> 3, jc = blockIdx.x & 7;
    int tid = threadIdx.x;
    __shared__ float zl[16 * 128];
    for (int i = tid; i < 2048; i += 512) zl[i] = zs[(long)rg * 2048 + i];
    __syncthreads();
    int j = jc * 512 + tid;
    float acc[16];
#pragma unroll
    for (int r = 0; r < 16; ++r) acc[r] = 0.f;
    for (int m = 0; m < 128; ++m) {
        float wv = dP[(long)m * 4096 + j];
#pragma unroll
        for (int r = 0; r < 16; ++r) acc[r] += zl[r * 128 + m] * wv;
    }
    float bv = db[j];
    for (int r = 0; r < 16; ++r) {
        float v = fmaxf(acc[r] + bv, 0.f);
        outh[(long)(rg * 16 + r) * 4096 + j] = f2bf(v);
    }
}

extern "C" void kernel_launch(void* const* d_in, const int* in_sizes, int n_in,
                              void* d_out, int out_size, void* d_ws, size_t ws_size,
                              hipStream_t stream) {
    (void)in_sizes; (void)n_in; (void)out_size; (void)ws_size;
    const float* video  = (const float*)d_in[0];
    const float* ec1_w  = (const float*)d_in[2];  const float* ec1_b = (const float*)d_in[3];
    const float* ec2_w  = (const float*)d_in[4];  const float* ec2_b = (const float*)d_in[5];
    const float* ec3_w  = (const float*)d_in[6];  const float* ec3_b = (const float*)d_in[7];
    const float* ec4_w  = (const float*)d_in[8];  const float* ec4_b = (const float*)d_in[9];
    const float* fcmu_w = (const float*)d_in[10]; const float* fcmu_b = (const float*)d_in[11];
    const float* dfc_w  = (const float*)d_in[12]; const float* dfc_b = (const float*)d_in[13];
    const float* dt1_w  = (const float*)d_in[14]; const float* dt1_b = (const float*)d_in[15];
    const float* dt2_w  = (const float*)d_in[16]; const float* dt2_b = (const float*)d_in[17];
    const float* dt3_w  = (const float*)d_in[18]; const float* dt3_b = (const float*)d_in[19];
    const float* dt4_w  = (const float*)d_in[20]; const float* dt4_b = (const float*)d_in[21];
    const float* wih_e  = (const float*)d_in[22]; const float* whh_e = (const float*)d_in[23];
    const float* bih_e  = (const float*)d_in[24]; const float* bhh_e = (const float*)d_in[25];
    const float* wih_d  = (const float*)d_in[26]; const float* whh_d = (const float*)d_in[27];
    const float* bih_d  = (const float*)d_in[28]; const float* bhh_d = (const float*)d_in[29];
    const float* fc_w   = (const float*)d_in[30]; const float* fc_b  = (const float*)d_in[31];

    char* wsb = (char*)d_ws;
    unsigned short* B1h = (unsigned short*)wsb;              // 8,388,608 e
    float*          X0f = (float*)(wsb + 33554432);
    unsigned short* B2h = (unsigned short*)(wsb + 33554432); // 4,194,304 e
    unsigned short* B3h = (unsigned short*)(wsb + 50331648); // 2,097,152 e
    unsigned short* B4h = (unsigned short*)(wsb + 58720256); // 1,048,576 e
    float* R1f    = (float*)wsb;
    float* WH4_E  = R1f;
    float* WH4_DC = R1f + 1048576;
    float* WIHP_E = R1f + 2097152;
    float* WIHP_D = R1f + 2359296;
    float* GX_E   = R1f + 2621440;
    float* GX_D0  = R1f + 3145728;
    float* BIASDC = R1f + 3178496;
    float* HA     = R1f + 3180544;
    float* HB     = R1f + 3188736;
    float* CB     = R1f + 3196928;
    float* HALL   = R1f + 3205120;
    float* FCMUP  = R1f + 3336192;
    float* ZPART  = R1f + 3860480;
    float* FCP    = R1f + 4122624;
    float* DFCP   = R1f + 4188160;
    float* DFCB   = R1f + 4712448;
    float* Z      = R1f + 4716544;
    float* ZS     = R1f + 4749312;
    unsigned short* WBe3 = (unsigned short*)(R1f + 4782080);
    unsigned short* WBe4 = (unsigned short*)(R1f + 4913152);
    unsigned short* WBd1 = (unsigned short*)(R1f + 5437440);
    unsigned short* WBd2 = (unsigned short*)(R1f + 5961728);
    unsigned short* WBe1 = (unsigned short*)(wsb + 62914560);
    unsigned short* WBe2 = (unsigned short*)(wsb + 62922752);
    unsigned short* WBd3 = (unsigned short*)(wsb + 63053824);
    float*          WTd4 = (float*)(wsb + 63184896);

    // ---- merged tail prep + encoder ec1/ec2 ----
    prep_tail<<<266, 256, 0, stream>>>(ec1_w, ec2_w, dt3_w, dt4_w,
                                       WBe1, WBe2, WBd3, (float4*)WTd4);
    to_nhwc4v<<<4096, 256, 0, stream>>>(video, (float4*)X0f);
    conv_mfma<4, 64, 64, 32, 2, 4, 1, 0, 1><<<1024, 256, 0, stream>>>(
        nullptr, X0f, WBe1, ec1_b, B1h);
    conv_mfma<32, 32, 32, 64, 2, 2, 2, 0, 0><<<512, 256, 0, stream>>>(
        B1h, nullptr, WBe2, ec2_b, B2h);

    // ---- R1 free: merged prep + big packs ----
    prep_r1<<<6408, 256, 0, stream>>>(wih_e, wih_d, fc_w, bih_d, bhh_d, fc_b,
                                      fcmu_w, dfc_w, dfc_b,
                                      WIHP_E, WIHP_D, FCP, BIASDC, FCMUP, DFCP, DFCB);
    pack_wb_conv<64, 64, 128><<<512, 256, 0, stream>>>(ec3_w, WBe3);
    pack_wb_conv<128, 128, 256><<<2048, 256, 0, stream>>>(ec4_w, WBe4);
    pack_wb_convt<256, 128><<<2048, 256, 0, stream>>>(dt1_w, WBd1);
    pack_wb_convt<128, 64><<<512, 256, 0, stream>>>(dt2_w, WBd2);
    pack_whh<<<1024, 256, 0, stream>>>(whh_e, (float4*)WH4_E);
    merge_dc<<<256, 256, 0, stream>>>(wih_d, fc_w, whh_d, WH4_DC);
    hipMemsetAsync(HA, 0, 3 * 8192 * sizeof(float), stream);

    // ---- encoder ec3/ec4 + fcmu ----
    conv_mfma<64, 16, 16, 128, 2, 2, 2, 0, 0><<<256, 256, 0, stream>>>(
        B2h, nullptr, WBe3, ec3_b, B3h);
    conv_mfma<128, 8, 8, 256, 1, 2, 2, 0, 0><<<256, 256, 0, stream>>>(
        B3h, nullptr, WBe4, ec4_b, B4h);
    fcmu_part<<<128, 512, 0, stream>>>(B4h, FCMUP, ZPART);
    fcmu_red<<<128, 256, 0, stream>>>(ZPART, fcmu_b, Z);

    // ---- merged x projections ----
    gx2_kernel<<<68, 512, 0, stream>>>(Z, WIHP_E, bih_e, bhh_e,
                                       WIHP_D, bih_d, bhh_d, GX_E, GX_D0);

    // ---- LSTM chains (per-step launches; coop grid-sync measured 5x slower) ----
    float* hin = HA; float* hout = HB;
    for (int t = 0; t < 16; ++t) {
        lstm_step<<<64, 512, 0, stream>>>((const float4*)WH4_E, GX_E + t * 2048, 32768,
                                          hin, hout, CB, (float*)nullptr);
        float* tmp = hin; hin = hout; hout = tmp;
    }
    pack_whh<<<1024, 256, 0, stream>>>(whh_d, (float4*)WH4_E);  // reuse for dec step 0
    lstm_step<<<64, 512, 0, stream>>>((const float4*)WH4_E, GX_D0, 2048,
                                      hin, hout, CB, HALL);
    { float* tmp = hin; hin = hout; hout = tmp; }
    for (int t = 1; t < 16; ++t) {
        lstm_step<<<64, 512, 0, stream>>>((const float4*)WH4_DC, BIASDC, 0,
                                          hin, hout, CB, HALL + t * 8192);
        float* tmp = hin; hin = hout; hout = tmp;
    }
    zs_k<<<16, 512, 0, stream>>>(HALL, FCP, fc_b, ZS);

    // ---- decoder ----
    dfc_k<<<128, 512, 0, stream>>>(ZS, DFCP, DFCB, B4h);
    conv_mfma<256, 4, 4, 128, 1, 2, 2, 1, 0><<<512, 256, 0, stream>>>(
        B4h, nullptr, WBd1, dt1_b, B3h);
    conv_mfma<128, 8, 8, 64, 2, 2, 2, 1, 0><<<512, 256, 0, stream>>>(
        B3h, nullptr, WBd2, dt2_b, B2h);
    conv_mfma<64, 16, 16, 32, 2, 4, 1, 1, 0><<<1024, 256, 0, stream>>>(
        B2h, nullptr, WBd3, dt3_b, B1h);
    dt4_tiled<<<1024, 256, 0, stream>>>(B1h, (const float4*)WTd4, dt4_b, (float*)d_out);
}

// Round 11
// 618.915 us; speedup vs baseline: 4.0476x; 1.1320x over previous
//
#include <hip/hip_runtime.h>
#include <math.h>

// ---------------------------------------------------------------------------
// CNN-LSTM video predictor, round 11: conv grids >=512 blocks (occupancy),
// LSTM chain re-partitioned to 128 blocks x 16 cols (L1-resident weights,
// new orig_row permutation shared by all packs), dt4 4-row stripes,
// pack launches merged. Core math = round 10 (700us, absmax 2e-3).
// ---------------------------------------------------------------------------

typedef float f32x4 __attribute__((ext_vector_type(4)));
typedef short bf16x8 __attribute__((ext_vector_type(8)));

__device__ __forceinline__ float sig_(float x) { return 1.f / (1.f + expf(-x)); }
__device__ __forceinline__ float dot4(float4 a, float4 b) {
    return a.x * b.x + a.y * b.y + a.z * b.z + a.w * b.w;
}
// LSTM column permutation (16 cols/block, 4 j per block, 128 blocks):
// c = b*16 + g*4 + jl  ->  orig gate row g*512 + b*4 + jl
__device__ __forceinline__ int orig_row(int c) {
    return ((c >> 2) & 3) * 512 + (c >> 4) * 4 + (c & 3);
}
__device__ __forceinline__ unsigned short f2bf(float f) {
    unsigned int b = __float_as_uint(f);
    return (unsigned short)((b + 0x7fffu + ((b >> 16) & 1u)) >> 16);
}
__device__ __forceinline__ float bf2f(unsigned short h) {
    return __uint_as_float(((unsigned int)h) << 16);
}
__device__ __forceinline__ float4 bf4_to_f4(uint2 u) {
    float4 r;
    r.x = __uint_as_float((u.x & 0xffffu) << 16);
    r.y = __uint_as_float(u.x & 0xffff0000u);
    r.z = __uint_as_float((u.y & 0xffffu) << 16);
    r.w = __uint_as_float(u.y & 0xffff0000u);
    return r;
}

// =================== MFMA conv / convT (A bf16, W split) ====================
template<int CIP, int HI, int WI, int CO, int MREP, int WM, int WN, int MODE, int SRCF32>
__global__ __launch_bounds__(64 * WM * WN)
void conv_mfma(const unsigned short* __restrict__ Ahi, const float* __restrict__ Af,
               const unsigned short* __restrict__ WB, const float* __restrict__ bias,
               unsigned short* __restrict__ Yhi) {
    constexpr int K    = CIP * (MODE ? 4 : 16);
    constexpr int K32  = K / 32;
    constexpr int NI   = 2 * MREP;
    constexpr int TAPS = MODE ? 4 : 16;
    constexpr int CC   = (CIP >= 32) ? CIP / 32 : 1;
    constexpr int HO   = MODE ? HI * 2 : HI / 2;
    constexpr int WO   = MODE ? WI * 2 : WI / 2;
    constexpr int SH   = MODE ? HI : HI / 2;
    constexpr int SW   = MODE ? WI : WI / 2;
    constexpr int HWS  = SH * SW;
    constexpr int MT   = (256 * HWS) / (32 * MREP * WM);
    constexpr int NT   = CO / (32 * WN);
    constexpr int PLANE = CO * K;

    int bid = blockIdx.x;
    int mt = bid % MT; bid /= MT;
    int nt = bid % NT; int par = bid / NT;
    int p = par >> 1, q = par & 1;

    int tid = threadIdx.x;
    int lane = tid & 63, wid = tid >> 6;
    int wm = wid % WM, wn = wid / WM;
    int mbase = mt * (32 * MREP * WM) + wm * (32 * MREP);
    int nbase = nt * (32 * WN) + wn * 32;
    int lm = lane & 15, lg = lane >> 4;

    int ani[NI], asy[NI], asx[NI];
#pragma unroll
    for (int i = 0; i < NI; ++i) {
        int m = mbase + 16 * i + lm;
        ani[i] = m / HWS; int r = m % HWS; asy[i] = r / SW; asx[i] = r % SW;
    }

    f32x4 acc[NI][2];
#pragma unroll
    for (int i = 0; i < NI; ++i)
#pragma unroll
        for (int j = 0; j < 2; ++j)
#pragma unroll
            for (int e = 0; e < 4; ++e) acc[i][j][e] = 0.f;

    const unsigned short* WBp = WB + (long)par * 2 * PLANE;

    if constexpr (SRCF32) {
        for (int kb = 0; kb < K; kb += 32) {
            int k0 = kb + lg * 8;
            int t0 = k0 >> 2;
            bf16x8 ah[NI];
#pragma unroll
            for (int i = 0; i < NI; ++i) {
                float f[8];
#pragma unroll
                for (int h = 0; h < 2; ++h) {
                    int tap = t0 + h;
                    int ih = 2 * asy[i] + (tap >> 2) - 1;
                    int iw = 2 * asx[i] + (tap & 3) - 1;
                    float4 v = {0.f, 0.f, 0.f, 0.f};
                    if ((unsigned)ih < (unsigned)HI && (unsigned)iw < (unsigned)WI)
                        v = *(const float4*)(Af + (((long)ani[i] * HI + ih) * WI + iw) * 4);
                    f[h * 4 + 0] = v.x; f[h * 4 + 1] = v.y;
                    f[h * 4 + 2] = v.z; f[h * 4 + 3] = v.w;
                }
#pragma unroll
                for (int e = 0; e < 8; ++e) ah[i][e] = (short)f2bf(f[e]);
            }
            bf16x8 bh[2], bl[2];
#pragma unroll
            for (int j = 0; j < 2; ++j) {
                long bidx = ((long)((nbase >> 4) + j) * K32 + (kb >> 5)) * 512 + lane * 8;
                bh[j] = *(const bf16x8*)(WBp + bidx);
                bl[j] = *(const bf16x8*)(WBp + PLANE + bidx);
            }
#pragma unroll
            for (int i = 0; i < NI; ++i)
#pragma unroll
                for (int j = 0; j < 2; ++j) {
                    acc[i][j] = __builtin_amdgcn_mfma_f32_16x16x32_bf16(ah[i], bh[j], acc[i][j], 0, 0, 0);
                    acc[i][j] = __builtin_amdgcn_mfma_f32_16x16x32_bf16(ah[i], bl[j], acc[i][j], 0, 0, 0);
                }
        }
    } else {
        long abase[NI]; unsigned vmask[NI];
#pragma unroll
        for (int i = 0; i < NI; ++i) {
            abase[i] = (long)ani[i] * HI * WI * CIP;
            unsigned vm = 0;
#pragma unroll
            for (int t = 0; t < TAPS; ++t) {
                int iy, ix;
                if constexpr (MODE == 0) {
                    iy = 2 * asy[i] + (t >> 2) - 1; ix = 2 * asx[i] + (t & 3) - 1;
                } else {
                    iy = asy[i] + p + (t >> 1) - 1; ix = asx[i] + q + (t & 1) - 1;
                }
                if (iy >= 0 && iy < HI && ix >= 0 && ix < WI) vm |= (1u << t);
            }
            vmask[i] = vm;
        }
#pragma unroll 2
        for (int tap = 0; tap < TAPS; ++tap) {
            int dy, dx;
            if constexpr (MODE == 0) { dy = (tap >> 2) - 1; dx = (tap & 3) - 1; }
            else { dy = p + (tap >> 1) - 1; dx = q + (tap & 1) - 1; }
            long roff[NI]; unsigned msk[NI];
#pragma unroll
            for (int i = 0; i < NI; ++i) {
                int iy = (MODE == 0 ? 2 * asy[i] : asy[i]) + dy;
                int ix = (MODE == 0 ? 2 * asx[i] : asx[i]) + dx;
                int iyc = min(max(iy, 0), HI - 1);
                int ixc = min(max(ix, 0), WI - 1);
                roff[i] = abase[i] + ((long)iyc * WI + ixc) * CIP + lg * 8;
                msk[i] = ((vmask[i] >> tap) & 1u) ? 0xffffffffu : 0u;
            }
#pragma unroll
            for (int cc = 0; cc < CC; ++cc) {
                int kb32 = tap * CC + cc;
                bf16x8 ah[NI];
#pragma unroll
                for (int i = 0; i < NI; ++i) {
                    uint4 u = *(const uint4*)(Ahi + roff[i] + cc * 32);
                    u.x &= msk[i]; u.y &= msk[i]; u.z &= msk[i]; u.w &= msk[i];
                    ah[i] = *(bf16x8*)&u;
                }
                bf16x8 bh[2], bl[2];
#pragma unroll
                for (int j = 0; j < 2; ++j) {
                    long bidx = ((long)((nbase >> 4) + j) * K32 + kb32) * 512 + lane * 8;
                    bh[j] = *(const bf16x8*)(WBp + bidx);
                    bl[j] = *(const bf16x8*)(WBp + PLANE + bidx);
                }
#pragma unroll
                for (int i = 0; i < NI; ++i)
#pragma unroll
                    for (int j = 0; j < 2; ++j) {
                        acc[i][j] = __builtin_amdgcn_mfma_f32_16x16x32_bf16(ah[i], bh[j], acc[i][j], 0, 0, 0);
                        acc[i][j] = __builtin_amdgcn_mfma_f32_16x16x32_bf16(ah[i], bl[j], acc[i][j], 0, 0, 0);
                    }
            }
        }
    }

#pragma unroll
    for (int i = 0; i < NI; ++i)
#pragma unroll
        for (int j = 0; j < 2; ++j)
#pragma unroll
            for (int r = 0; r < 4; ++r) {
                int m = mbase + 16 * i + lg * 4 + r;
                int co = nbase + 16 * j + lm;
                float v = fmaxf(acc[i][j][r] + bias[co], 0.f);
                long off;
                if constexpr (MODE == 0) {
                    off = (long)m * CO + co;
                } else {
                    int ni = m / HWS; int rm = m % HWS;
                    int oy = 2 * (rm / SW) + p, ox = 2 * (rm % SW) + q;
                    off = (((long)ni * HO + oy) * WO + ox) * CO + co;
                }
                Yhi[off] = f2bf(v);
            }
}

// ====== dt4: LDS-tiled (bf16 LDS), 4-row stripes, CO=3, sigmoid, NCHW =======
__global__ __launch_bounds__(128)
void dt4_tiled(const unsigned short* __restrict__ Xh,
               const float4* __restrict__ Wd, const float* __restrict__ bias,
               float* __restrict__ out) {
    __shared__ uint2 xt[8 * 205];  // 6 rows x 34 cols per c4 (pos = r*34+cc)
    int bid = blockIdx.x;
    int n = bid >> 3, yg = bid & 7;
    int y0 = yg * 4;
    int tid = threadIdx.x;
    long nb = (long)n * 32768;
    for (int j = tid; j < 1632; j += 128) {   // 8 c4 x 204 pos
        int c4 = j & 7; int pos = j >> 3;
        int r = pos / 34, cc = pos % 34;
        int ih = y0 - 1 + r, iw = cc - 1;
        uint2 u = {0u, 0u};
        if ((unsigned)ih < 32u && (unsigned)iw < 32u)
            u = *(const uint2*)(Xh + nb + ((long)ih * 32 + iw) * 32 + c4 * 4);
        xt[c4 * 205 + pos] = u;
    }
    __syncthreads();
    int ly = tid >> 5, lx = tid & 31;   // ly in [0,4)
    float acc[3][4];
#pragma unroll
    for (int j = 0; j < 3; ++j) {
        float b = bias[j];
#pragma unroll
        for (int par = 0; par < 4; ++par) acc[j][par] = b;
    }
#pragma unroll
    for (int ci4 = 0; ci4 < 8; ++ci4) {
        float4 xv[9];
        int base = ci4 * 205 + ly * 34 + lx;
#pragma unroll
        for (int r = 0; r < 3; ++r)
#pragma unroll
            for (int c = 0; c < 3; ++c)
                xv[r * 3 + c] = bf4_to_f4(xt[base + r * 34 + c]);
        const float4* wp = Wd + ci4 * 48;
#pragma unroll
        for (int j = 0; j < 3; ++j)
#pragma unroll
            for (int par = 0; par < 4; ++par) {
                int p = par >> 1, q = par & 1;
#pragma unroll
                for (int t4 = 0; t4 < 4; ++t4) {
                    int dh = t4 >> 1, dw = t4 & 1;
                    acc[j][par] += dot4(xv[(p + dh) * 3 + (q + dw)],
                                        wp[(j * 4 + par) * 4 + t4]);
                }
            }
    }
    int yy = y0 + ly, xx = lx;
#pragma unroll
    for (int j = 0; j < 3; ++j)
#pragma unroll
        for (int p = 0; p < 2; ++p) {
            float2 v;
            v.x = sig_(acc[j][p * 2 + 0]);
            v.y = sig_(acc[j][p * 2 + 1]);
            *(float2*)(out + (((long)n * 3 + j) * 64 + 2 * yy + p) * 64 + 2 * xx) = v;
        }
}

// ========================= weight / layout prep =============================
// merged big packs: ec3 + ec4 (conv) + dt1 + dt2 (convt). 5120 blocks.
__global__ void prep_packs(const float* __restrict__ ec3_w, const float* __restrict__ ec4_w,
                           const float* __restrict__ dt1_w, const float* __restrict__ dt2_w,
                           unsigned short* __restrict__ WBe3, unsigned short* __restrict__ WBe4,
                           unsigned short* __restrict__ WBd1, unsigned short* __restrict__ WBd2) {
    int idx = blockIdx.x * 256 + threadIdx.x;
    if (idx < 131072) {  // ec3 conv: CI=64 CO=128 K=1024
        int li = idx;
        int j = li & 7, lane = (li >> 3) & 63;
        int kb = (li >> 9) & 31, nt = li >> 14;
        int k = kb * 32 + (lane >> 4) * 8 + j;
        int tap = k >> 6, ci = k & 63;
        int co = nt * 16 + (lane & 15);
        float f = ec3_w[((long)co * 64 + ci) * 16 + tap];
        unsigned short hi = f2bf(f);
        WBe3[li] = hi; WBe3[131072 + li] = f2bf(f - bf2f(hi));
    } else if (idx < 655360) {  // ec4 conv: CI=128 CO=256 K=2048
        int li = idx - 131072;
        int j = li & 7, lane = (li >> 3) & 63;
        int kb = (li >> 9) & 63, nt = li >> 15;
        int k = kb * 32 + (lane >> 4) * 8 + j;
        int tap = k >> 7, ci = k & 127;
        int co = nt * 16 + (lane & 15);
        float f = ec4_w[((long)co * 128 + ci) * 16 + tap];
        unsigned short hi = f2bf(f);
        WBe4[li] = hi; WBe4[524288 + li] = f2bf(f - bf2f(hi));
    } else if (idx < 1179648) {  // dt1 convt: CI=256 CO=128 Kp=1024
        int li = idx - 655360;
        int par = li >> 17; int rem = li & 131071;
        int j = rem & 7, lane = (rem >> 3) & 63;
        int kb = (rem >> 9) & 31, nt = rem >> 14;
        int k = kb * 32 + (lane >> 4) * 8 + j;
        int t4 = k >> 8, ci = k & 255;
        int p = par >> 1, q = par & 1, dh = t4 >> 1, dw = t4 & 1;
        int tap = (p + 2 * dh) * 4 + (q + 2 * dw);
        int co = nt * 16 + (lane & 15);
        float f = dt1_w[((long)co * 256 + ci) * 16 + tap];
        unsigned short hi = f2bf(f);
        WBd1[(long)par * 262144 + rem] = hi;
        WBd1[(long)par * 262144 + 131072 + rem] = f2bf(f - bf2f(hi));
    } else if (idx < 1310720) {  // dt2 convt: CI=128 CO=64 Kp=512
        int li = idx - 1179648;
        int par = li >> 15; int rem = li & 32767;
        int j = rem & 7, lane = (rem >> 3) & 63;
        int kb = (rem >> 9) & 15, nt = rem >> 13;
        int k = kb * 32 + (lane >> 4) * 8 + j;
        int t4 = k >> 7, ci = k & 127;
        int p = par >> 1, q = par & 1, dh = t4 >> 1, dw = t4 & 1;
        int tap = (p + 2 * dh) * 4 + (q + 2 * dw);
        int co = nt * 16 + (lane & 15);
        float f = dt2_w[((long)co * 128 + ci) * 16 + tap];
        unsigned short hi = f2bf(f);
        WBd2[(long)par * 65536 + rem] = hi;
        WBd2[(long)par * 65536 + 32768 + rem] = f2bf(f - bf2f(hi));
    }
}

__global__ void prep_tail(const float* __restrict__ ec1_w, const float* __restrict__ ec2_w,
                          const float* __restrict__ dt3_w, const float* __restrict__ dt4_w,
                          unsigned short* __restrict__ WBe1, unsigned short* __restrict__ WBe2,
                          unsigned short* __restrict__ WBd3, float4* __restrict__ WTd4) {
    int idx = blockIdx.x * 256 + threadIdx.x;
    if (idx < 2048) {
        int li = idx;
        int j = li & 7, lane = (li >> 3) & 63;
        int kb = (li >> 9) & 1, nt = li / 1024;
        int k = kb * 32 + (lane >> 4) * 8 + j;
        int tap = k >> 2, ci = k & 3;
        int co = nt * 16 + (lane & 15);
        float f = (ci < 3) ? ec1_w[((long)co * 3 + ci) * 16 + tap] : 0.f;
        unsigned short hi = f2bf(f);
        WBe1[li] = hi; WBe1[2048 + li] = f2bf(f - bf2f(hi));
    } else if (idx < 34816) {
        int li = idx - 2048;
        int j = li & 7, lane = (li >> 3) & 63;
        int kb = (li >> 9) & 15, nt = li / 8192;
        int k = kb * 32 + (lane >> 4) * 8 + j;
        int tap = k >> 5, ci = k & 31;
        int co = nt * 16 + (lane & 15);
        float f = ec2_w[((long)co * 32 + ci) * 16 + tap];
        unsigned short hi = f2bf(f);
        WBe2[li] = hi; WBe2[32768 + li] = f2bf(f - bf2f(hi));
    } else if (idx < 67584) {
        int li = idx - 34816;
        int par = li >> 13; int rem = li & 8191;
        int j = rem & 7, lane = (rem >> 3) & 63;
        int kb = (rem >> 9) & 7, nt = rem >> 12;
        int k = kb * 32 + (lane >> 4) * 8 + j;
        int t4 = k >> 6, ci = k & 63;
        int p = par >> 1, q = par & 1, dh = t4 >> 1, dw = t4 & 1;
        int tap = (p + 2 * dh) * 4 + (q + 2 * dw);
        int co = nt * 16 + (lane & 15);
        float f = dt3_w[((long)co * 64 + ci) * 16 + tap];
        unsigned short hi = f2bf(f);
        WBd3[par * 16384 + rem] = hi;
        WBd3[par * 16384 + 8192 + rem] = f2bf(f - bf2f(hi));
    } else if (idx < 67968) {
        int li = idx - 67584;
        int t4 = li & 3, par = (li >> 2) & 3;
        int co = (li >> 4) % 3, ci4 = (li >> 4) / 3;
        int p = par >> 1, q = par & 1, dh = t4 >> 1, dw = t4 & 1;
        int tap = (p + 2 * dh) * 4 + (q + 2 * dw);
        float4 v; float* pv = (float*)&v;
#pragma unroll
        for (int l = 0; l < 4; ++l)
            pv[l] = dt4_w[((long)co * 32 + ci4 * 4 + l) * 16 + tap];
        WTd4[li] = v;
    }
}

__global__ void prep_r1(const float* __restrict__ wih_e, const float* __restrict__ wih_d,
                        const float* __restrict__ fc_w,
                        const float* __restrict__ bih_d, const float* __restrict__ bhh_d,
                        const float* __restrict__ fc_b,
                        const float* __restrict__ fcmu_w, const float* __restrict__ dfc_w,
                        const float* __restrict__ dfc_b,
                        float* __restrict__ WIHP_E, float* __restrict__ WIHP_D,
                        float* __restrict__ FCP, float* __restrict__ BIASDC,
                        float* __restrict__ FCMUP, float* __restrict__ DFCP,
                        float* __restrict__ DFCB) {
    int idx = blockIdx.x * 256 + threadIdx.x;
    if (idx < 262144) {
        int c = idx & 2047, m = idx >> 11;
        WIHP_E[idx] = wih_e[orig_row(c) * 128 + m];
    } else if (idx < 524288) {
        int li = idx - 262144;
        int c = li & 2047, m = li >> 11;
        WIHP_D[li] = wih_d[orig_row(c) * 128 + m];
    } else if (idx < 589824) {
        int li = idx - 524288;
        int r = li & 127, c = li >> 7;
        FCP[li] = fc_w[(long)r * 512 + c];
    } else if (idx < 591872) {
        int c = idx - 589824;
        int orow = orig_row(c);
        float s = bih_d[orow] + bhh_d[orow];
        for (int m = 0; m < 128; ++m) s += fc_b[m] * wih_d[orow * 128 + m];
        BIASDC[c] = s;
    } else if (idx < 1116160) {
        int li = idx - 591872;
        int j = li & 127, k = li >> 7;
        FCMUP[li] = fcmu_w[(long)j * 4096 + (k & 255) * 16 + (k >> 8)];
    } else {
        int li = idx - 1116160;
        int j = li & 4095, m = li >> 12;
        int jc = (j & 255) * 16 + (j >> 8);
        DFCP[li] = dfc_w[(long)jc * 128 + m];
        if (li < 4096) DFCB[li] = dfc_b[(li & 255) * 16 + (li >> 8)];
    }
}

__global__ void to_nhwc4v(const float* __restrict__ v, float4* __restrict__ out) {
    int idx = blockIdx.x * 256 + threadIdx.x;  // 1,048,576
    int w = idx & 63, h = (idx >> 6) & 63, n = idx >> 12;
    long base = (long)n * 12288 + h * 64 + w;
    float4 o;
    o.x = v[base];
    o.y = v[base + 4096];
    o.z = v[base + 8192];
    o.w = 0.f;
    out[idx] = o;
}

__global__ void pack_whh(const float* __restrict__ whh, float4* __restrict__ out) {
    int idx = blockIdx.x * 256 + threadIdx.x;  // 262144
    int c = idx & 2047, k4 = idx >> 11;
    const float4* src = (const float4*)(whh + orig_row(c) * 512);
    out[idx] = src[k4];
}

__global__ __launch_bounds__(256)
void merge_dc(const float* __restrict__ wih_d, const float* __restrict__ fc_w,
              const float* __restrict__ whh_d, float* __restrict__ out) {
    int cb = (blockIdx.x >> 3) * 64, kb = (blockIdx.x & 7) * 64;
    int tid = threadIdx.x;
    int cgl = (tid & 15) * 4, kgl = (tid >> 4) * 4;
    __shared__ float At[64][65];
    __shared__ float Bt[64][65];
    float acc[4][4] = {};
    for (int mc = 0; mc < 128; mc += 64) {
        __syncthreads();
        for (int i = tid; i < 4096; i += 256) {
            int cl = i >> 6, m = i & 63;
            At[cl][m] = wih_d[orig_row(cb + cl) * 128 + mc + m];
            Bt[cl][m] = fc_w[(mc + cl) * 512 + kb + m];
        }
        __syncthreads();
        for (int m = 0; m < 64; ++m) {
            float a[4], b[4];
#pragma unroll
            for (int i = 0; i < 4; ++i) { a[i] = At[cgl + i][m]; b[i] = Bt[m][kgl + i]; }
#pragma unroll
            for (int i = 0; i < 4; ++i)
#pragma unroll
                for (int j = 0; j < 4; ++j) acc[i][j] += a[i] * b[j];
        }
    }
    for (int i = 0; i < 4; ++i) {
        int c = cb + cgl + i; int orow = orig_row(c);
        for (int j = 0; j < 4; ++j) {
            int k = kb + kgl + j;
            out[((k >> 2) * 2048 + c) * 4 + (k & 3)] = acc[i][j] + whh_d[orow * 512 + k];
        }
    }
}

// ============================ LSTM / FC path ================================
__global__ __launch_bounds__(512)
void gx2_kernel(const float* __restrict__ Z,
                const float* __restrict__ wE, const float* __restrict__ biE,
                const float* __restrict__ bhE,
                const float* __restrict__ wD, const float* __restrict__ biD,
                const float* __restrict__ bhD,
                float* __restrict__ gxe, float* __restrict__ gxd0) {
    __shared__ float zl[2048];
    int bid = blockIdx.x, tid = threadIdx.x;
    if (bid < 64) {
        int rg = bid >> 2, cch = bid & 3;
        for (int i = tid; i < 2048; i += 512)
            zl[i] = Z[(long)(rg * 16 + (i >> 7)) * 128 + (i & 127)];
        __syncthreads();
        int c = cch * 512 + tid;
        int orow = orig_row(c);
        float bsum = biE[orow] + bhE[orow];
        float acc[16];
#pragma unroll
        for (int r = 0; r < 16; ++r) acc[r] = bsum;
        for (int m = 0; m < 128; ++m) {
            float wv = wE[m * 2048 + c];
#pragma unroll
            for (int r = 0; r < 16; ++r) acc[r] += zl[r * 128 + m] * wv;
        }
        for (int r = 0; r < 16; ++r) gxe[(long)(rg * 16 + r) * 2048 + c] = acc[r];
    } else {
        int cch = bid - 64;
        for (int i = tid; i < 2048; i += 512)
            zl[i] = Z[(long)((i >> 7) * 16 + 15) * 128 + (i & 127)];
        __syncthreads();
        int c = cch * 512 + tid;
        int orow = orig_row(c);
        float bsum = biD[orow] + bhD[orow];
        float acc[16];
#pragma unroll
        for (int r = 0; r < 16; ++r) acc[r] = bsum;
        for (int m = 0; m < 128; ++m) {
            float wv = wD[m * 2048 + c];
#pragma unroll
            for (int r = 0; r < 16; ++r) acc[r] += zl[r * 128 + m] * wv;
        }
        for (int r = 0; r < 16; ++r) gxd0[(long)r * 2048 + c] = acc[r];
    }
}

// one LSTM step: 128 blocks x 256 threads; block owns 16 cols (4 j x 4 gates)
__global__ __launch_bounds__(256)
void lstm_step(const float4* __restrict__ wh4, const float* __restrict__ gadd,
               int gstride, const float* __restrict__ h_in, float* __restrict__ h_out,
               float* __restrict__ cst, float* __restrict__ hall) {
    __shared__ float hs[8192];
    __shared__ float gb[16][16];
    int tid = threadIdx.x;
    float4* hs4 = (float4*)hs;
    const float4* hi4 = (const float4*)h_in;
#pragma unroll
    for (int i = 0; i < 8; ++i) hs4[tid + 256 * i] = hi4[tid + 256 * i];
    __syncthreads();
    int col = tid & 15, n = tid >> 4;
    int cg = blockIdx.x * 16 + col;
    float acc = gadd[n * gstride + cg];
    const float4* wp = wh4 + cg;
    const float4* hv = (const float4*)(hs + n * 512);
#pragma unroll 8
    for (int k4 = 0; k4 < 128; ++k4) {
        float4 wv = wp[(long)k4 * 2048];
        float4 h4 = hv[k4];
        acc += wv.x * h4.x + wv.y * h4.y + wv.z * h4.z + wv.w * h4.w;
    }
    gb[n][col] = acc;
    __syncthreads();
    if (col < 4) {
        int j = blockIdx.x * 4 + col;
        float gi = sig_(gb[n][col]);
        float gf = sig_(gb[n][col + 4]);
        float gg = tanhf(gb[n][col + 8]);
        float go = sig_(gb[n][col + 12]);
        int idx = n * 512 + j;
        float cv = gf * cst[idx] + gi * gg;
        cst[idx] = cv;
        float hvv = go * tanhf(cv);
        h_out[idx] = hvv;
        if (hall) hall[idx] = hvv;
    }
}

__global__ __launch_bounds__(512)
void fcmu_part(const unsigned short* __restrict__ xh,
               const float* __restrict__ wP, float* __restrict__ part) {
    int rg = blockIdx.x >> 3, ks = blockIdx.x & 7;
    int tid = threadIdx.x;
    __shared__ float xls[16 * 512];
    for (int i = tid; i < 8192; i += 512) {
        long gi = (long)(rg * 16 + (i >> 9)) * 4096 + ks * 512 + (i & 511);
        xls[i] = bf2f(xh[gi]);
    }
    __syncthreads();
    int j = tid & 127, rq = tid >> 7;
    float acc[4] = {0, 0, 0, 0};
    for (int k = 0; k < 512; ++k) {
        float wv = wP[(ks * 512 + k) * 128 + j];
#pragma unroll
        for (int i = 0; i < 4; ++i) acc[i] += xls[(rq + 4 * i) * 512 + k] * wv;
    }
    for (int i = 0; i < 4; ++i)
        part[((long)ks * 256 + rg * 16 + rq + 4 * i) * 128 + j] = acc[i];
}

__global__ void fcmu_red(const float* __restrict__ part, const float* __restrict__ b,
                         float* __restrict__ z) {
    int idx = blockIdx.x * 256 + threadIdx.x;  // 32768
    float s = b[idx & 127];
    for (int k = 0; k < 8; ++k) s += part[k * 32768 + idx];
    z[idx] = s;
}

__global__ __launch_bounds__(512)
void zs_k(const float* __restrict__ hall, const float* __restrict__ fcP,
          const float* __restrict__ fcb, float* __restrict__ zs) {
    int t = blockIdx.x;
    int tid = threadIdx.x;
    __shared__ float hs[8192];
    const float* h = hall + t * 8192;
    for (int i = tid; i < 8192; i += 512) hs[i] = h[i];
    __syncthreads();
    int j = tid & 127, ng = tid >> 7;
    float acc[4] = {0, 0, 0, 0};
    for (int k = 0; k < 512; ++k) {
        float wv = fcP[k * 128 + j];
#pragma unroll
        for (int i = 0; i < 4; ++i) acc[i] += hs[(ng + 4 * i) * 512 + k] * wv;
    }
    float bv = fcb[j];
    for (int i = 0; i < 4; ++i)
        zs[((ng + 4 * i) * 16 + t) * 128 + j] = acc[i] + bv;
}

__global__ __launch_bounds__(512)
void dfc_k(const float* __restrict__ zs, const float* __restrict__ dP,
           const float* __restrict__ db, unsigned short* __restrict__ outh) {
    int rg = blockIdx.x >> 3, jc = blockIdx.x & 7;
    int tid = threadIdx.x;
    __shared__ float zl[16 * 128];
    for (int i = tid; i < 2048; i += 512) zl[i] = zs[(long)rg * 2048 + i];
    __syncthreads();
    int j = jc * 512 + tid;
    float acc[16];
#pragma unroll
    for (int r = 0; r < 16; ++r) acc[r] = 0.f;
    for (int m = 0; m < 128; ++m) {
        float wv = dP[(long)m * 4096 + j];
#pragma unroll
        for (int r = 0; r < 16; ++r) acc[r] += zl[r * 128 + m] * wv;
    }
    float bv = db[j];
    for (int r = 0; r < 16; ++r) {
        float v = fmaxf(acc[r] + bv, 0.f);
        outh[(long)(rg * 16 + r) * 4096 + j] = f2bf(v);
    }
}

extern "C" void kernel_launch(void* const* d_in, const int* in_sizes, int n_in,
                              void* d_out, int out_size, void* d_ws, size_t ws_size,
                              hipStream_t stream) {
    (void)in_sizes; (void)n_in; (void)out_size; (void)ws_size;
    const float* video  = (const float*)d_in[0];
    const float* ec1_w  = (const float*)d_in[2];  const float* ec1_b = (const float*)d_in[3];
    const float* ec2_w  = (const float*)d_in[4];  const float* ec2_b = (const float*)d_in[5];
    const float* ec3_w  = (const float*)d_in[6];  const float* ec3_b = (const float*)d_in[7];
    const float* ec4_w  = (const float*)d_in[8];  const float* ec4_b = (const float*)d_in[9];
    const float* fcmu_w = (const float*)d_in[10]; const float* fcmu_b = (const float*)d_in[11];
    const float* dfc_w  = (const float*)d_in[12]; const float* dfc_b = (const float*)d_in[13];
    const float* dt1_w  = (const float*)d_in[14]; const float* dt1_b = (const float*)d_in[15];
    const float* dt2_w  = (const float*)d_in[16]; const float* dt2_b = (const float*)d_in[17];
    const float* dt3_w  = (const float*)d_in[18]; const float* dt3_b = (const float*)d_in[19];
    const float* dt4_w  = (const float*)d_in[20]; const float* dt4_b = (const float*)d_in[21];
    const float* wih_e  = (const float*)d_in[22]; const float* whh_e = (const float*)d_in[23];
    const float* bih_e  = (const float*)d_in[24]; const float* bhh_e = (const float*)d_in[25];
    const float* wih_d  = (const float*)d_in[26]; const float* whh_d = (const float*)d_in[27];
    const float* bih_d  = (const float*)d_in[28]; const float* bhh_d = (const float*)d_in[29];
    const float* fc_w   = (const float*)d_in[30]; const float* fc_b  = (const float*)d_in[31];

    char* wsb = (char*)d_ws;
    unsigned short* B1h = (unsigned short*)wsb;              // 8,388,608 e
    float*          X0f = (float*)(wsb + 33554432);
    unsigned short* B2h = (unsigned short*)(wsb + 33554432); // 4,194,304 e
    unsigned short* B3h = (unsigned short*)(wsb + 50331648); // 2,097,152 e
    unsigned short* B4h = (unsigned short*)(wsb + 58720256); // 1,048,576 e
    float* R1f    = (float*)wsb;
    float* WH4_E  = R1f;
    float* WH4_DC = R1f + 1048576;
    float* WIHP_E = R1f + 2097152;
    float* WIHP_D = R1f + 2359296;
    float* GX_E   = R1f + 2621440;
    float* GX_D0  = R1f + 3145728;
    float* BIASDC = R1f + 3178496;
    float* HA     = R1f + 3180544;
    float* HB     = R1f + 3188736;
    float* CB     = R1f + 3196928;
    float* HALL   = R1f + 3205120;
    float* FCMUP  = R1f + 3336192;
    float* ZPART  = R1f + 3860480;
    float* FCP    = R1f + 4122624;
    float* DFCP   = R1f + 4188160;
    float* DFCB   = R1f + 4712448;
    float* Z      = R1f + 4716544;
    float* ZS     = R1f + 4749312;
    unsigned short* WBe3 = (unsigned short*)(R1f + 4782080);
    unsigned short* WBe4 = (unsigned short*)(R1f + 4913152);
    unsigned short* WBd1 = (unsigned short*)(R1f + 5437440);
    unsigned short* WBd2 = (unsigned short*)(R1f + 5961728);
    unsigned short* WBe1 = (unsigned short*)(wsb + 62914560);
    unsigned short* WBe2 = (unsigned short*)(wsb + 62922752);
    unsigned short* WBd3 = (unsigned short*)(wsb + 63053824);
    float*          WTd4 = (float*)(wsb + 63184896);

    // ---- merged tail prep + encoder ec1/ec2 ----
    prep_tail<<<266, 256, 0, stream>>>(ec1_w, ec2_w, dt3_w, dt4_w,
                                       WBe1, WBe2, WBd3, (float4*)WTd4);
    to_nhwc4v<<<4096, 256, 0, stream>>>(video, (float4*)X0f);
    conv_mfma<4, 64, 64, 32, 2, 4, 1, 0, 1><<<1024, 256, 0, stream>>>(
        nullptr, X0f, WBe1, ec1_b, B1h);
    conv_mfma<32, 32, 32, 64, 1, 2, 2, 0, 0><<<1024, 256, 0, stream>>>(
        B1h, nullptr, WBe2, ec2_b, B2h);

    // ---- R1 free: merged preps ----
    prep_r1<<<6408, 256, 0, stream>>>(wih_e, wih_d, fc_w, bih_d, bhh_d, fc_b,
                                      fcmu_w, dfc_w, dfc_b,
                                      WIHP_E, WIHP_D, FCP, BIASDC, FCMUP, DFCP, DFCB);
    prep_packs<<<5120, 256, 0, stream>>>(ec3_w, ec4_w, dt1_w, dt2_w,
                                         WBe3, WBe4, WBd1, WBd2);
    pack_whh<<<1024, 256, 0, stream>>>(whh_e, (float4*)WH4_E);
    merge_dc<<<256, 256, 0, stream>>>(wih_d, fc_w, whh_d, WH4_DC);
    hipMemsetAsync(HA, 0, 3 * 8192 * sizeof(float), stream);

    // ---- encoder ec3/ec4 + fcmu ----
    conv_mfma<64, 16, 16, 128, 1, 2, 2, 0, 0><<<512, 256, 0, stream>>>(
        B2h, nullptr, WBe3, ec3_b, B3h);
    conv_mfma<128, 8, 8, 256, 1, 1, 2, 0, 0><<<512, 128, 0, stream>>>(
        B3h, nullptr, WBe4, ec4_b, B4h);
    fcmu_part<<<128, 512, 0, stream>>>(B4h, FCMUP, ZPART);
    fcmu_red<<<128, 256, 0, stream>>>(ZPART, fcmu_b, Z);

    // ---- merged x projections ----
    gx2_kernel<<<68, 512, 0, stream>>>(Z, WIHP_E, bih_e, bhh_e,
                                       WIHP_D, bih_d, bhh_d, GX_E, GX_D0);

    // ---- LSTM chains (per-step launches; coop grid-sync measured 5x slower) ----
    float* hin = HA; float* hout = HB;
    for (int t = 0; t < 16; ++t) {
        lstm_step<<<128, 256, 0, stream>>>((const float4*)WH4_E, GX_E + t * 2048, 32768,
                                           hin, hout, CB, (float*)nullptr);
        float* tmp = hin; hin = hout; hout = tmp;
    }
    pack_whh<<<1024, 256, 0, stream>>>(whh_d, (float4*)WH4_E);  // reuse for dec step 0
    lstm_step<<<128, 256, 0, stream>>>((const float4*)WH4_E, GX_D0, 2048,
                                       hin, hout, CB, HALL);
    { float* tmp = hin; hin = hout; hout = tmp; }
    for (int t = 1; t < 16; ++t) {
        lstm_step<<<128, 256, 0, stream>>>((const float4*)WH4_DC, BIASDC, 0,
                                           hin, hout, CB, HALL + t * 8192);
        float* tmp = hin; hin = hout; hout = tmp;
    }
    zs_k<<<16, 512, 0, stream>>>(HALL, FCP, fc_b, ZS);

    // ---- decoder ----
    dfc_k<<<128, 512, 0, stream>>>(ZS, DFCP, DFCB, B4h);
    conv_mfma<256, 4, 4, 128, 1, 2, 2, 1, 0><<<512, 256, 0, stream>>>(
        B4h, nullptr, WBd1, dt1_b, B3h);
    conv_mfma<128, 8, 8, 64, 1, 2, 2, 1, 0><<<1024, 256, 0, stream>>>(
        B3h, nullptr, WBd2, dt2_b, B2h);
    conv_mfma<64, 16, 16, 32, 2, 4, 1, 1, 0><<<1024, 256, 0, stream>>>(
        B2h, nullptr, WBd3, dt3_b, B1h);
    dt4_tiled<<<2048, 128, 0, stream>>>(B1h, (const float4*)WTd4, dt4_b, (float*)d_out);
}

// Round 12
// 601.486 us; speedup vs baseline: 4.1649x; 1.0290x over previous
//
#include <hip/hip_runtime.h>
#include <math.h>

// ---------------------------------------------------------------------------
// CNN-LSTM video predictor, round 12: FC kernels re-gridded for occupancy
// (dfc 1024 blocks, fcmu 256, zs 64, gx2 132). Conv/LSTM/dt4 = round 11
// (619us, absmax 2e-3).
// ---------------------------------------------------------------------------

typedef float f32x4 __attribute__((ext_vector_type(4)));
typedef short bf16x8 __attribute__((ext_vector_type(8)));

__device__ __forceinline__ float sig_(float x) { return 1.f / (1.f + expf(-x)); }
__device__ __forceinline__ float dot4(float4 a, float4 b) {
    return a.x * b.x + a.y * b.y + a.z * b.z + a.w * b.w;
}
// LSTM column permutation (16 cols/block, 4 j per block, 128 blocks):
// c = b*16 + g*4 + jl  ->  orig gate row g*512 + b*4 + jl
__device__ __forceinline__ int orig_row(int c) {
    return ((c >> 2) & 3) * 512 + (c >> 4) * 4 + (c & 3);
}
__device__ __forceinline__ unsigned short f2bf(float f) {
    unsigned int b = __float_as_uint(f);
    return (unsigned short)((b + 0x7fffu + ((b >> 16) & 1u)) >> 16);
}
__device__ __forceinline__ float bf2f(unsigned short h) {
    return __uint_as_float(((unsigned int)h) << 16);
}
__device__ __forceinline__ float4 bf4_to_f4(uint2 u) {
    float4 r;
    r.x = __uint_as_float((u.x & 0xffffu) << 16);
    r.y = __uint_as_float(u.x & 0xffff0000u);
    r.z = __uint_as_float((u.y & 0xffffu) << 16);
    r.w = __uint_as_float(u.y & 0xffff0000u);
    return r;
}

// =================== MFMA conv / convT (A bf16, W split) ====================
template<int CIP, int HI, int WI, int CO, int MREP, int WM, int WN, int MODE, int SRCF32>
__global__ __launch_bounds__(64 * WM * WN)
void conv_mfma(const unsigned short* __restrict__ Ahi, const float* __restrict__ Af,
               const unsigned short* __restrict__ WB, const float* __restrict__ bias,
               unsigned short* __restrict__ Yhi) {
    constexpr int K    = CIP * (MODE ? 4 : 16);
    constexpr int K32  = K / 32;
    constexpr int NI   = 2 * MREP;
    constexpr int TAPS = MODE ? 4 : 16;
    constexpr int CC   = (CIP >= 32) ? CIP / 32 : 1;
    constexpr int HO   = MODE ? HI * 2 : HI / 2;
    constexpr int WO   = MODE ? WI * 2 : WI / 2;
    constexpr int SH   = MODE ? HI : HI / 2;
    constexpr int SW   = MODE ? WI : WI / 2;
    constexpr int HWS  = SH * SW;
    constexpr int MT   = (256 * HWS) / (32 * MREP * WM);
    constexpr int NT   = CO / (32 * WN);
    constexpr int PLANE = CO * K;

    int bid = blockIdx.x;
    int mt = bid % MT; bid /= MT;
    int nt = bid % NT; int par = bid / NT;
    int p = par >> 1, q = par & 1;

    int tid = threadIdx.x;
    int lane = tid & 63, wid = tid >> 6;
    int wm = wid % WM, wn = wid / WM;
    int mbase = mt * (32 * MREP * WM) + wm * (32 * MREP);
    int nbase = nt * (32 * WN) + wn * 32;
    int lm = lane & 15, lg = lane >> 4;

    int ani[NI], asy[NI], asx[NI];
#pragma unroll
    for (int i = 0; i < NI; ++i) {
        int m = mbase + 16 * i + lm;
        ani[i] = m / HWS; int r = m % HWS; asy[i] = r / SW; asx[i] = r % SW;
    }

    f32x4 acc[NI][2];
#pragma unroll
    for (int i = 0; i < NI; ++i)
#pragma unroll
        for (int j = 0; j < 2; ++j)
#pragma unroll
            for (int e = 0; e < 4; ++e) acc[i][j][e] = 0.f;

    const unsigned short* WBp = WB + (long)par * 2 * PLANE;

    if constexpr (SRCF32) {
        for (int kb = 0; kb < K; kb += 32) {
            int k0 = kb + lg * 8;
            int t0 = k0 >> 2;
            bf16x8 ah[NI];
#pragma unroll
            for (int i = 0; i < NI; ++i) {
                float f[8];
#pragma unroll
                for (int h = 0; h < 2; ++h) {
                    int tap = t0 + h;
                    int ih = 2 * asy[i] + (tap >> 2) - 1;
                    int iw = 2 * asx[i] + (tap & 3) - 1;
                    float4 v = {0.f, 0.f, 0.f, 0.f};
                    if ((unsigned)ih < (unsigned)HI && (unsigned)iw < (unsigned)WI)
                        v = *(const float4*)(Af + (((long)ani[i] * HI + ih) * WI + iw) * 4);
                    f[h * 4 + 0] = v.x; f[h * 4 + 1] = v.y;
                    f[h * 4 + 2] = v.z; f[h * 4 + 3] = v.w;
                }
#pragma unroll
                for (int e = 0; e < 8; ++e) ah[i][e] = (short)f2bf(f[e]);
            }
            bf16x8 bh[2], bl[2];
#pragma unroll
            for (int j = 0; j < 2; ++j) {
                long bidx = ((long)((nbase >> 4) + j) * K32 + (kb >> 5)) * 512 + lane * 8;
                bh[j] = *(const bf16x8*)(WBp + bidx);
                bl[j] = *(const bf16x8*)(WBp + PLANE + bidx);
            }
#pragma unroll
            for (int i = 0; i < NI; ++i)
#pragma unroll
                for (int j = 0; j < 2; ++j) {
                    acc[i][j] = __builtin_amdgcn_mfma_f32_16x16x32_bf16(ah[i], bh[j], acc[i][j], 0, 0, 0);
                    acc[i][j] = __builtin_amdgcn_mfma_f32_16x16x32_bf16(ah[i], bl[j], acc[i][j], 0, 0, 0);
                }
        }
    } else {
        long abase[NI]; unsigned vmask[NI];
#pragma unroll
        for (int i = 0; i < NI; ++i) {
            abase[i] = (long)ani[i] * HI * WI * CIP;
            unsigned vm = 0;
#pragma unroll
            for (int t = 0; t < TAPS; ++t) {
                int iy, ix;
                if constexpr (MODE == 0) {
                    iy = 2 * asy[i] + (t >> 2) - 1; ix = 2 * asx[i] + (t & 3) - 1;
                } else {
                    iy = asy[i] + p + (t >> 1) - 1; ix = asx[i] + q + (t & 1) - 1;
                }
                if (iy >= 0 && iy < HI && ix >= 0 && ix < WI) vm |= (1u << t);
            }
            vmask[i] = vm;
        }
#pragma unroll 2
        for (int tap = 0; tap < TAPS; ++tap) {
            int dy, dx;
            if constexpr (MODE == 0) { dy = (tap >> 2) - 1; dx = (tap & 3) - 1; }
            else { dy = p + (tap >> 1) - 1; dx = q + (tap & 1) - 1; }
            long roff[NI]; unsigned msk[NI];
#pragma unroll
            for (int i = 0; i < NI; ++i) {
                int iy = (MODE == 0 ? 2 * asy[i] : asy[i]) + dy;
                int ix = (MODE == 0 ? 2 * asx[i] : asx[i]) + dx;
                int iyc = min(max(iy, 0), HI - 1);
                int ixc = min(max(ix, 0), WI - 1);
                roff[i] = abase[i] + ((long)iyc * WI + ixc) * CIP + lg * 8;
                msk[i] = ((vmask[i] >> tap) & 1u) ? 0xffffffffu : 0u;
            }
#pragma unroll
            for (int cc = 0; cc < CC; ++cc) {
                int kb32 = tap * CC + cc;
                bf16x8 ah[NI];
#pragma unroll
                for (int i = 0; i < NI; ++i) {
                    uint4 u = *(const uint4*)(Ahi + roff[i] + cc * 32);
                    u.x &= msk[i]; u.y &= msk[i]; u.z &= msk[i]; u.w &= msk[i];
                    ah[i] = *(bf16x8*)&u;
                }
                bf16x8 bh[2], bl[2];
#pragma unroll
                for (int j = 0; j < 2; ++j) {
                    long bidx = ((long)((nbase >> 4) + j) * K32 + kb32) * 512 + lane * 8;
                    bh[j] = *(const bf16x8*)(WBp + bidx);
                    bl[j] = *(const bf16x8*)(WBp + PLANE + bidx);
                }
#pragma unroll
                for (int i = 0; i < NI; ++i)
#pragma unroll
                    for (int j = 0; j < 2; ++j) {
                        acc[i][j] = __builtin_amdgcn_mfma_f32_16x16x32_bf16(ah[i], bh[j], acc[i][j], 0, 0, 0);
                        acc[i][j] = __builtin_amdgcn_mfma_f32_16x16x32_bf16(ah[i], bl[j], acc[i][j], 0, 0, 0);
                    }
            }
        }
    }

#pragma unroll
    for (int i = 0; i < NI; ++i)
#pragma unroll
        for (int j = 0; j < 2; ++j)
#pragma unroll
            for (int r = 0; r < 4; ++r) {
                int m = mbase + 16 * i + lg * 4 + r;
                int co = nbase + 16 * j + lm;
                float v = fmaxf(acc[i][j][r] + bias[co], 0.f);
                long off;
                if constexpr (MODE == 0) {
                    off = (long)m * CO + co;
                } else {
                    int ni = m / HWS; int rm = m % HWS;
                    int oy = 2 * (rm / SW) + p, ox = 2 * (rm % SW) + q;
                    off = (((long)ni * HO + oy) * WO + ox) * CO + co;
                }
                Yhi[off] = f2bf(v);
            }
}

// ====== dt4: LDS-tiled (bf16 LDS), 4-row stripes, CO=3, sigmoid, NCHW =======
__global__ __launch_bounds__(128)
void dt4_tiled(const unsigned short* __restrict__ Xh,
               const float4* __restrict__ Wd, const float* __restrict__ bias,
               float* __restrict__ out) {
    __shared__ uint2 xt[8 * 205];
    int bid = blockIdx.x;
    int n = bid >> 3, yg = bid & 7;
    int y0 = yg * 4;
    int tid = threadIdx.x;
    long nb = (long)n * 32768;
    for (int j = tid; j < 1632; j += 128) {
        int c4 = j & 7; int pos = j >> 3;
        int r = pos / 34, cc = pos % 34;
        int ih = y0 - 1 + r, iw = cc - 1;
        uint2 u = {0u, 0u};
        if ((unsigned)ih < 32u && (unsigned)iw < 32u)
            u = *(const uint2*)(Xh + nb + ((long)ih * 32 + iw) * 32 + c4 * 4);
        xt[c4 * 205 + pos] = u;
    }
    __syncthreads();
    int ly = tid >> 5, lx = tid & 31;
    float acc[3][4];
#pragma unroll
    for (int j = 0; j < 3; ++j) {
        float b = bias[j];
#pragma unroll
        for (int par = 0; par < 4; ++par) acc[j][par] = b;
    }
#pragma unroll
    for (int ci4 = 0; ci4 < 8; ++ci4) {
        float4 xv[9];
        int base = ci4 * 205 + ly * 34 + lx;
#pragma unroll
        for (int r = 0; r < 3; ++r)
#pragma unroll
            for (int c = 0; c < 3; ++c)
                xv[r * 3 + c] = bf4_to_f4(xt[base + r * 34 + c]);
        const float4* wp = Wd + ci4 * 48;
#pragma unroll
        for (int j = 0; j < 3; ++j)
#pragma unroll
            for (int par = 0; par < 4; ++par) {
                int p = par >> 1, q = par & 1;
#pragma unroll
                for (int t4 = 0; t4 < 4; ++t4) {
                    int dh = t4 >> 1, dw = t4 & 1;
                    acc[j][par] += dot4(xv[(p + dh) * 3 + (q + dw)],
                                        wp[(j * 4 + par) * 4 + t4]);
                }
            }
    }
    int yy = y0 + ly, xx = lx;
#pragma unroll
    for (int j = 0; j < 3; ++j)
#pragma unroll
        for (int p = 0; p < 2; ++p) {
            float2 v;
            v.x = sig_(acc[j][p * 2 + 0]);
            v.y = sig_(acc[j][p * 2 + 1]);
            *(float2*)(out + (((long)n * 3 + j) * 64 + 2 * yy + p) * 64 + 2 * xx) = v;
        }
}

// ========================= weight / layout prep =============================
__global__ void prep_packs(const float* __restrict__ ec3_w, const float* __restrict__ ec4_w,
                           const float* __restrict__ dt1_w, const float* __restrict__ dt2_w,
                           unsigned short* __restrict__ WBe3, unsigned short* __restrict__ WBe4,
                           unsigned short* __restrict__ WBd1, unsigned short* __restrict__ WBd2) {
    int idx = blockIdx.x * 256 + threadIdx.x;
    if (idx < 131072) {  // ec3 conv: CI=64 CO=128 K=1024
        int li = idx;
        int j = li & 7, lane = (li >> 3) & 63;
        int kb = (li >> 9) & 31, nt = li >> 14;
        int k = kb * 32 + (lane >> 4) * 8 + j;
        int tap = k >> 6, ci = k & 63;
        int co = nt * 16 + (lane & 15);
        float f = ec3_w[((long)co * 64 + ci) * 16 + tap];
        unsigned short hi = f2bf(f);
        WBe3[li] = hi; WBe3[131072 + li] = f2bf(f - bf2f(hi));
    } else if (idx < 655360) {  // ec4 conv: CI=128 CO=256 K=2048
        int li = idx - 131072;
        int j = li & 7, lane = (li >> 3) & 63;
        int kb = (li >> 9) & 63, nt = li >> 15;
        int k = kb * 32 + (lane >> 4) * 8 + j;
        int tap = k >> 7, ci = k & 127;
        int co = nt * 16 + (lane & 15);
        float f = ec4_w[((long)co * 128 + ci) * 16 + tap];
        unsigned short hi = f2bf(f);
        WBe4[li] = hi; WBe4[524288 + li] = f2bf(f - bf2f(hi));
    } else if (idx < 1179648) {  // dt1 convt: CI=256 CO=128 Kp=1024
        int li = idx - 655360;
        int par = li >> 17; int rem = li & 131071;
        int j = rem & 7, lane = (rem >> 3) & 63;
        int kb = (rem >> 9) & 31, nt = rem >> 14;
        int k = kb * 32 + (lane >> 4) * 8 + j;
        int t4 = k >> 8, ci = k & 255;
        int p = par >> 1, q = par & 1, dh = t4 >> 1, dw = t4 & 1;
        int tap = (p + 2 * dh) * 4 + (q + 2 * dw);
        int co = nt * 16 + (lane & 15);
        float f = dt1_w[((long)co * 256 + ci) * 16 + tap];
        unsigned short hi = f2bf(f);
        WBd1[(long)par * 262144 + rem] = hi;
        WBd1[(long)par * 262144 + 131072 + rem] = f2bf(f - bf2f(hi));
    } else if (idx < 1310720) {  // dt2 convt: CI=128 CO=64 Kp=512
        int li = idx - 1179648;
        int par = li >> 15; int rem = li & 32767;
        int j = rem & 7, lane = (rem >> 3) & 63;
        int kb = (rem >> 9) & 15, nt = rem >> 13;
        int k = kb * 32 + (lane >> 4) * 8 + j;
        int t4 = k >> 7, ci = k & 127;
        int p = par >> 1, q = par & 1, dh = t4 >> 1, dw = t4 & 1;
        int tap = (p + 2 * dh) * 4 + (q + 2 * dw);
        int co = nt * 16 + (lane & 15);
        float f = dt2_w[((long)co * 128 + ci) * 16 + tap];
        unsigned short hi = f2bf(f);
        WBd2[(long)par * 65536 + rem] = hi;
        WBd2[(long)par * 65536 + 32768 + rem] = f2bf(f - bf2f(hi));
    }
}

__global__ void prep_tail(const float* __restrict__ ec1_w, const float* __restrict__ ec2_w,
                          const float* __restrict__ dt3_w, const float* __restrict__ dt4_w,
                          unsigned short* __restrict__ WBe1, unsigned short* __restrict__ WBe2,
                          unsigned short* __restrict__ WBd3, float4* __restrict__ WTd4) {
    int idx = blockIdx.x * 256 + threadIdx.x;
    if (idx < 2048) {
        int li = idx;
        int j = li & 7, lane = (li >> 3) & 63;
        int kb = (li >> 9) & 1, nt = li / 1024;
        int k = kb * 32 + (lane >> 4) * 8 + j;
        int tap = k >> 2, ci = k & 3;
        int co = nt * 16 + (lane & 15);
        float f = (ci < 3) ? ec1_w[((long)co * 3 + ci) * 16 + tap] : 0.f;
        unsigned short hi = f2bf(f);
        WBe1[li] = hi; WBe1[2048 + li] = f2bf(f - bf2f(hi));
    } else if (idx < 34816) {
        int li = idx - 2048;
        int j = li & 7, lane = (li >> 3) & 63;
        int kb = (li >> 9) & 15, nt = li / 8192;
        int k = kb * 32 + (lane >> 4) * 8 + j;
        int tap = k >> 5, ci = k & 31;
        int co = nt * 16 + (lane & 15);
        float f = ec2_w[((long)co * 32 + ci) * 16 + tap];
        unsigned short hi = f2bf(f);
        WBe2[li] = hi; WBe2[32768 + li] = f2bf(f - bf2f(hi));
    } else if (idx < 67584) {
        int li = idx - 34816;
        int par = li >> 13; int rem = li & 8191;
        int j = rem & 7, lane = (rem >> 3) & 63;
        int kb = (rem >> 9) & 7, nt = rem >> 12;
        int k = kb * 32 + (lane >> 4) * 8 + j;
        int t4 = k >> 6, ci = k & 63;
        int p = par >> 1, q = par & 1, dh = t4 >> 1, dw = t4 & 1;
        int tap = (p + 2 * dh) * 4 + (q + 2 * dw);
        int co = nt * 16 + (lane & 15);
        float f = dt3_w[((long)co * 64 + ci) * 16 + tap];
        unsigned short hi = f2bf(f);
        WBd3[par * 16384 + rem] = hi;
        WBd3[par * 16384 + 8192 + rem] = f2bf(f - bf2f(hi));
    } else if (idx < 67968) {
        int li = idx - 67584;
        int t4 = li & 3, par = (li >> 2) & 3;
        int co = (li >> 4) % 3, ci4 = (li >> 4) / 3;
        int p = par >> 1, q = par & 1, dh = t4 >> 1, dw = t4 & 1;
        int tap = (p + 2 * dh) * 4 + (q + 2 * dw);
        float4 v; float* pv = (float*)&v;
#pragma unroll
        for (int l = 0; l < 4; ++l)
            pv[l] = dt4_w[((long)co * 32 + ci4 * 4 + l) * 16 + tap];
        WTd4[li] = v;
    }
}

__global__ void prep_r1(const float* __restrict__ wih_e, const float* __restrict__ wih_d,
                        const float* __restrict__ fc_w,
                        const float* __restrict__ bih_d, const float* __restrict__ bhh_d,
                        const float* __restrict__ fc_b,
                        const float* __restrict__ fcmu_w, const float* __restrict__ dfc_w,
                        const float* __restrict__ dfc_b,
                        float* __restrict__ WIHP_E, float* __restrict__ WIHP_D,
                        float* __restrict__ FCP, float* __restrict__ BIASDC,
                        float* __restrict__ FCMUP, float* __restrict__ DFCP,
                        float* __restrict__ DFCB) {
    int idx = blockIdx.x * 256 + threadIdx.x;
    if (idx < 262144) {
        int c = idx & 2047, m = idx >> 11;
        WIHP_E[idx] = wih_e[orig_row(c) * 128 + m];
    } else if (idx < 524288) {
        int li = idx - 262144;
        int c = li & 2047, m = li >> 11;
        WIHP_D[li] = wih_d[orig_row(c) * 128 + m];
    } else if (idx < 589824) {
        int li = idx - 524288;
        int r = li & 127, c = li >> 7;
        FCP[li] = fc_w[(long)r * 512 + c];
    } else if (idx < 591872) {
        int c = idx - 589824;
        int orow = orig_row(c);
        float s = bih_d[orow] + bhh_d[orow];
        for (int m = 0; m < 128; ++m) s += fc_b[m] * wih_d[orow * 128 + m];
        BIASDC[c] = s;
    } else if (idx < 1116160) {
        int li = idx - 591872;
        int j = li & 127, k = li >> 7;
        FCMUP[li] = fcmu_w[(long)j * 4096 + (k & 255) * 16 + (k >> 8)];
    } else {
        int li = idx - 1116160;
        int j = li & 4095, m = li >> 12;
        int jc = (j & 255) * 16 + (j >> 8);
        DFCP[li] = dfc_w[(long)jc * 128 + m];
        if (li < 4096) DFCB[li] = dfc_b[(li & 255) * 16 + (li >> 8)];
    }
}

__global__ void to_nhwc4v(const float* __restrict__ v, float4* __restrict__ out) {
    int idx = blockIdx.x * 256 + threadIdx.x;  // 1,048,576
    int w = idx & 63, h = (idx >> 6) & 63, n = idx >> 12;
    long base = (long)n * 12288 + h * 64 + w;
    float4 o;
    o.x = v[base];
    o.y = v[base + 4096];
    o.z = v[base + 8192];
    o.w = 0.f;
    out[idx] = o;
}

__global__ void pack_whh(const float* __restrict__ whh, float4* __restrict__ out) {
    int idx = blockIdx.x * 256 + threadIdx.x;  // 262144
    int c = idx & 2047, k4 = idx >> 11;
    const float4* src = (const float4*)(whh + orig_row(c) * 512);
    out[idx] = src[k4];
}

__global__ __launch_bounds__(256)
void merge_dc(const float* __restrict__ wih_d, const float* __restrict__ fc_w,
              const float* __restrict__ whh_d, float* __restrict__ out) {
    int cb = (blockIdx.x >> 3) * 64, kb = (blockIdx.x & 7) * 64;
    int tid = threadIdx.x;
    int cgl = (tid & 15) * 4, kgl = (tid >> 4) * 4;
    __shared__ float At[64][65];
    __shared__ float Bt[64][65];
    float acc[4][4] = {};
    for (int mc = 0; mc < 128; mc += 64) {
        __syncthreads();
        for (int i = tid; i < 4096; i += 256) {
            int cl = i >> 6, m = i & 63;
            At[cl][m] = wih_d[orig_row(cb + cl) * 128 + mc + m];
            Bt[cl][m] = fc_w[(mc + cl) * 512 + kb + m];
        }
        __syncthreads();
        for (int m = 0; m < 64; ++m) {
            float a[4], b[4];
#pragma unroll
            for (int i = 0; i < 4; ++i) { a[i] = At[cgl + i][m]; b[i] = Bt[m][kgl + i]; }
#pragma unroll
            for (int i = 0; i < 4; ++i)
#pragma unroll
                for (int j = 0; j < 4; ++j) acc[i][j] += a[i] * b[j];
        }
    }
    for (int i = 0; i < 4; ++i) {
        int c = cb + cgl + i; int orow = orig_row(c);
        for (int j = 0; j < 4; ++j) {
            int k = kb + kgl + j;
            out[((k >> 2) * 2048 + c) * 4 + (k & 3)] = acc[i][j] + whh_d[orow * 512 + k];
        }
    }
}

// ============================ LSTM / FC path ================================
// gx2: blocks 0-127 encoder (32 row-groups of 8 x 4 col-chunks);
// blocks 128-131 decoder step-0 (16 rows x 4 col-chunks)
__global__ __launch_bounds__(512)
void gx2_kernel(const float* __restrict__ Z,
                const float* __restrict__ wE, const float* __restrict__ biE,
                const float* __restrict__ bhE,
                const float* __restrict__ wD, const float* __restrict__ biD,
                const float* __restrict__ bhD,
                float* __restrict__ gxe, float* __restrict__ gxd0) {
    __shared__ float zl[2048];
    int bid = blockIdx.x, tid = threadIdx.x;
    if (bid < 128) {
        int rg = bid >> 2, cch = bid & 3;   // 32 groups of 8 rows
        for (int i = tid; i < 1024; i += 512)
            zl[i] = Z[(long)(rg * 8 + (i >> 7)) * 128 + (i & 127)];
        __syncthreads();
        int c = cch * 512 + tid;
        int orow = orig_row(c);
        float bsum = biE[orow] + bhE[orow];
        float acc[8];
#pragma unroll
        for (int r = 0; r < 8; ++r) acc[r] = bsum;
        for (int m = 0; m < 128; ++m) {
            float wv = wE[m * 2048 + c];
#pragma unroll
            for (int r = 0; r < 8; ++r) acc[r] += zl[r * 128 + m] * wv;
        }
        for (int r = 0; r < 8; ++r) gxe[(long)(rg * 8 + r) * 2048 + c] = acc[r];
    } else {
        int cch = bid - 128;
        for (int i = tid; i < 2048; i += 512)
            zl[i] = Z[(long)((i >> 7) * 16 + 15) * 128 + (i & 127)];
        __syncthreads();
        int c = cch * 512 + tid;
        int orow = orig_row(c);
        float bsum = biD[orow] + bhD[orow];
        float acc[16];
#pragma unroll
        for (int r = 0; r < 16; ++r) acc[r] = bsum;
        for (int m = 0; m < 128; ++m) {
            float wv = wD[m * 2048 + c];
#pragma unroll
            for (int r = 0; r < 16; ++r) acc[r] += zl[r * 128 + m] * wv;
        }
        for (int r = 0; r < 16; ++r) gxd0[(long)r * 2048 + c] = acc[r];
    }
}

// one LSTM step: 128 blocks x 256 threads; block owns 16 cols (4 j x 4 gates)
__global__ __launch_bounds__(256)
void lstm_step(const float4* __restrict__ wh4, const float* __restrict__ gadd,
               int gstride, const float* __restrict__ h_in, float* __restrict__ h_out,
               float* __restrict__ cst, float* __restrict__ hall) {
    __shared__ float hs[8192];
    __shared__ float gb[16][16];
    int tid = threadIdx.x;
    float4* hs4 = (float4*)hs;
    const float4* hi4 = (const float4*)h_in;
#pragma unroll
    for (int i = 0; i < 8; ++i) hs4[tid + 256 * i] = hi4[tid + 256 * i];
    __syncthreads();
    int col = tid & 15, n = tid >> 4;
    int cg = blockIdx.x * 16 + col;
    float acc = gadd[n * gstride + cg];
    const float4* wp = wh4 + cg;
    const float4* hv = (const float4*)(hs + n * 512);
#pragma unroll 8
    for (int k4 = 0; k4 < 128; ++k4) {
        float4 wv = wp[(long)k4 * 2048];
        float4 h4 = hv[k4];
        acc += wv.x * h4.x + wv.y * h4.y + wv.z * h4.z + wv.w * h4.w;
    }
    gb[n][col] = acc;
    __syncthreads();
    if (col < 4) {
        int j = blockIdx.x * 4 + col;
        float gi = sig_(gb[n][col]);
        float gf = sig_(gb[n][col + 4]);
        float gg = tanhf(gb[n][col + 8]);
        float go = sig_(gb[n][col + 12]);
        int idx = n * 512 + j;
        float cv = gf * cst[idx] + gi * gg;
        cst[idx] = cv;
        float hvv = go * tanhf(cv);
        h_out[idx] = hvv;
        if (hall) hall[idx] = hvv;
    }
}

// fcmu partials: 256 blocks = 16 row-groups x 16 k-slices (256 K each)
__global__ __launch_bounds__(512)
void fcmu_part(const unsigned short* __restrict__ xh,
               const float* __restrict__ wP, float* __restrict__ part) {
    int rg = blockIdx.x >> 4, ks = blockIdx.x & 15;
    int tid = threadIdx.x;
    __shared__ float xls[16 * 256];
    for (int i = tid; i < 4096; i += 512) {
        long gi = (long)(rg * 16 + (i >> 8)) * 4096 + ks * 256 + (i & 255);
        xls[i] = bf2f(xh[gi]);
    }
    __syncthreads();
    int j = tid & 127, rq = tid >> 7;
    float acc[4] = {0, 0, 0, 0};
    for (int k = 0; k < 256; ++k) {
        float wv = wP[(ks * 256 + k) * 128 + j];
#pragma unroll
        for (int i = 0; i < 4; ++i) acc[i] += xls[(rq + 4 * i) * 256 + k] * wv;
    }
    for (int i = 0; i < 4; ++i)
        part[((long)ks * 256 + rg * 16 + rq + 4 * i) * 128 + j] = acc[i];
}

__global__ void fcmu_red(const float* __restrict__ part, const float* __restrict__ b,
                         float* __restrict__ z) {
    int idx = blockIdx.x * 256 + threadIdx.x;  // 32768
    float s = b[idx & 127];
    for (int k = 0; k < 16; ++k) s += part[k * 32768 + idx];
    z[idx] = s;
}

// zs: 64 blocks = 16 t x 4 n-quads; thread = (j, n-local), 1 output
__global__ __launch_bounds__(512)
void zs_k(const float* __restrict__ hall, const float* __restrict__ fcP,
          const float* __restrict__ fcb, float* __restrict__ zs) {
    int t = blockIdx.x >> 2, nq = blockIdx.x & 3;
    int tid = threadIdx.x;
    __shared__ float hs[4 * 512];
    const float* h = hall + (long)t * 8192 + nq * 2048;
    for (int i = tid; i < 2048; i += 512) hs[i] = h[i];
    __syncthreads();
    int j = tid & 127, nl = tid >> 7;
    float a0 = 0.f, a1 = 0.f, a2 = 0.f, a3 = 0.f;
    const float* hr = hs + nl * 512;
    for (int k = 0; k < 512; k += 4) {
        a0 += hr[k] * fcP[k * 128 + j];
        a1 += hr[k + 1] * fcP[(k + 1) * 128 + j];
        a2 += hr[k + 2] * fcP[(k + 2) * 128 + j];
        a3 += hr[k + 3] * fcP[(k + 3) * 128 + j];
    }
    int n = nq * 4 + nl;
    zs[((long)n * 16 + t) * 128 + j] = (a0 + a1) + (a2 + a3) + fcb[j];
}

// dfc: 1024 blocks = 64 row-quads x 16 j-chunks (256 j each)
__global__ __launch_bounds__(256)
void dfc_k(const float* __restrict__ zs, const float* __restrict__ dP,
           const float* __restrict__ db, unsigned short* __restrict__ outh) {
    int rg = blockIdx.x >> 4, jc = blockIdx.x & 15;
    int tid = threadIdx.x;
    __shared__ float zl[512];
    for (int i = tid; i < 512; i += 256) zl[i] = zs[(long)rg * 512 + i];
    __syncthreads();
    int j = jc * 256 + tid;
    float acc[4] = {0.f, 0.f, 0.f, 0.f};
    for (int m = 0; m < 128; ++m) {
        float wv = dP[(long)m * 4096 + j];
#pragma unroll
        for (int r = 0; r < 4; ++r) acc[r] += zl[r * 128 + m] * wv;
    }
    float bv = db[j];
    for (int r = 0; r < 4; ++r) {
        float v = fmaxf(acc[r] + bv, 0.f);
        outh[(long)(rg * 4 + r) * 4096 + j] = f2bf(v);
    }
}

extern "C" void kernel_launch(void* const* d_in, const int* in_sizes, int n_in,
                              void* d_out, int out_size, void* d_ws, size_t ws_size,
                              hipStream_t stream) {
    (void)in_sizes; (void)n_in; (void)out_size; (void)ws_size;
    const float* video  = (const float*)d_in[0];
    const float* ec1_w  = (const float*)d_in[2];  const float* ec1_b = (const float*)d_in[3];
    const float* ec2_w  = (const float*)d_in[4];  const float* ec2_b = (const float*)d_in[5];
    const float* ec3_w  = (const float*)d_in[6];  const float* ec3_b = (const float*)d_in[7];
    const float* ec4_w  = (const float*)d_in[8];  const float* ec4_b = (const float*)d_in[9];
    const float* fcmu_w = (const float*)d_in[10]; const float* fcmu_b = (const float*)d_in[11];
    const float* dfc_w  = (const float*)d_in[12]; const float* dfc_b = (const float*)d_in[13];
    const float* dt1_w  = (const float*)d_in[14]; const float* dt1_b = (const float*)d_in[15];
    const float* dt2_w  = (const float*)d_in[16]; const float* dt2_b = (const float*)d_in[17];
    const float* dt3_w  = (const float*)d_in[18]; const float* dt3_b = (const float*)d_in[19];
    const float* dt4_w  = (const float*)d_in[20]; const float* dt4_b = (const float*)d_in[21];
    const float* wih_e  = (const float*)d_in[22]; const float* whh_e = (const float*)d_in[23];
    const float* bih_e  = (const float*)d_in[24]; const float* bhh_e = (const float*)d_in[25];
    const float* wih_d  = (const float*)d_in[26]; const float* whh_d = (const float*)d_in[27];
    const float* bih_d  = (const float*)d_in[28]; const float* bhh_d = (const float*)d_in[29];
    const float* fc_w   = (const float*)d_in[30]; const float* fc_b  = (const float*)d_in[31];

    char* wsb = (char*)d_ws;
    unsigned short* B1h = (unsigned short*)wsb;              // 8,388,608 e
    float*          X0f = (float*)(wsb + 33554432);
    unsigned short* B2h = (unsigned short*)(wsb + 33554432); // 4,194,304 e
    unsigned short* B3h = (unsigned short*)(wsb + 50331648); // 2,097,152 e
    unsigned short* B4h = (unsigned short*)(wsb + 58720256); // 1,048,576 e
    float* R1f    = (float*)wsb;
    float* WH4_E  = R1f;
    float* WH4_DC = R1f + 1048576;
    float* WIHP_E = R1f + 2097152;
    float* WIHP_D = R1f + 2359296;
    float* GX_E   = R1f + 2621440;
    float* GX_D0  = R1f + 3145728;
    float* BIASDC = R1f + 3178496;
    float* HA     = R1f + 3180544;
    float* HB     = R1f + 3188736;
    float* CB     = R1f + 3196928;
    float* HALL   = R1f + 3205120;
    float* FCMUP  = R1f + 3336192;
    float* FCP    = R1f + 4122624;
    float* DFCP   = R1f + 4188160;
    float* DFCB   = R1f + 4712448;
    float* Z      = R1f + 4716544;
    float* ZS     = R1f + 4749312;
    unsigned short* WBe3 = (unsigned short*)(R1f + 4782080);
    unsigned short* WBe4 = (unsigned short*)(R1f + 4913152);
    unsigned short* WBd1 = (unsigned short*)(R1f + 5437440);
    unsigned short* WBd2 = (unsigned short*)(R1f + 5961728);
    float* ZPART  = R1f + 6092800;   // 524,288 (16 k-slices)
    unsigned short* WBe1 = (unsigned short*)(wsb + 62914560);
    unsigned short* WBe2 = (unsigned short*)(wsb + 62922752);
    unsigned short* WBd3 = (unsigned short*)(wsb + 63053824);
    float*          WTd4 = (float*)(wsb + 63184896);

    // ---- merged tail prep + encoder ec1/ec2 ----
    prep_tail<<<266, 256, 0, stream>>>(ec1_w, ec2_w, dt3_w, dt4_w,
                                       WBe1, WBe2, WBd3, (float4*)WTd4);
    to_nhwc4v<<<4096, 256, 0, stream>>>(video, (float4*)X0f);
    conv_mfma<4, 64, 64, 32, 2, 4, 1, 0, 1><<<1024, 256, 0, stream>>>(
        nullptr, X0f, WBe1, ec1_b, B1h);
    conv_mfma<32, 32, 32, 64, 1, 2, 2, 0, 0><<<1024, 256, 0, stream>>>(
        B1h, nullptr, WBe2, ec2_b, B2h);

    // ---- R1 free: merged preps ----
    prep_r1<<<6408, 256, 0, stream>>>(wih_e, wih_d, fc_w, bih_d, bhh_d, fc_b,
                                      fcmu_w, dfc_w, dfc_b,
                                      WIHP_E, WIHP_D, FCP, BIASDC, FCMUP, DFCP, DFCB);
    prep_packs<<<5120, 256, 0, stream>>>(ec3_w, ec4_w, dt1_w, dt2_w,
                                         WBe3, WBe4, WBd1, WBd2);
    pack_whh<<<1024, 256, 0, stream>>>(whh_e, (float4*)WH4_E);
    merge_dc<<<256, 256, 0, stream>>>(wih_d, fc_w, whh_d, WH4_DC);
    hipMemsetAsync(HA, 0, 3 * 8192 * sizeof(float), stream);

    // ---- encoder ec3/ec4 + fcmu ----
    conv_mfma<64, 16, 16, 128, 1, 2, 2, 0, 0><<<512, 256, 0, stream>>>(
        B2h, nullptr, WBe3, ec3_b, B3h);
    conv_mfma<128, 8, 8, 256, 1, 1, 2, 0, 0><<<512, 128, 0, stream>>>(
        B3h, nullptr, WBe4, ec4_b, B4h);
    fcmu_part<<<256, 512, 0, stream>>>(B4h, FCMUP, ZPART);
    fcmu_red<<<128, 256, 0, stream>>>(ZPART, fcmu_b, Z);

    // ---- merged x projections ----
    gx2_kernel<<<132, 512, 0, stream>>>(Z, WIHP_E, bih_e, bhh_e,
                                        WIHP_D, bih_d, bhh_d, GX_E, GX_D0);

    // ---- LSTM chains (per-step launches; coop grid-sync measured 5x slower) ----
    float* hin = HA; float* hout = HB;
    for (int t = 0; t < 16; ++t) {
        lstm_step<<<128, 256, 0, stream>>>((const float4*)WH4_E, GX_E + t * 2048, 32768,
                                           hin, hout, CB, (float*)nullptr);
        float* tmp = hin; hin = hout; hout = tmp;
    }
    pack_whh<<<1024, 256, 0, stream>>>(whh_d, (float4*)WH4_E);  // reuse for dec step 0
    lstm_step<<<128, 256, 0, stream>>>((const float4*)WH4_E, GX_D0, 2048,
                                       hin, hout, CB, HALL);
    { float* tmp = hin; hin = hout; hout = tmp; }
    for (int t = 1; t < 16; ++t) {
        lstm_step<<<128, 256, 0, stream>>>((const float4*)WH4_DC, BIASDC, 0,
                                           hin, hout, CB, HALL + t * 8192);
        float* tmp = hin; hin = hout; hout = tmp;
    }
    zs_k<<<64, 512, 0, stream>>>(HALL, FCP, fc_b, ZS);

    // ---- decoder ----
    dfc_k<<<1024, 256, 0, stream>>>(ZS, DFCP, DFCB, B4h);
    conv_mfma<256, 4, 4, 128, 1, 2, 2, 1, 0><<<512, 256, 0, stream>>>(
        B4h, nullptr, WBd1, dt1_b, B3h);
    conv_mfma<128, 8, 8, 64, 1, 2, 2, 1, 0><<<1024, 256, 0, stream>>>(
        B3h, nullptr, WBd2, dt2_b, B2h);
    conv_mfma<64, 16, 16, 32, 2, 4, 1, 1, 0><<<1024, 256, 0, stream>>>(
        B2h, nullptr, WBd3, dt3_b, B1h);
    dt4_tiled<<<2048, 128, 0, stream>>>(B1h, (const float4*)WTd4, dt4_b, (float*)d_out);
}

// Round 13
// 535.788 us; speedup vs baseline: 4.6756x; 1.1226x over previous
//
#include <hip/hip_runtime.h>
#include <math.h>

// ---------------------------------------------------------------------------
// CNN-LSTM video predictor, round 13: LSTM chain re-gridded to 256 blocks
// (8 cols/block, 2-way k-split, full CU coverage) + decoder whh pack hoisted
// out of the chain. Conv/FC paths = round 12 (601us, absmax 2e-3).
// ---------------------------------------------------------------------------

typedef float f32x4 __attribute__((ext_vector_type(4)));
typedef short bf16x8 __attribute__((ext_vector_type(8)));

__device__ __forceinline__ float sig_(float x) { return 1.f / (1.f + expf(-x)); }
__device__ __forceinline__ float dot4(float4 a, float4 b) {
    return a.x * b.x + a.y * b.y + a.z * b.z + a.w * b.w;
}
// LSTM column permutation (8 cols/block, 2 j per block, 256 blocks):
// c = b*8 + g*2 + jl  ->  orig gate row g*512 + b*2 + jl
__device__ __forceinline__ int orig_row(int c) {
    return ((c >> 1) & 3) * 512 + (c >> 3) * 2 + (c & 1);
}
__device__ __forceinline__ unsigned short f2bf(float f) {
    unsigned int b = __float_as_uint(f);
    return (unsigned short)((b + 0x7fffu + ((b >> 16) & 1u)) >> 16);
}
__device__ __forceinline__ float bf2f(unsigned short h) {
    return __uint_as_float(((unsigned int)h) << 16);
}
__device__ __forceinline__ float4 bf4_to_f4(uint2 u) {
    float4 r;
    r.x = __uint_as_float((u.x & 0xffffu) << 16);
    r.y = __uint_as_float(u.x & 0xffff0000u);
    r.z = __uint_as_float((u.y & 0xffffu) << 16);
    r.w = __uint_as_float(u.y & 0xffff0000u);
    return r;
}

// =================== MFMA conv / convT (A bf16, W split) ====================
template<int CIP, int HI, int WI, int CO, int MREP, int WM, int WN, int MODE, int SRCF32>
__global__ __launch_bounds__(64 * WM * WN)
void conv_mfma(const unsigned short* __restrict__ Ahi, const float* __restrict__ Af,
               const unsigned short* __restrict__ WB, const float* __restrict__ bias,
               unsigned short* __restrict__ Yhi) {
    constexpr int K    = CIP * (MODE ? 4 : 16);
    constexpr int K32  = K / 32;
    constexpr int NI   = 2 * MREP;
    constexpr int TAPS = MODE ? 4 : 16;
    constexpr int CC   = (CIP >= 32) ? CIP / 32 : 1;
    constexpr int HO   = MODE ? HI * 2 : HI / 2;
    constexpr int WO   = MODE ? WI * 2 : WI / 2;
    constexpr int SH   = MODE ? HI : HI / 2;
    constexpr int SW   = MODE ? WI : WI / 2;
    constexpr int HWS  = SH * SW;
    constexpr int MT   = (256 * HWS) / (32 * MREP * WM);
    constexpr int NT   = CO / (32 * WN);
    constexpr int PLANE = CO * K;

    int bid = blockIdx.x;
    int mt = bid % MT; bid /= MT;
    int nt = bid % NT; int par = bid / NT;
    int p = par >> 1, q = par & 1;

    int tid = threadIdx.x;
    int lane = tid & 63, wid = tid >> 6;
    int wm = wid % WM, wn = wid / WM;
    int mbase = mt * (32 * MREP * WM) + wm * (32 * MREP);
    int nbase = nt * (32 * WN) + wn * 32;
    int lm = lane & 15, lg = lane >> 4;

    int ani[NI], asy[NI], asx[NI];
#pragma unroll
    for (int i = 0; i < NI; ++i) {
        int m = mbase + 16 * i + lm;
        ani[i] = m / HWS; int r = m % HWS; asy[i] = r / SW; asx[i] = r % SW;
    }

    f32x4 acc[NI][2];
#pragma unroll
    for (int i = 0; i < NI; ++i)
#pragma unroll
        for (int j = 0; j < 2; ++j)
#pragma unroll
            for (int e = 0; e < 4; ++e) acc[i][j][e] = 0.f;

    const unsigned short* WBp = WB + (long)par * 2 * PLANE;

    if constexpr (SRCF32) {
        for (int kb = 0; kb < K; kb += 32) {
            int k0 = kb + lg * 8;
            int t0 = k0 >> 2;
            bf16x8 ah[NI];
#pragma unroll
            for (int i = 0; i < NI; ++i) {
                float f[8];
#pragma unroll
                for (int h = 0; h < 2; ++h) {
                    int tap = t0 + h;
                    int ih = 2 * asy[i] + (tap >> 2) - 1;
                    int iw = 2 * asx[i] + (tap & 3) - 1;
                    float4 v = {0.f, 0.f, 0.f, 0.f};
                    if ((unsigned)ih < (unsigned)HI && (unsigned)iw < (unsigned)WI)
                        v = *(const float4*)(Af + (((long)ani[i] * HI + ih) * WI + iw) * 4);
                    f[h * 4 + 0] = v.x; f[h * 4 + 1] = v.y;
                    f[h * 4 + 2] = v.z; f[h * 4 + 3] = v.w;
                }
#pragma unroll
                for (int e = 0; e < 8; ++e) ah[i][e] = (short)f2bf(f[e]);
            }
            bf16x8 bh[2], bl[2];
#pragma unroll
            for (int j = 0; j < 2; ++j) {
                long bidx = ((long)((nbase >> 4) + j) * K32 + (kb >> 5)) * 512 + lane * 8;
                bh[j] = *(const bf16x8*)(WBp + bidx);
                bl[j] = *(const bf16x8*)(WBp + PLANE + bidx);
            }
#pragma unroll
            for (int i = 0; i < NI; ++i)
#pragma unroll
                for (int j = 0; j < 2; ++j) {
                    acc[i][j] = __builtin_amdgcn_mfma_f32_16x16x32_bf16(ah[i], bh[j], acc[i][j], 0, 0, 0);
                    acc[i][j] = __builtin_amdgcn_mfma_f32_16x16x32_bf16(ah[i], bl[j], acc[i][j], 0, 0, 0);
                }
        }
    } else {
        long abase[NI]; unsigned vmask[NI];
#pragma unroll
        for (int i = 0; i < NI; ++i) {
            abase[i] = (long)ani[i] * HI * WI * CIP;
            unsigned vm = 0;
#pragma unroll
            for (int t = 0; t < TAPS; ++t) {
                int iy, ix;
                if constexpr (MODE == 0) {
                    iy = 2 * asy[i] + (t >> 2) - 1; ix = 2 * asx[i] + (t & 3) - 1;
                } else {
                    iy = asy[i] + p + (t >> 1) - 1; ix = asx[i] + q + (t & 1) - 1;
                }
                if (iy >= 0 && iy < HI && ix >= 0 && ix < WI) vm |= (1u << t);
            }
            vmask[i] = vm;
        }
#pragma unroll 2
        for (int tap = 0; tap < TAPS; ++tap) {
            int dy, dx;
            if constexpr (MODE == 0) { dy = (tap >> 2) - 1; dx = (tap & 3) - 1; }
            else { dy = p + (tap >> 1) - 1; dx = q + (tap & 1) - 1; }
            long roff[NI]; unsigned msk[NI];
#pragma unroll
            for (int i = 0; i < NI; ++i) {
                int iy = (MODE == 0 ? 2 * asy[i] : asy[i]) + dy;
                int ix = (MODE == 0 ? 2 * asx[i] : asx[i]) + dx;
                int iyc = min(max(iy, 0), HI - 1);
                int ixc = min(max(ix, 0), WI - 1);
                roff[i] = abase[i] + ((long)iyc * WI + ixc) * CIP + lg * 8;
                msk[i] = ((vmask[i] >> tap) & 1u) ? 0xffffffffu : 0u;
            }
#pragma unroll
            for (int cc = 0; cc < CC; ++cc) {
                int kb32 = tap * CC + cc;
                bf16x8 ah[NI];
#pragma unroll
                for (int i = 0; i < NI; ++i) {
                    uint4 u = *(const uint4*)(Ahi + roff[i] + cc * 32);
                    u.x &= msk[i]; u.y &= msk[i]; u.z &= msk[i]; u.w &= msk[i];
                    ah[i] = *(bf16x8*)&u;
                }
                bf16x8 bh[2], bl[2];
#pragma unroll
                for (int j = 0; j < 2; ++j) {
                    long bidx = ((long)((nbase >> 4) + j) * K32 + kb32) * 512 + lane * 8;
                    bh[j] = *(const bf16x8*)(WBp + bidx);
                    bl[j] = *(const bf16x8*)(WBp + PLANE + bidx);
                }
#pragma unroll
                for (int i = 0; i < NI; ++i)
#pragma unroll
                    for (int j = 0; j < 2; ++j) {
                        acc[i][j] = __builtin_amdgcn_mfma_f32_16x16x32_bf16(ah[i], bh[j], acc[i][j], 0, 0, 0);
                        acc[i][j] = __builtin_amdgcn_mfma_f32_16x16x32_bf16(ah[i], bl[j], acc[i][j], 0, 0, 0);
                    }
            }
        }
    }

#pragma unroll
    for (int i = 0; i < NI; ++i)
#pragma unroll
        for (int j = 0; j < 2; ++j)
#pragma unroll
            for (int r = 0; r < 4; ++r) {
                int m = mbase + 16 * i + lg * 4 + r;
                int co = nbase + 16 * j + lm;
                float v = fmaxf(acc[i][j][r] + bias[co], 0.f);
                long off;
                if constexpr (MODE == 0) {
                    off = (long)m * CO + co;
                } else {
                    int ni = m / HWS; int rm = m % HWS;
                    int oy = 2 * (rm / SW) + p, ox = 2 * (rm % SW) + q;
                    off = (((long)ni * HO + oy) * WO + ox) * CO + co;
                }
                Yhi[off] = f2bf(v);
            }
}

// ====== dt4: LDS-tiled (bf16 LDS), 4-row stripes, CO=3, sigmoid, NCHW =======
__global__ __launch_bounds__(128)
void dt4_tiled(const unsigned short* __restrict__ Xh,
               const float4* __restrict__ Wd, const float* __restrict__ bias,
               float* __restrict__ out) {
    __shared__ uint2 xt[8 * 205];
    int bid = blockIdx.x;
    int n = bid >> 3, yg = bid & 7;
    int y0 = yg * 4;
    int tid = threadIdx.x;
    long nb = (long)n * 32768;
    for (int j = tid; j < 1632; j += 128) {
        int c4 = j & 7; int pos = j >> 3;
        int r = pos / 34, cc = pos % 34;
        int ih = y0 - 1 + r, iw = cc - 1;
        uint2 u = {0u, 0u};
        if ((unsigned)ih < 32u && (unsigned)iw < 32u)
            u = *(const uint2*)(Xh + nb + ((long)ih * 32 + iw) * 32 + c4 * 4);
        xt[c4 * 205 + pos] = u;
    }
    __syncthreads();
    int ly = tid >> 5, lx = tid & 31;
    float acc[3][4];
#pragma unroll
    for (int j = 0; j < 3; ++j) {
        float b = bias[j];
#pragma unroll
        for (int par = 0; par < 4; ++par) acc[j][par] = b;
    }
#pragma unroll
    for (int ci4 = 0; ci4 < 8; ++ci4) {
        float4 xv[9];
        int base = ci4 * 205 + ly * 34 + lx;
#pragma unroll
        for (int r = 0; r < 3; ++r)
#pragma unroll
            for (int c = 0; c < 3; ++c)
                xv[r * 3 + c] = bf4_to_f4(xt[base + r * 34 + c]);
        const float4* wp = Wd + ci4 * 48;
#pragma unroll
        for (int j = 0; j < 3; ++j)
#pragma unroll
            for (int par = 0; par < 4; ++par) {
                int p = par >> 1, q = par & 1;
#pragma unroll
                for (int t4 = 0; t4 < 4; ++t4) {
                    int dh = t4 >> 1, dw = t4 & 1;
                    acc[j][par] += dot4(xv[(p + dh) * 3 + (q + dw)],
                                        wp[(j * 4 + par) * 4 + t4]);
                }
            }
    }
    int yy = y0 + ly, xx = lx;
#pragma unroll
    for (int j = 0; j < 3; ++j)
#pragma unroll
        for (int p = 0; p < 2; ++p) {
            float2 v;
            v.x = sig_(acc[j][p * 2 + 0]);
            v.y = sig_(acc[j][p * 2 + 1]);
            *(float2*)(out + (((long)n * 3 + j) * 64 + 2 * yy + p) * 64 + 2 * xx) = v;
        }
}

// ========================= weight / layout prep =============================
__global__ void prep_packs(const float* __restrict__ ec3_w, const float* __restrict__ ec4_w,
                           const float* __restrict__ dt1_w, const float* __restrict__ dt2_w,
                           unsigned short* __restrict__ WBe3, unsigned short* __restrict__ WBe4,
                           unsigned short* __restrict__ WBd1, unsigned short* __restrict__ WBd2) {
    int idx = blockIdx.x * 256 + threadIdx.x;
    if (idx < 131072) {  // ec3 conv: CI=64 CO=128 K=1024
        int li = idx;
        int j = li & 7, lane = (li >> 3) & 63;
        int kb = (li >> 9) & 31, nt = li >> 14;
        int k = kb * 32 + (lane >> 4) * 8 + j;
        int tap = k >> 6, ci = k & 63;
        int co = nt * 16 + (lane & 15);
        float f = ec3_w[((long)co * 64 + ci) * 16 + tap];
        unsigned short hi = f2bf(f);
        WBe3[li] = hi; WBe3[131072 + li] = f2bf(f - bf2f(hi));
    } else if (idx < 655360) {  // ec4 conv: CI=128 CO=256 K=2048
        int li = idx - 131072;
        int j = li & 7, lane = (li >> 3) & 63;
        int kb = (li >> 9) & 63, nt = li >> 15;
        int k = kb * 32 + (lane >> 4) * 8 + j;
        int tap = k >> 7, ci = k & 127;
        int co = nt * 16 + (lane & 15);
        float f = ec4_w[((long)co * 128 + ci) * 16 + tap];
        unsigned short hi = f2bf(f);
        WBe4[li] = hi; WBe4[524288 + li] = f2bf(f - bf2f(hi));
    } else if (idx < 1179648) {  // dt1 convt: CI=256 CO=128 Kp=1024
        int li = idx - 655360;
        int par = li >> 17; int rem = li & 131071;
        int j = rem & 7, lane = (rem >> 3) & 63;
        int kb = (rem >> 9) & 31, nt = rem >> 14;
        int k = kb * 32 + (lane >> 4) * 8 + j;
        int t4 = k >> 8, ci = k & 255;
        int p = par >> 1, q = par & 1, dh = t4 >> 1, dw = t4 & 1;
        int tap = (p + 2 * dh) * 4 + (q + 2 * dw);
        int co = nt * 16 + (lane & 15);
        float f = dt1_w[((long)co * 256 + ci) * 16 + tap];
        unsigned short hi = f2bf(f);
        WBd1[(long)par * 262144 + rem] = hi;
        WBd1[(long)par * 262144 + 131072 + rem] = f2bf(f - bf2f(hi));
    } else if (idx < 1310720) {  // dt2 convt: CI=128 CO=64 Kp=512
        int li = idx - 1179648;
        int par = li >> 15; int rem = li & 32767;
        int j = rem & 7, lane = (rem >> 3) & 63;
        int kb = (rem >> 9) & 15, nt = rem >> 13;
        int k = kb * 32 + (lane >> 4) * 8 + j;
        int t4 = k >> 7, ci = k & 127;
        int p = par >> 1, q = par & 1, dh = t4 >> 1, dw = t4 & 1;
        int tap = (p + 2 * dh) * 4 + (q + 2 * dw);
        int co = nt * 16 + (lane & 15);
        float f = dt2_w[((long)co * 128 + ci) * 16 + tap];
        unsigned short hi = f2bf(f);
        WBd2[(long)par * 65536 + rem] = hi;
        WBd2[(long)par * 65536 + 32768 + rem] = f2bf(f - bf2f(hi));
    }
}

__global__ void prep_tail(const float* __restrict__ ec1_w, const float* __restrict__ ec2_w,
                          const float* __restrict__ dt3_w, const float* __restrict__ dt4_w,
                          unsigned short* __restrict__ WBe1, unsigned short* __restrict__ WBe2,
                          unsigned short* __restrict__ WBd3, float4* __restrict__ WTd4) {
    int idx = blockIdx.x * 256 + threadIdx.x;
    if (idx < 2048) {
        int li = idx;
        int j = li & 7, lane = (li >> 3) & 63;
        int kb = (li >> 9) & 1, nt = li / 1024;
        int k = kb * 32 + (lane >> 4) * 8 + j;
        int tap = k >> 2, ci = k & 3;
        int co = nt * 16 + (lane & 15);
        float f = (ci < 3) ? ec1_w[((long)co * 3 + ci) * 16 + tap] : 0.f;
        unsigned short hi = f2bf(f);
        WBe1[li] = hi; WBe1[2048 + li] = f2bf(f - bf2f(hi));
    } else if (idx < 34816) {
        int li = idx - 2048;
        int j = li & 7, lane = (li >> 3) & 63;
        int kb = (li >> 9) & 15, nt = li / 8192;
        int k = kb * 32 + (lane >> 4) * 8 + j;
        int tap = k >> 5, ci = k & 31;
        int co = nt * 16 + (lane & 15);
        float f = ec2_w[((long)co * 32 + ci) * 16 + tap];
        unsigned short hi = f2bf(f);
        WBe2[li] = hi; WBe2[32768 + li] = f2bf(f - bf2f(hi));
    } else if (idx < 67584) {
        int li = idx - 34816;
        int par = li >> 13; int rem = li & 8191;
        int j = rem & 7, lane = (rem >> 3) & 63;
        int kb = (rem >> 9) & 7, nt = rem >> 12;
        int k = kb * 32 + (lane >> 4) * 8 + j;
        int t4 = k >> 6, ci = k & 63;
        int p = par >> 1, q = par & 1, dh = t4 >> 1, dw = t4 & 1;
        int tap = (p + 2 * dh) * 4 + (q + 2 * dw);
        int co = nt * 16 + (lane & 15);
        float f = dt3_w[((long)co * 64 + ci) * 16 + tap];
        unsigned short hi = f2bf(f);
        WBd3[par * 16384 + rem] = hi;
        WBd3[par * 16384 + 8192 + rem] = f2bf(f - bf2f(hi));
    } else if (idx < 67968) {
        int li = idx - 67584;
        int t4 = li & 3, par = (li >> 2) & 3;
        int co = (li >> 4) % 3, ci4 = (li >> 4) / 3;
        int p = par >> 1, q = par & 1, dh = t4 >> 1, dw = t4 & 1;
        int tap = (p + 2 * dh) * 4 + (q + 2 * dw);
        float4 v; float* pv = (float*)&v;
#pragma unroll
        for (int l = 0; l < 4; ++l)
            pv[l] = dt4_w[((long)co * 32 + ci4 * 4 + l) * 16 + tap];
        WTd4[li] = v;
    }
}

__global__ void prep_r1(const float* __restrict__ wih_e, const float* __restrict__ wih_d,
                        const float* __restrict__ fc_w,
                        const float* __restrict__ bih_d, const float* __restrict__ bhh_d,
                        const float* __restrict__ fc_b,
                        const float* __restrict__ fcmu_w, const float* __restrict__ dfc_w,
                        const float* __restrict__ dfc_b,
                        float* __restrict__ WIHP_E, float* __restrict__ WIHP_D,
                        float* __restrict__ FCP, float* __restrict__ BIASDC,
                        float* __restrict__ FCMUP, float* __restrict__ DFCP,
                        float* __restrict__ DFCB) {
    int idx = blockIdx.x * 256 + threadIdx.x;
    if (idx < 262144) {
        int c = idx & 2047, m = idx >> 11;
        WIHP_E[idx] = wih_e[orig_row(c) * 128 + m];
    } else if (idx < 524288) {
        int li = idx - 262144;
        int c = li & 2047, m = li >> 11;
        WIHP_D[li] = wih_d[orig_row(c) * 128 + m];
    } else if (idx < 589824) {
        int li = idx - 524288;
        int r = li & 127, c = li >> 7;
        FCP[li] = fc_w[(long)r * 512 + c];
    } else if (idx < 591872) {
        int c = idx - 589824;
        int orow = orig_row(c);
        float s = bih_d[orow] + bhh_d[orow];
        for (int m = 0; m < 128; ++m) s += fc_b[m] * wih_d[orow * 128 + m];
        BIASDC[c] = s;
    } else if (idx < 1116160) {
        int li = idx - 591872;
        int j = li & 127, k = li >> 7;
        FCMUP[li] = fcmu_w[(long)j * 4096 + (k & 255) * 16 + (k >> 8)];
    } else {
        int li = idx - 1116160;
        int j = li & 4095, m = li >> 12;
        int jc = (j & 255) * 16 + (j >> 8);
        DFCP[li] = dfc_w[(long)jc * 128 + m];
        if (li < 4096) DFCB[li] = dfc_b[(li & 255) * 16 + (li >> 8)];
    }
}

__global__ void to_nhwc4v(const float* __restrict__ v, float4* __restrict__ out) {
    int idx = blockIdx.x * 256 + threadIdx.x;  // 1,048,576
    int w = idx & 63, h = (idx >> 6) & 63, n = idx >> 12;
    long base = (long)n * 12288 + h * 64 + w;
    float4 o;
    o.x = v[base];
    o.y = v[base + 4096];
    o.z = v[base + 8192];
    o.w = 0.f;
    out[idx] = o;
}

__global__ void pack_whh(const float* __restrict__ whh, float4* __restrict__ out) {
    int idx = blockIdx.x * 256 + threadIdx.x;  // 262144
    int c = idx & 2047, k4 = idx >> 11;
    const float4* src = (const float4*)(whh + orig_row(c) * 512);
    out[idx] = src[k4];
}

__global__ __launch_bounds__(256)
void merge_dc(const float* __restrict__ wih_d, const float* __restrict__ fc_w,
              const float* __restrict__ whh_d, float* __restrict__ out) {
    int cb = (blockIdx.x >> 3) * 64, kb = (blockIdx.x & 7) * 64;
    int tid = threadIdx.x;
    int cgl = (tid & 15) * 4, kgl = (tid >> 4) * 4;
    __shared__ float At[64][65];
    __shared__ float Bt[64][65];
    float acc[4][4] = {};
    for (int mc = 0; mc < 128; mc += 64) {
        __syncthreads();
        for (int i = tid; i < 4096; i += 256) {
            int cl = i >> 6, m = i & 63;
            At[cl][m] = wih_d[orig_row(cb + cl) * 128 + mc + m];
            Bt[cl][m] = fc_w[(mc + cl) * 512 + kb + m];
        }
        __syncthreads();
        for (int m = 0; m < 64; ++m) {
            float a[4], b[4];
#pragma unroll
            for (int i = 0; i < 4; ++i) { a[i] = At[cgl + i][m]; b[i] = Bt[m][kgl + i]; }
#pragma unroll
            for (int i = 0; i < 4; ++i)
#pragma unroll
                for (int j = 0; j < 4; ++j) acc[i][j] += a[i] * b[j];
        }
    }
    for (int i = 0; i < 4; ++i) {
        int c = cb + cgl + i; int orow = orig_row(c);
        for (int j = 0; j < 4; ++j) {
            int k = kb + kgl + j;
            out[((k >> 2) * 2048 + c) * 4 + (k & 3)] = acc[i][j] + whh_d[orow * 512 + k];
        }
    }
}

// ============================ LSTM / FC path ================================
// gx2: blocks 0-127 encoder (32 row-groups of 8 x 4 col-chunks);
// blocks 128-131 decoder step-0 (16 rows x 4 col-chunks)
__global__ __launch_bounds__(512)
void gx2_kernel(const float* __restrict__ Z,
                const float* __restrict__ wE, const float* __restrict__ biE,
                const float* __restrict__ bhE,
                const float* __restrict__ wD, const float* __restrict__ biD,
                const float* __restrict__ bhD,
                float* __restrict__ gxe, float* __restrict__ gxd0) {
    __shared__ float zl[2048];
    int bid = blockIdx.x, tid = threadIdx.x;
    if (bid < 128) {
        int rg = bid >> 2, cch = bid & 3;   // 32 groups of 8 rows
        for (int i = tid; i < 1024; i += 512)
            zl[i] = Z[(long)(rg * 8 + (i >> 7)) * 128 + (i & 127)];
        __syncthreads();
        int c = cch * 512 + tid;
        int orow = orig_row(c);
        float bsum = biE[orow] + bhE[orow];
        float acc[8];
#pragma unroll
        for (int r = 0; r < 8; ++r) acc[r] = bsum;
        for (int m = 0; m < 128; ++m) {
            float wv = wE[m * 2048 + c];
#pragma unroll
            for (int r = 0; r < 8; ++r) acc[r] += zl[r * 128 + m] * wv;
        }
        for (int r = 0; r < 8; ++r) gxe[(long)(rg * 8 + r) * 2048 + c] = acc[r];
    } else {
        int cch = bid - 128;
        for (int i = tid; i < 2048; i += 512)
            zl[i] = Z[(long)((i >> 7) * 16 + 15) * 128 + (i & 127)];
        __syncthreads();
        int c = cch * 512 + tid;
        int orow = orig_row(c);
        float bsum = biD[orow] + bhD[orow];
        float acc[16];
#pragma unroll
        for (int r = 0; r < 16; ++r) acc[r] = bsum;
        for (int m = 0; m < 128; ++m) {
            float wv = wD[m * 2048 + c];
#pragma unroll
            for (int r = 0; r < 16; ++r) acc[r] += zl[r * 128 + m] * wv;
        }
        for (int r = 0; r < 16; ++r) gxd0[(long)r * 2048 + c] = acc[r];
    }
}

// one LSTM step: 256 blocks x 256 threads; block owns 8 cols (2 j x 4 gates),
// 2-way k-split per column, LDS pair-reduce.
__global__ __launch_bounds__(256)
void lstm_step(const float4* __restrict__ wh4, const float* __restrict__ gadd,
               int gstride, const float* __restrict__ h_in, float* __restrict__ h_out,
               float* __restrict__ cst, float* __restrict__ hall) {
    __shared__ float hs[8192];
    __shared__ float gp[2][16][8];
    int tid = threadIdx.x;
    float4* hs4 = (float4*)hs;
    const float4* hi4 = (const float4*)h_in;
#pragma unroll
    for (int i = 0; i < 8; ++i) hs4[tid + 256 * i] = hi4[tid + 256 * i];
    __syncthreads();
    int col = tid & 7, n = (tid >> 3) & 15, kh = tid >> 7;
    int cg = blockIdx.x * 8 + col;
    const float4* wp = wh4 + cg;
    const float4* hv = (const float4*)(hs + n * 512);
    float acc = 0.f;
    int k0 = kh * 64;
#pragma unroll 8
    for (int k4 = k0; k4 < k0 + 64; ++k4) {
        float4 wv = wp[(long)k4 * 2048];
        float4 h4 = hv[k4];
        acc += wv.x * h4.x + wv.y * h4.y + wv.z * h4.z + wv.w * h4.w;
    }
    gp[kh][n][col] = acc;
    __syncthreads();
    if (tid < 128) {
        int cc = tid & 7, nn = tid >> 3;
        gp[0][nn][cc] = gp[0][nn][cc] + gp[1][nn][cc]
                      + gadd[nn * gstride + blockIdx.x * 8 + cc];
    }
    __syncthreads();
    if (tid < 32) {
        int c2 = tid & 1, n2 = tid >> 1;
        float gi = sig_(gp[0][n2][c2]);
        float gf = sig_(gp[0][n2][c2 + 2]);
        float gg = tanhf(gp[0][n2][c2 + 4]);
        float go = sig_(gp[0][n2][c2 + 6]);
        int j = blockIdx.x * 2 + c2;
        int idx = n2 * 512 + j;
        float cv = gf * cst[idx] + gi * gg;
        cst[idx] = cv;
        float hvv = go * tanhf(cv);
        h_out[idx] = hvv;
        if (hall) hall[idx] = hvv;
    }
}

// fcmu partials: 256 blocks = 16 row-groups x 16 k-slices (256 K each)
__global__ __launch_bounds__(512)
void fcmu_part(const unsigned short* __restrict__ xh,
               const float* __restrict__ wP, float* __restrict__ part) {
    int rg = blockIdx.x >> 4, ks = blockIdx.x & 15;
    int tid = threadIdx.x;
    __shared__ float xls[16 * 256];
    for (int i = tid; i < 4096; i += 512) {
        long gi = (long)(rg * 16 + (i >> 8)) * 4096 + ks * 256 + (i & 255);
        xls[i] = bf2f(xh[gi]);
    }
    __syncthreads();
    int j = tid & 127, rq = tid >> 7;
    float acc[4] = {0, 0, 0, 0};
    for (int k = 0; k < 256; ++k) {
        float wv = wP[(ks * 256 + k) * 128 + j];
#pragma unroll
        for (int i = 0; i < 4; ++i) acc[i] += xls[(rq + 4 * i) * 256 + k] * wv;
    }
    for (int i = 0; i < 4; ++i)
        part[((long)ks * 256 + rg * 16 + rq + 4 * i) * 128 + j] = acc[i];
}

__global__ void fcmu_red(const float* __restrict__ part, const float* __restrict__ b,
                         float* __restrict__ z) {
    int idx = blockIdx.x * 256 + threadIdx.x;  // 32768
    float s = b[idx & 127];
    for (int k = 0; k < 16; ++k) s += part[k * 32768 + idx];
    z[idx] = s;
}

// zs: 64 blocks = 16 t x 4 n-quads; thread = (j, n-local), 1 output
__global__ __launch_bounds__(512)
void zs_k(const float* __restrict__ hall, const float* __restrict__ fcP,
          const float* __restrict__ fcb, float* __restrict__ zs) {
    int t = blockIdx.x >> 2, nq = blockIdx.x & 3;
    int tid = threadIdx.x;
    __shared__ float hs[4 * 512];
    const float* h = hall + (long)t * 8192 + nq * 2048;
    for (int i = tid; i < 2048; i += 512) hs[i] = h[i];
    __syncthreads();
    int j = tid & 127, nl = tid >> 7;
    float a0 = 0.f, a1 = 0.f, a2 = 0.f, a3 = 0.f;
    const float* hr = hs + nl * 512;
    for (int k = 0; k < 512; k += 4) {
        a0 += hr[k] * fcP[k * 128 + j];
        a1 += hr[k + 1] * fcP[(k + 1) * 128 + j];
        a2 += hr[k + 2] * fcP[(k + 2) * 128 + j];
        a3 += hr[k + 3] * fcP[(k + 3) * 128 + j];
    }
    int n = nq * 4 + nl;
    zs[((long)n * 16 + t) * 128 + j] = (a0 + a1) + (a2 + a3) + fcb[j];
}

// dfc: 1024 blocks = 64 row-quads x 16 j-chunks (256 j each)
__global__ __launch_bounds__(256)
void dfc_k(const float* __restrict__ zs, const float* __restrict__ dP,
           const float* __restrict__ db, unsigned short* __restrict__ outh) {
    int rg = blockIdx.x >> 4, jc = blockIdx.x & 15;
    int tid = threadIdx.x;
    __shared__ float zl[512];
    for (int i = tid; i < 512; i += 256) zl[i] = zs[(long)rg * 512 + i];
    __syncthreads();
    int j = jc * 256 + tid;
    float acc[4] = {0.f, 0.f, 0.f, 0.f};
    for (int m = 0; m < 128; ++m) {
        float wv = dP[(long)m * 4096 + j];
#pragma unroll
        for (int r = 0; r < 4; ++r) acc[r] += zl[r * 128 + m] * wv;
    }
    float bv = db[j];
    for (int r = 0; r < 4; ++r) {
        float v = fmaxf(acc[r] + bv, 0.f);
        outh[(long)(rg * 4 + r) * 4096 + j] = f2bf(v);
    }
}

extern "C" void kernel_launch(void* const* d_in, const int* in_sizes, int n_in,
                              void* d_out, int out_size, void* d_ws, size_t ws_size,
                              hipStream_t stream) {
    (void)in_sizes; (void)n_in; (void)out_size; (void)ws_size;
    const float* video  = (const float*)d_in[0];
    const float* ec1_w  = (const float*)d_in[2];  const float* ec1_b = (const float*)d_in[3];
    const float* ec2_w  = (const float*)d_in[4];  const float* ec2_b = (const float*)d_in[5];
    const float* ec3_w  = (const float*)d_in[6];  const float* ec3_b = (const float*)d_in[7];
    const float* ec4_w  = (const float*)d_in[8];  const float* ec4_b = (const float*)d_in[9];
    const float* fcmu_w = (const float*)d_in[10]; const float* fcmu_b = (const float*)d_in[11];
    const float* dfc_w  = (const float*)d_in[12]; const float* dfc_b = (const float*)d_in[13];
    const float* dt1_w  = (const float*)d_in[14]; const float* dt1_b = (const float*)d_in[15];
    const float* dt2_w  = (const float*)d_in[16]; const float* dt2_b = (const float*)d_in[17];
    const float* dt3_w  = (const float*)d_in[18]; const float* dt3_b = (const float*)d_in[19];
    const float* dt4_w  = (const float*)d_in[20]; const float* dt4_b = (const float*)d_in[21];
    const float* wih_e  = (const float*)d_in[22]; const float* whh_e = (const float*)d_in[23];
    const float* bih_e  = (const float*)d_in[24]; const float* bhh_e = (const float*)d_in[25];
    const float* wih_d  = (const float*)d_in[26]; const float* whh_d = (const float*)d_in[27];
    const float* bih_d  = (const float*)d_in[28]; const float* bhh_d = (const float*)d_in[29];
    const float* fc_w   = (const float*)d_in[30]; const float* fc_b  = (const float*)d_in[31];

    char* wsb = (char*)d_ws;
    unsigned short* B1h = (unsigned short*)wsb;              // 8,388,608 e
    float*          X0f = (float*)(wsb + 33554432);
    unsigned short* B2h = (unsigned short*)(wsb + 33554432); // 4,194,304 e
    unsigned short* B3h = (unsigned short*)(wsb + 50331648); // 2,097,152 e
    unsigned short* B4h = (unsigned short*)(wsb + 58720256); // 1,048,576 e
    float* R1f    = (float*)wsb;
    float* WH4_E  = R1f;
    float* WH4_DC = R1f + 1048576;
    float* WIHP_E = R1f + 2097152;
    float* WIHP_D = R1f + 2359296;
    float* GX_E   = R1f + 2621440;
    float* GX_D0  = R1f + 3145728;
    float* BIASDC = R1f + 3178496;
    float* HA     = R1f + 3180544;
    float* HB     = R1f + 3188736;
    float* CB     = R1f + 3196928;
    float* HALL   = R1f + 3205120;
    float* FCMUP  = R1f + 3336192;
    float* FCP    = R1f + 4122624;
    float* DFCP   = R1f + 4188160;
    float* DFCB   = R1f + 4712448;
    float* Z      = R1f + 4716544;
    float* ZS     = R1f + 4749312;
    unsigned short* WBe3 = (unsigned short*)(R1f + 4782080);
    unsigned short* WBe4 = (unsigned short*)(R1f + 4913152);
    unsigned short* WBd1 = (unsigned short*)(R1f + 5437440);
    unsigned short* WBd2 = (unsigned short*)(R1f + 5961728);
    float* ZPART  = R1f + 6092800;   // 524,288 (16 k-slices)
    float* WH4_D0 = R1f + 6617088;   // 1,048,576 (decoder step-0 whh pack)
    unsigned short* WBe1 = (unsigned short*)(wsb + 62914560);
    unsigned short* WBe2 = (unsigned short*)(wsb + 62922752);
    unsigned short* WBd3 = (unsigned short*)(wsb + 63053824);
    float*          WTd4 = (float*)(wsb + 63184896);

    // ---- merged tail prep + encoder ec1/ec2 ----
    prep_tail<<<266, 256, 0, stream>>>(ec1_w, ec2_w, dt3_w, dt4_w,
                                       WBe1, WBe2, WBd3, (float4*)WTd4);
    to_nhwc4v<<<4096, 256, 0, stream>>>(video, (float4*)X0f);
    conv_mfma<4, 64, 64, 32, 2, 4, 1, 0, 1><<<1024, 256, 0, stream>>>(
        nullptr, X0f, WBe1, ec1_b, B1h);
    conv_mfma<32, 32, 32, 64, 1, 2, 2, 0, 0><<<1024, 256, 0, stream>>>(
        B1h, nullptr, WBe2, ec2_b, B2h);

    // ---- R1 free: merged preps ----
    prep_r1<<<6408, 256, 0, stream>>>(wih_e, wih_d, fc_w, bih_d, bhh_d, fc_b,
                                      fcmu_w, dfc_w, dfc_b,
                                      WIHP_E, WIHP_D, FCP, BIASDC, FCMUP, DFCP, DFCB);
    prep_packs<<<5120, 256, 0, stream>>>(ec3_w, ec4_w, dt1_w, dt2_w,
                                         WBe3, WBe4, WBd1, WBd2);
    pack_whh<<<1024, 256, 0, stream>>>(whh_e, (float4*)WH4_E);
    pack_whh<<<1024, 256, 0, stream>>>(whh_d, (float4*)WH4_D0);
    merge_dc<<<256, 256, 0, stream>>>(wih_d, fc_w, whh_d, WH4_DC);
    hipMemsetAsync(HA, 0, 3 * 8192 * sizeof(float), stream);

    // ---- encoder ec3/ec4 + fcmu ----
    conv_mfma<64, 16, 16, 128, 1, 2, 2, 0, 0><<<512, 256, 0, stream>>>(
        B2h, nullptr, WBe3, ec3_b, B3h);
    conv_mfma<128, 8, 8, 256, 1, 1, 2, 0, 0><<<512, 128, 0, stream>>>(
        B3h, nullptr, WBe4, ec4_b, B4h);
    fcmu_part<<<256, 512, 0, stream>>>(B4h, FCMUP, ZPART);
    fcmu_red<<<128, 256, 0, stream>>>(ZPART, fcmu_b, Z);

    // ---- merged x projections ----
    gx2_kernel<<<132, 512, 0, stream>>>(Z, WIHP_E, bih_e, bhh_e,
                                        WIHP_D, bih_d, bhh_d, GX_E, GX_D0);

    // ---- LSTM chains (per-step launches; coop grid-sync measured 5x slower) ----
    float* hin = HA; float* hout = HB;
    for (int t = 0; t < 16; ++t) {
        lstm_step<<<256, 256, 0, stream>>>((const float4*)WH4_E, GX_E + t * 2048, 32768,
                                           hin, hout, CB, (float*)nullptr);
        float* tmp = hin; hin = hout; hout = tmp;
    }
    lstm_step<<<256, 256, 0, stream>>>((const float4*)WH4_D0, GX_D0, 2048,
                                       hin, hout, CB, HALL);
    { float* tmp = hin; hin = hout; hout = tmp; }
    for (int t = 1; t < 16; ++t) {
        lstm_step<<<256, 256, 0, stream>>>((const float4*)WH4_DC, BIASDC, 0,
                                           hin, hout, CB, HALL + t * 8192);
        float* tmp = hin; hin = hout; hout = tmp;
    }
    zs_k<<<64, 512, 0, stream>>>(HALL, FCP, fc_b, ZS);

    // ---- decoder ----
    dfc_k<<<1024, 256, 0, stream>>>(ZS, DFCP, DFCB, B4h);
    conv_mfma<256, 4, 4, 128, 1, 2, 2, 1, 0><<<512, 256, 0, stream>>>(
        B4h, nullptr, WBd1, dt1_b, B3h);
    conv_mfma<128, 8, 8, 64, 1, 2, 2, 1, 0><<<1024, 256, 0, stream>>>(
        B3h, nullptr, WBd2, dt2_b, B2h);
    conv_mfma<64, 16, 16, 32, 2, 4, 1, 1, 0><<<1024, 256, 0, stream>>>(
        B2h, nullptr, WBd3, dt3_b, B1h);
    dt4_tiled<<<2048, 128, 0, stream>>>(B1h, (const float4*)WTd4, dt4_b, (float*)d_out);
}

// Round 14
// 498.150 us; speedup vs baseline: 5.0289x; 1.0756x over previous
//
#include <hip/hip_runtime.h>
#include <math.h>

// ---------------------------------------------------------------------------
// CNN-LSTM video predictor, round 14: conv weights single-bf16 (lo plane
// dropped -> 1 MFMA per subtile, 2/3 operand bytes). Everything else =
// round 13 (536us, absmax 2e-3). Expected absmax ~3-4e-3 (threshold 1e-2).
// ---------------------------------------------------------------------------

typedef float f32x4 __attribute__((ext_vector_type(4)));
typedef short bf16x8 __attribute__((ext_vector_type(8)));

__device__ __forceinline__ float sig_(float x) { return 1.f / (1.f + expf(-x)); }
__device__ __forceinline__ float dot4(float4 a, float4 b) {
    return a.x * b.x + a.y * b.y + a.z * b.z + a.w * b.w;
}
// LSTM column permutation (8 cols/block, 2 j per block, 256 blocks):
// c = b*8 + g*2 + jl  ->  orig gate row g*512 + b*2 + jl
__device__ __forceinline__ int orig_row(int c) {
    return ((c >> 1) & 3) * 512 + (c >> 3) * 2 + (c & 1);
}
__device__ __forceinline__ unsigned short f2bf(float f) {
    unsigned int b = __float_as_uint(f);
    return (unsigned short)((b + 0x7fffu + ((b >> 16) & 1u)) >> 16);
}
__device__ __forceinline__ float bf2f(unsigned short h) {
    return __uint_as_float(((unsigned int)h) << 16);
}
__device__ __forceinline__ float4 bf4_to_f4(uint2 u) {
    float4 r;
    r.x = __uint_as_float((u.x & 0xffffu) << 16);
    r.y = __uint_as_float(u.x & 0xffff0000u);
    r.z = __uint_as_float((u.y & 0xffffu) << 16);
    r.w = __uint_as_float(u.y & 0xffff0000u);
    return r;
}

// =================== MFMA conv / convT (A bf16, W bf16) =====================
template<int CIP, int HI, int WI, int CO, int MREP, int WM, int WN, int MODE, int SRCF32>
__global__ __launch_bounds__(64 * WM * WN)
void conv_mfma(const unsigned short* __restrict__ Ahi, const float* __restrict__ Af,
               const unsigned short* __restrict__ WB, const float* __restrict__ bias,
               unsigned short* __restrict__ Yhi) {
    constexpr int K    = CIP * (MODE ? 4 : 16);
    constexpr int K32  = K / 32;
    constexpr int NI   = 2 * MREP;
    constexpr int TAPS = MODE ? 4 : 16;
    constexpr int CC   = (CIP >= 32) ? CIP / 32 : 1;
    constexpr int HO   = MODE ? HI * 2 : HI / 2;
    constexpr int WO   = MODE ? WI * 2 : WI / 2;
    constexpr int SH   = MODE ? HI : HI / 2;
    constexpr int SW   = MODE ? WI : WI / 2;
    constexpr int HWS  = SH * SW;
    constexpr int MT   = (256 * HWS) / (32 * MREP * WM);
    constexpr int NT   = CO / (32 * WN);
    constexpr int PLANE = CO * K;

    int bid = blockIdx.x;
    int mt = bid % MT; bid /= MT;
    int nt = bid % NT; int par = bid / NT;
    int p = par >> 1, q = par & 1;

    int tid = threadIdx.x;
    int lane = tid & 63, wid = tid >> 6;
    int wm = wid % WM, wn = wid / WM;
    int mbase = mt * (32 * MREP * WM) + wm * (32 * MREP);
    int nbase = nt * (32 * WN) + wn * 32;
    int lm = lane & 15, lg = lane >> 4;

    int ani[NI], asy[NI], asx[NI];
#pragma unroll
    for (int i = 0; i < NI; ++i) {
        int m = mbase + 16 * i + lm;
        ani[i] = m / HWS; int r = m % HWS; asy[i] = r / SW; asx[i] = r % SW;
    }

    f32x4 acc[NI][2];
#pragma unroll
    for (int i = 0; i < NI; ++i)
#pragma unroll
        for (int j = 0; j < 2; ++j)
#pragma unroll
            for (int e = 0; e < 4; ++e) acc[i][j][e] = 0.f;

    const unsigned short* WBp = WB + (long)par * 2 * PLANE;

    if constexpr (SRCF32) {
        for (int kb = 0; kb < K; kb += 32) {
            int k0 = kb + lg * 8;
            int t0 = k0 >> 2;
            bf16x8 ah[NI];
#pragma unroll
            for (int i = 0; i < NI; ++i) {
                float f[8];
#pragma unroll
                for (int h = 0; h < 2; ++h) {
                    int tap = t0 + h;
                    int ih = 2 * asy[i] + (tap >> 2) - 1;
                    int iw = 2 * asx[i] + (tap & 3) - 1;
                    float4 v = {0.f, 0.f, 0.f, 0.f};
                    if ((unsigned)ih < (unsigned)HI && (unsigned)iw < (unsigned)WI)
                        v = *(const float4*)(Af + (((long)ani[i] * HI + ih) * WI + iw) * 4);
                    f[h * 4 + 0] = v.x; f[h * 4 + 1] = v.y;
                    f[h * 4 + 2] = v.z; f[h * 4 + 3] = v.w;
                }
#pragma unroll
                for (int e = 0; e < 8; ++e) ah[i][e] = (short)f2bf(f[e]);
            }
            bf16x8 bh[2];
#pragma unroll
            for (int j = 0; j < 2; ++j) {
                long bidx = ((long)((nbase >> 4) + j) * K32 + (kb >> 5)) * 512 + lane * 8;
                bh[j] = *(const bf16x8*)(WBp + bidx);
            }
#pragma unroll
            for (int i = 0; i < NI; ++i)
#pragma unroll
                for (int j = 0; j < 2; ++j)
                    acc[i][j] = __builtin_amdgcn_mfma_f32_16x16x32_bf16(ah[i], bh[j], acc[i][j], 0, 0, 0);
        }
    } else {
        long abase[NI]; unsigned vmask[NI];
#pragma unroll
        for (int i = 0; i < NI; ++i) {
            abase[i] = (long)ani[i] * HI * WI * CIP;
            unsigned vm = 0;
#pragma unroll
            for (int t = 0; t < TAPS; ++t) {
                int iy, ix;
                if constexpr (MODE == 0) {
                    iy = 2 * asy[i] + (t >> 2) - 1; ix = 2 * asx[i] + (t & 3) - 1;
                } else {
                    iy = asy[i] + p + (t >> 1) - 1; ix = asx[i] + q + (t & 1) - 1;
                }
                if (iy >= 0 && iy < HI && ix >= 0 && ix < WI) vm |= (1u << t);
            }
            vmask[i] = vm;
        }
#pragma unroll 2
        for (int tap = 0; tap < TAPS; ++tap) {
            int dy, dx;
            if constexpr (MODE == 0) { dy = (tap >> 2) - 1; dx = (tap & 3) - 1; }
            else { dy = p + (tap >> 1) - 1; dx = q + (tap & 1) - 1; }
            long roff[NI]; unsigned msk[NI];
#pragma unroll
            for (int i = 0; i < NI; ++i) {
                int iy = (MODE == 0 ? 2 * asy[i] : asy[i]) + dy;
                int ix = (MODE == 0 ? 2 * asx[i] : asx[i]) + dx;
                int iyc = min(max(iy, 0), HI - 1);
                int ixc = min(max(ix, 0), WI - 1);
                roff[i] = abase[i] + ((long)iyc * WI + ixc) * CIP + lg * 8;
                msk[i] = ((vmask[i] >> tap) & 1u) ? 0xffffffffu : 0u;
            }
#pragma unroll
            for (int cc = 0; cc < CC; ++cc) {
                int kb32 = tap * CC + cc;
                bf16x8 ah[NI];
#pragma unroll
                for (int i = 0; i < NI; ++i) {
                    uint4 u = *(const uint4*)(Ahi + roff[i] + cc * 32);
                    u.x &= msk[i]; u.y &= msk[i]; u.z &= msk[i]; u.w &= msk[i];
                    ah[i] = *(bf16x8*)&u;
                }
                bf16x8 bh[2];
#pragma unroll
                for (int j = 0; j < 2; ++j) {
                    long bidx = ((long)((nbase >> 4) + j) * K32 + kb32) * 512 + lane * 8;
                    bh[j] = *(const bf16x8*)(WBp + bidx);
                }
#pragma unroll
                for (int i = 0; i < NI; ++i)
#pragma unroll
                    for (int j = 0; j < 2; ++j)
                        acc[i][j] = __builtin_amdgcn_mfma_f32_16x16x32_bf16(ah[i], bh[j], acc[i][j], 0, 0, 0);
            }
        }
    }

#pragma unroll
    for (int i = 0; i < NI; ++i)
#pragma unroll
        for (int j = 0; j < 2; ++j)
#pragma unroll
            for (int r = 0; r < 4; ++r) {
                int m = mbase + 16 * i + lg * 4 + r;
                int co = nbase + 16 * j + lm;
                float v = fmaxf(acc[i][j][r] + bias[co], 0.f);
                long off;
                if constexpr (MODE == 0) {
                    off = (long)m * CO + co;
                } else {
                    int ni = m / HWS; int rm = m % HWS;
                    int oy = 2 * (rm / SW) + p, ox = 2 * (rm % SW) + q;
                    off = (((long)ni * HO + oy) * WO + ox) * CO + co;
                }
                Yhi[off] = f2bf(v);
            }
}

// ====== dt4: LDS-tiled (bf16 LDS), 4-row stripes, CO=3, sigmoid, NCHW =======
__global__ __launch_bounds__(128)
void dt4_tiled(const unsigned short* __restrict__ Xh,
               const float4* __restrict__ Wd, const float* __restrict__ bias,
               float* __restrict__ out) {
    __shared__ uint2 xt[8 * 205];
    int bid = blockIdx.x;
    int n = bid >> 3, yg = bid & 7;
    int y0 = yg * 4;
    int tid = threadIdx.x;
    long nb = (long)n * 32768;
    for (int j = tid; j < 1632; j += 128) {
        int c4 = j & 7; int pos = j >> 3;
        int r = pos / 34, cc = pos % 34;
        int ih = y0 - 1 + r, iw = cc - 1;
        uint2 u = {0u, 0u};
        if ((unsigned)ih < 32u && (unsigned)iw < 32u)
            u = *(const uint2*)(Xh + nb + ((long)ih * 32 + iw) * 32 + c4 * 4);
        xt[c4 * 205 + pos] = u;
    }
    __syncthreads();
    int ly = tid >> 5, lx = tid & 31;
    float acc[3][4];
#pragma unroll
    for (int j = 0; j < 3; ++j) {
        float b = bias[j];
#pragma unroll
        for (int par = 0; par < 4; ++par) acc[j][par] = b;
    }
#pragma unroll
    for (int ci4 = 0; ci4 < 8; ++ci4) {
        float4 xv[9];
        int base = ci4 * 205 + ly * 34 + lx;
#pragma unroll
        for (int r = 0; r < 3; ++r)
#pragma unroll
            for (int c = 0; c < 3; ++c)
                xv[r * 3 + c] = bf4_to_f4(xt[base + r * 34 + c]);
        const float4* wp = Wd + ci4 * 48;
#pragma unroll
        for (int j = 0; j < 3; ++j)
#pragma unroll
            for (int par = 0; par < 4; ++par) {
                int p = par >> 1, q = par & 1;
#pragma unroll
                for (int t4 = 0; t4 < 4; ++t4) {
                    int dh = t4 >> 1, dw = t4 & 1;
                    acc[j][par] += dot4(xv[(p + dh) * 3 + (q + dw)],
                                        wp[(j * 4 + par) * 4 + t4]);
                }
            }
    }
    int yy = y0 + ly, xx = lx;
#pragma unroll
    for (int j = 0; j < 3; ++j)
#pragma unroll
        for (int p = 0; p < 2; ++p) {
            float2 v;
            v.x = sig_(acc[j][p * 2 + 0]);
            v.y = sig_(acc[j][p * 2 + 1]);
            *(float2*)(out + (((long)n * 3 + j) * 64 + 2 * yy + p) * 64 + 2 * xx) = v;
        }
}

// ========================= weight / layout prep =============================
__global__ void prep_packs(const float* __restrict__ ec3_w, const float* __restrict__ ec4_w,
                           const float* __restrict__ dt1_w, const float* __restrict__ dt2_w,
                           unsigned short* __restrict__ WBe3, unsigned short* __restrict__ WBe4,
                           unsigned short* __restrict__ WBd1, unsigned short* __restrict__ WBd2) {
    int idx = blockIdx.x * 256 + threadIdx.x;
    if (idx < 131072) {  // ec3 conv: CI=64 CO=128 K=1024
        int li = idx;
        int j = li & 7, lane = (li >> 3) & 63;
        int kb = (li >> 9) & 31, nt = li >> 14;
        int k = kb * 32 + (lane >> 4) * 8 + j;
        int tap = k >> 6, ci = k & 63;
        int co = nt * 16 + (lane & 15);
        float f = ec3_w[((long)co * 64 + ci) * 16 + tap];
        WBe3[li] = f2bf(f);
    } else if (idx < 655360) {  // ec4 conv: CI=128 CO=256 K=2048
        int li = idx - 131072;
        int j = li & 7, lane = (li >> 3) & 63;
        int kb = (li >> 9) & 63, nt = li >> 15;
        int k = kb * 32 + (lane >> 4) * 8 + j;
        int tap = k >> 7, ci = k & 127;
        int co = nt * 16 + (lane & 15);
        float f = ec4_w[((long)co * 128 + ci) * 16 + tap];
        WBe4[li] = f2bf(f);
    } else if (idx < 1179648) {  // dt1 convt: CI=256 CO=128 Kp=1024
        int li = idx - 655360;
        int par = li >> 17; int rem = li & 131071;
        int j = rem & 7, lane = (rem >> 3) & 63;
        int kb = (rem >> 9) & 31, nt = rem >> 14;
        int k = kb * 32 + (lane >> 4) * 8 + j;
        int t4 = k >> 8, ci = k & 255;
        int p = par >> 1, q = par & 1, dh = t4 >> 1, dw = t4 & 1;
        int tap = (p + 2 * dh) * 4 + (q + 2 * dw);
        int co = nt * 16 + (lane & 15);
        float f = dt1_w[((long)co * 256 + ci) * 16 + tap];
        WBd1[(long)par * 262144 + rem] = f2bf(f);
    } else if (idx < 1310720) {  // dt2 convt: CI=128 CO=64 Kp=512
        int li = idx - 1179648;
        int par = li >> 15; int rem = li & 32767;
        int j = rem & 7, lane = (rem >> 3) & 63;
        int kb = (rem >> 9) & 15, nt = rem >> 13;
        int k = kb * 32 + (lane >> 4) * 8 + j;
        int t4 = k >> 7, ci = k & 127;
        int p = par >> 1, q = par & 1, dh = t4 >> 1, dw = t4 & 1;
        int tap = (p + 2 * dh) * 4 + (q + 2 * dw);
        int co = nt * 16 + (lane & 15);
        float f = dt2_w[((long)co * 128 + ci) * 16 + tap];
        WBd2[(long)par * 65536 + rem] = f2bf(f);
    }
}

__global__ void prep_tail(const float* __restrict__ ec1_w, const float* __restrict__ ec2_w,
                          const float* __restrict__ dt3_w, const float* __restrict__ dt4_w,
                          unsigned short* __restrict__ WBe1, unsigned short* __restrict__ WBe2,
                          unsigned short* __restrict__ WBd3, float4* __restrict__ WTd4) {
    int idx = blockIdx.x * 256 + threadIdx.x;
    if (idx < 2048) {
        int li = idx;
        int j = li & 7, lane = (li >> 3) & 63;
        int kb = (li >> 9) & 1, nt = li / 1024;
        int k = kb * 32 + (lane >> 4) * 8 + j;
        int tap = k >> 2, ci = k & 3;
        int co = nt * 16 + (lane & 15);
        float f = (ci < 3) ? ec1_w[((long)co * 3 + ci) * 16 + tap] : 0.f;
        WBe1[li] = f2bf(f);
    } else if (idx < 34816) {
        int li = idx - 2048;
        int j = li & 7, lane = (li >> 3) & 63;
        int kb = (li >> 9) & 15, nt = li / 8192;
        int k = kb * 32 + (lane >> 4) * 8 + j;
        int tap = k >> 5, ci = k & 31;
        int co = nt * 16 + (lane & 15);
        float f = ec2_w[((long)co * 32 + ci) * 16 + tap];
        WBe2[li] = f2bf(f);
    } else if (idx < 67584) {
        int li = idx - 34816;
        int par = li >> 13; int rem = li & 8191;
        int j = rem & 7, lane = (rem >> 3) & 63;
        int kb = (rem >> 9) & 7, nt = rem >> 12;
        int k = kb * 32 + (lane >> 4) * 8 + j;
        int t4 = k >> 6, ci = k & 63;
        int p = par >> 1, q = par & 1, dh = t4 >> 1, dw = t4 & 1;
        int tap = (p + 2 * dh) * 4 + (q + 2 * dw);
        int co = nt * 16 + (lane & 15);
        float f = dt3_w[((long)co * 64 + ci) * 16 + tap];
        WBd3[par * 16384 + rem] = f2bf(f);
    } else if (idx < 67968) {
        int li = idx - 67584;
        int t4 = li & 3, par = (li >> 2) & 3;
        int co = (li >> 4) % 3, ci4 = (li >> 4) / 3;
        int p = par >> 1, q = par & 1, dh = t4 >> 1, dw = t4 & 1;
        int tap = (p + 2 * dh) * 4 + (q + 2 * dw);
        float4 v; float* pv = (float*)&v;
#pragma unroll
        for (int l = 0; l < 4; ++l)
            pv[l] = dt4_w[((long)co * 32 + ci4 * 4 + l) * 16 + tap];
        WTd4[li] = v;
    }
}

__global__ void prep_r1(const float* __restrict__ wih_e, const float* __restrict__ wih_d,
                        const float* __restrict__ fc_w,
                        const float* __restrict__ bih_d, const float* __restrict__ bhh_d,
                        const float* __restrict__ fc_b,
                        const float* __restrict__ fcmu_w, const float* __restrict__ dfc_w,
                        const float* __restrict__ dfc_b,
                        float* __restrict__ WIHP_E, float* __restrict__ WIHP_D,
                        float* __restrict__ FCP, float* __restrict__ BIASDC,
                        float* __restrict__ FCMUP, float* __restrict__ DFCP,
                        float* __restrict__ DFCB) {
    int idx = blockIdx.x * 256 + threadIdx.x;
    if (idx < 262144) {
        int c = idx & 2047, m = idx >> 11;
        WIHP_E[idx] = wih_e[orig_row(c) * 128 + m];
    } else if (idx < 524288) {
        int li = idx - 262144;
        int c = li & 2047, m = li >> 11;
        WIHP_D[li] = wih_d[orig_row(c) * 128 + m];
    } else if (idx < 589824) {
        int li = idx - 524288;
        int r = li & 127, c = li >> 7;
        FCP[li] = fc_w[(long)r * 512 + c];
    } else if (idx < 591872) {
        int c = idx - 589824;
        int orow = orig_row(c);
        float s = bih_d[orow] + bhh_d[orow];
        for (int m = 0; m < 128; ++m) s += fc_b[m] * wih_d[orow * 128 + m];
        BIASDC[c] = s;
    } else if (idx < 1116160) {
        int li = idx - 591872;
        int j = li & 127, k = li >> 7;
        FCMUP[li] = fcmu_w[(long)j * 4096 + (k & 255) * 16 + (k >> 8)];
    } else {
        int li = idx - 1116160;
        int j = li & 4095, m = li >> 12;
        int jc = (j & 255) * 16 + (j >> 8);
        DFCP[li] = dfc_w[(long)jc * 128 + m];
        if (li < 4096) DFCB[li] = dfc_b[(li & 255) * 16 + (li >> 8)];
    }
}

__global__ void to_nhwc4v(const float* __restrict__ v, float4* __restrict__ out) {
    int idx = blockIdx.x * 256 + threadIdx.x;  // 1,048,576
    int w = idx & 63, h = (idx >> 6) & 63, n = idx >> 12;
    long base = (long)n * 12288 + h * 64 + w;
    float4 o;
    o.x = v[base];
    o.y = v[base + 4096];
    o.z = v[base + 8192];
    o.w = 0.f;
    out[idx] = o;
}

__global__ void pack_whh(const float* __restrict__ whh, float4* __restrict__ out) {
    int idx = blockIdx.x * 256 + threadIdx.x;  // 262144
    int c = idx & 2047, k4 = idx >> 11;
    const float4* src = (const float4*)(whh + orig_row(c) * 512);
    out[idx] = src[k4];
}

__global__ __launch_bounds__(256)
void merge_dc(const float* __restrict__ wih_d, const float* __restrict__ fc_w,
              const float* __restrict__ whh_d, float* __restrict__ out) {
    int cb = (blockIdx.x >> 3) * 64, kb = (blockIdx.x & 7) * 64;
    int tid = threadIdx.x;
    int cgl = (tid & 15) * 4, kgl = (tid >> 4) * 4;
    __shared__ float At[64][65];
    __shared__ float Bt[64][65];
    float acc[4][4] = {};
    for (int mc = 0; mc < 128; mc += 64) {
        __syncthreads();
        for (int i = tid; i < 4096; i += 256) {
            int cl = i >> 6, m = i & 63;
            At[cl][m] = wih_d[orig_row(cb + cl) * 128 + mc + m];
            Bt[cl][m] = fc_w[(mc + cl) * 512 + kb + m];
        }
        __syncthreads();
        for (int m = 0; m < 64; ++m) {
            float a[4], b[4];
#pragma unroll
            for (int i = 0; i < 4; ++i) { a[i] = At[cgl + i][m]; b[i] = Bt[m][kgl + i]; }
#pragma unroll
            for (int i = 0; i < 4; ++i)
#pragma unroll
                for (int j = 0; j < 4; ++j) acc[i][j] += a[i] * b[j];
        }
    }
    for (int i = 0; i < 4; ++i) {
        int c = cb + cgl + i; int orow = orig_row(c);
        for (int j = 0; j < 4; ++j) {
            int k = kb + kgl + j;
            out[((k >> 2) * 2048 + c) * 4 + (k & 3)] = acc[i][j] + whh_d[orow * 512 + k];
        }
    }
}

// ============================ LSTM / FC path ================================
__global__ __launch_bounds__(512)
void gx2_kernel(const float* __restrict__ Z,
                const float* __restrict__ wE, const float* __restrict__ biE,
                const float* __restrict__ bhE,
                const float* __restrict__ wD, const float* __restrict__ biD,
                const float* __restrict__ bhD,
                float* __restrict__ gxe, float* __restrict__ gxd0) {
    __shared__ float zl[2048];
    int bid = blockIdx.x, tid = threadIdx.x;
    if (bid < 128) {
        int rg = bid >> 2, cch = bid & 3;   // 32 groups of 8 rows
        for (int i = tid; i < 1024; i += 512)
            zl[i] = Z[(long)(rg * 8 + (i >> 7)) * 128 + (i & 127)];
        __syncthreads();
        int c = cch * 512 + tid;
        int orow = orig_row(c);
        float bsum = biE[orow] + bhE[orow];
        float acc[8];
#pragma unroll
        for (int r = 0; r < 8; ++r) acc[r] = bsum;
        for (int m = 0; m < 128; ++m) {
            float wv = wE[m * 2048 + c];
#pragma unroll
            for (int r = 0; r < 8; ++r) acc[r] += zl[r * 128 + m] * wv;
        }
        for (int r = 0; r < 8; ++r) gxe[(long)(rg * 8 + r) * 2048 + c] = acc[r];
    } else {
        int cch = bid - 128;
        for (int i = tid; i < 2048; i += 512)
            zl[i] = Z[(long)((i >> 7) * 16 + 15) * 128 + (i & 127)];
        __syncthreads();
        int c = cch * 512 + tid;
        int orow = orig_row(c);
        float bsum = biD[orow] + bhD[orow];
        float acc[16];
#pragma unroll
        for (int r = 0; r < 16; ++r) acc[r] = bsum;
        for (int m = 0; m < 128; ++m) {
            float wv = wD[m * 2048 + c];
#pragma unroll
            for (int r = 0; r < 16; ++r) acc[r] += zl[r * 128 + m] * wv;
        }
        for (int r = 0; r < 16; ++r) gxd0[(long)r * 2048 + c] = acc[r];
    }
}

// one LSTM step: 256 blocks x 256 threads; block owns 8 cols (2 j x 4 gates),
// 2-way k-split per column, LDS pair-reduce.
__global__ __launch_bounds__(256)
void lstm_step(const float4* __restrict__ wh4, const float* __restrict__ gadd,
               int gstride, const float* __restrict__ h_in, float* __restrict__ h_out,
               float* __restrict__ cst, float* __restrict__ hall) {
    __shared__ float hs[8192];
    __shared__ float gp[2][16][8];
    int tid = threadIdx.x;
    float4* hs4 = (float4*)hs;
    const float4* hi4 = (const float4*)h_in;
#pragma unroll
    for (int i = 0; i < 8; ++i) hs4[tid + 256 * i] = hi4[tid + 256 * i];
    __syncthreads();
    int col = tid & 7, n = (tid >> 3) & 15, kh = tid >> 7;
    int cg = blockIdx.x * 8 + col;
    const float4* wp = wh4 + cg;
    const float4* hv = (const float4*)(hs + n * 512);
    float acc = 0.f;
    int k0 = kh * 64;
#pragma unroll 8
    for (int k4 = k0; k4 < k0 + 64; ++k4) {
        float4 wv = wp[(long)k4 * 2048];
        float4 h4 = hv[k4];
        acc += wv.x * h4.x + wv.y * h4.y + wv.z * h4.z + wv.w * h4.w;
    }
    gp[kh][n][col] = acc;
    __syncthreads();
    if (tid < 128) {
        int cc = tid & 7, nn = tid >> 3;
        gp[0][nn][cc] = gp[0][nn][cc] + gp[1][nn][cc]
                      + gadd[nn * gstride + blockIdx.x * 8 + cc];
    }
    __syncthreads();
    if (tid < 32) {
        int c2 = tid & 1, n2 = tid >> 1;
        float gi = sig_(gp[0][n2][c2]);
        float gf = sig_(gp[0][n2][c2 + 2]);
        float gg = tanhf(gp[0][n2][c2 + 4]);
        float go = sig_(gp[0][n2][c2 + 6]);
        int j = blockIdx.x * 2 + c2;
        int idx = n2 * 512 + j;
        float cv = gf * cst[idx] + gi * gg;
        cst[idx] = cv;
        float hvv = go * tanhf(cv);
        h_out[idx] = hvv;
        if (hall) hall[idx] = hvv;
    }
}

// fcmu partials: 256 blocks = 16 row-groups x 16 k-slices (256 K each)
__global__ __launch_bounds__(512)
void fcmu_part(const unsigned short* __restrict__ xh,
               const float* __restrict__ wP, float* __restrict__ part) {
    int rg = blockIdx.x >> 4, ks = blockIdx.x & 15;
    int tid = threadIdx.x;
    __shared__ float xls[16 * 256];
    for (int i = tid; i < 4096; i += 512) {
        long gi = (long)(rg * 16 + (i >> 8)) * 4096 + ks * 256 + (i & 255);
        xls[i] = bf2f(xh[gi]);
    }
    __syncthreads();
    int j = tid & 127, rq = tid >> 7;
    float acc[4] = {0, 0, 0, 0};
    for (int k = 0; k < 256; ++k) {
        float wv = wP[(ks * 256 + k) * 128 + j];
#pragma unroll
        for (int i = 0; i < 4; ++i) acc[i] += xls[(rq + 4 * i) * 256 + k] * wv;
    }
    for (int i = 0; i < 4; ++i)
        part[((long)ks * 256 + rg * 16 + rq + 4 * i) * 128 + j] = acc[i];
}

__global__ void fcmu_red(const float* __restrict__ part, const float* __restrict__ b,
                         float* __restrict__ z) {
    int idx = blockIdx.x * 256 + threadIdx.x;  // 32768
    float s = b[idx & 127];
    for (int k = 0; k < 16; ++k) s += part[k * 32768 + idx];
    z[idx] = s;
}

// zs: 64 blocks = 16 t x 4 n-quads; thread = (j, n-local), 1 output
__global__ __launch_bounds__(512)
void zs_k(const float* __restrict__ hall, const float* __restrict__ fcP,
          const float* __restrict__ fcb, float* __restrict__ zs) {
    int t = blockIdx.x >> 2, nq = blockIdx.x & 3;
    int tid = threadIdx.x;
    __shared__ float hs[4 * 512];
    const float* h = hall + (long)t * 8192 + nq * 2048;
    for (int i = tid; i < 2048; i += 512) hs[i] = h[i];
    __syncthreads();
    int j = tid & 127, nl = tid >> 7;
    float a0 = 0.f, a1 = 0.f, a2 = 0.f, a3 = 0.f;
    const float* hr = hs + nl * 512;
    for (int k = 0; k < 512; k += 4) {
        a0 += hr[k] * fcP[k * 128 + j];
        a1 += hr[k + 1] * fcP[(k + 1) * 128 + j];
        a2 += hr[k + 2] * fcP[(k + 2) * 128 + j];
        a3 += hr[k + 3] * fcP[(k + 3) * 128 + j];
    }
    int n = nq * 4 + nl;
    zs[((long)n * 16 + t) * 128 + j] = (a0 + a1) + (a2 + a3) + fcb[j];
}

// dfc: 1024 blocks = 64 row-quads x 16 j-chunks (256 j each)
__global__ __launch_bounds__(256)
void dfc_k(const float* __restrict__ zs, const float* __restrict__ dP,
           const float* __restrict__ db, unsigned short* __restrict__ outh) {
    int rg = blockIdx.x >> 4, jc = blockIdx.x & 15;
    int tid = threadIdx.x;
    __shared__ float zl[512];
    for (int i = tid; i < 512; i += 256) zl[i] = zs[(long)rg * 512 + i];
    __syncthreads();
    int j = jc * 256 + tid;
    float acc[4] = {0.f, 0.f, 0.f, 0.f};
    for (int m = 0; m < 128; ++m) {
        float wv = dP[(long)m * 4096 + j];
#pragma unroll
        for (int r = 0; r < 4; ++r) acc[r] += zl[r * 128 + m] * wv;
    }
    float bv = db[j];
    for (int r = 0; r < 4; ++r) {
        float v = fmaxf(acc[r] + bv, 0.f);
        outh[(long)(rg * 4 + r) * 4096 + j] = f2bf(v);
    }
}

extern "C" void kernel_launch(void* const* d_in, const int* in_sizes, int n_in,
                              void* d_out, int out_size, void* d_ws, size_t ws_size,
                              hipStream_t stream) {
    (void)in_sizes; (void)n_in; (void)out_size; (void)ws_size;
    const float* video  = (const float*)d_in[0];
    const float* ec1_w  = (const float*)d_in[2];  const float* ec1_b = (const float*)d_in[3];
    const float* ec2_w  = (const float*)d_in[4];  const float* ec2_b = (const float*)d_in[5];
    const float* ec3_w  = (const float*)d_in[6];  const float* ec3_b = (const float*)d_in[7];
    const float* ec4_w  = (const float*)d_in[8];  const float* ec4_b = (const float*)d_in[9];
    const float* fcmu_w = (const float*)d_in[10]; const float* fcmu_b = (const float*)d_in[11];
    const float* dfc_w  = (const float*)d_in[12]; const float* dfc_b = (const float*)d_in[13];
    const float* dt1_w  = (const float*)d_in[14]; const float* dt1_b = (const float*)d_in[15];
    const float* dt2_w  = (const float*)d_in[16]; const float* dt2_b = (const float*)d_in[17];
    const float* dt3_w  = (const float*)d_in[18]; const float* dt3_b = (const float*)d_in[19];
    const float* dt4_w  = (const float*)d_in[20]; const float* dt4_b = (const float*)d_in[21];
    const float* wih_e  = (const float*)d_in[22]; const float* whh_e = (const float*)d_in[23];
    const float* bih_e  = (const float*)d_in[24]; const float* bhh_e = (const float*)d_in[25];
    const float* wih_d  = (const float*)d_in[26]; const float* whh_d = (const float*)d_in[27];
    const float* bih_d  = (const float*)d_in[28]; const float* bhh_d = (const float*)d_in[29];
    const float* fc_w   = (const float*)d_in[30]; const float* fc_b  = (const float*)d_in[31];

    char* wsb = (char*)d_ws;
    unsigned short* B1h = (unsigned short*)wsb;              // 8,388,608 e
    float*          X0f = (float*)(wsb + 33554432);
    unsigned short* B2h = (unsigned short*)(wsb + 33554432); // 4,194,304 e
    unsigned short* B3h = (unsigned short*)(wsb + 50331648); // 2,097,152 e
    unsigned short* B4h = (unsigned short*)(wsb + 58720256); // 1,048,576 e
    float* R1f    = (float*)wsb;
    float* WH4_E  = R1f;
    float* WH4_DC = R1f + 1048576;
    float* WIHP_E = R1f + 2097152;
    float* WIHP_D = R1f + 2359296;
    float* GX_E   = R1f + 2621440;
    float* GX_D0  = R1f + 3145728;
    float* BIASDC = R1f + 3178496;
    float* HA     = R1f + 3180544;
    float* HB     = R1f + 3188736;
    float* CB     = R1f + 3196928;
    float* HALL   = R1f + 3205120;
    float* FCMUP  = R1f + 3336192;
    float* FCP    = R1f + 4122624;
    float* DFCP   = R1f + 4188160;
    float* DFCB   = R1f + 4712448;
    float* Z      = R1f + 4716544;
    float* ZS     = R1f + 4749312;
    unsigned short* WBe3 = (unsigned short*)(R1f + 4782080);
    unsigned short* WBe4 = (unsigned short*)(R1f + 4913152);
    unsigned short* WBd1 = (unsigned short*)(R1f + 5437440);
    unsigned short* WBd2 = (unsigned short*)(R1f + 5961728);
    float* ZPART  = R1f + 6092800;   // 524,288 (16 k-slices)
    float* WH4_D0 = R1f + 6617088;   // 1,048,576 (decoder step-0 whh pack)
    unsigned short* WBe1 = (unsigned short*)(wsb + 62914560);
    unsigned short* WBe2 = (unsigned short*)(wsb + 62922752);
    unsigned short* WBd3 = (unsigned short*)(wsb + 63053824);
    float*          WTd4 = (float*)(wsb + 63184896);

    // ---- merged tail prep + encoder ec1/ec2 ----
    prep_tail<<<266, 256, 0, stream>>>(ec1_w, ec2_w, dt3_w, dt4_w,
                                       WBe1, WBe2, WBd3, (float4*)WTd4);
    to_nhwc4v<<<4096, 256, 0, stream>>>(video, (float4*)X0f);
    conv_mfma<4, 64, 64, 32, 2, 4, 1, 0, 1><<<1024, 256, 0, stream>>>(
        nullptr, X0f, WBe1, ec1_b, B1h);
    conv_mfma<32, 32, 32, 64, 1, 2, 2, 0, 0><<<1024, 256, 0, stream>>>(
        B1h, nullptr, WBe2, ec2_b, B2h);

    // ---- R1 free: merged preps ----
    prep_r1<<<6408, 256, 0, stream>>>(wih_e, wih_d, fc_w, bih_d, bhh_d, fc_b,
                                      fcmu_w, dfc_w, dfc_b,
                                      WIHP_E, WIHP_D, FCP, BIASDC, FCMUP, DFCP, DFCB);
    prep_packs<<<5120, 256, 0, stream>>>(ec3_w, ec4_w, dt1_w, dt2_w,
                                         WBe3, WBe4, WBd1, WBd2);
    pack_whh<<<1024, 256, 0, stream>>>(whh_e, (float4*)WH4_E);
    pack_whh<<<1024, 256, 0, stream>>>(whh_d, (float4*)WH4_D0);
    merge_dc<<<256, 256, 0, stream>>>(wih_d, fc_w, whh_d, WH4_DC);
    hipMemsetAsync(HA, 0, 3 * 8192 * sizeof(float), stream);

    // ---- encoder ec3/ec4 + fcmu ----
    conv_mfma<64, 16, 16, 128, 1, 2, 2, 0, 0><<<512, 256, 0, stream>>>(
        B2h, nullptr, WBe3, ec3_b, B3h);
    conv_mfma<128, 8, 8, 256, 1, 1, 2, 0, 0><<<512, 128, 0, stream>>>(
        B3h, nullptr, WBe4, ec4_b, B4h);
    fcmu_part<<<256, 512, 0, stream>>>(B4h, FCMUP, ZPART);
    fcmu_red<<<128, 256, 0, stream>>>(ZPART, fcmu_b, Z);

    // ---- merged x projections ----
    gx2_kernel<<<132, 512, 0, stream>>>(Z, WIHP_E, bih_e, bhh_e,
                                        WIHP_D, bih_d, bhh_d, GX_E, GX_D0);

    // ---- LSTM chains (per-step launches; coop grid-sync measured 5x slower) ----
    float* hin = HA; float* hout = HB;
    for (int t = 0; t < 16; ++t) {
        lstm_step<<<256, 256, 0, stream>>>((const float4*)WH4_E, GX_E + t * 2048, 32768,
                                           hin, hout, CB, (float*)nullptr);
        float* tmp = hin; hin = hout; hout = tmp;
    }
    lstm_step<<<256, 256, 0, stream>>>((const float4*)WH4_D0, GX_D0, 2048,
                                       hin, hout, CB, HALL);
    { float* tmp = hin; hin = hout; hout = tmp; }
    for (int t = 1; t < 16; ++t) {
        lstm_step<<<256, 256, 0, stream>>>((const float4*)WH4_DC, BIASDC, 0,
                                           hin, hout, CB, HALL + t * 8192);
        float* tmp = hin; hin = hout; hout = tmp;
    }
    zs_k<<<64, 512, 0, stream>>>(HALL, FCP, fc_b, ZS);

    // ---- decoder ----
    dfc_k<<<1024, 256, 0, stream>>>(ZS, DFCP, DFCB, B4h);
    conv_mfma<256, 4, 4, 128, 1, 2, 2, 1, 0><<<512, 256, 0, stream>>>(
        B4h, nullptr, WBd1, dt1_b, B3h);
    conv_mfma<128, 8, 8, 64, 1, 2, 2, 1, 0><<<1024, 256, 0, stream>>>(
        B3h, nullptr, WBd2, dt2_b, B2h);
    conv_mfma<64, 16, 16, 32, 2, 4, 1, 1, 0><<<1024, 256, 0, stream>>>(
        B2h, nullptr, WBd3, dt3_b, B1h);
    dt4_tiled<<<2048, 128, 0, stream>>>(B1h, (const float4*)WTd4, dt4_b, (float*)d_out);
}

// Round 15
// 495.165 us; speedup vs baseline: 5.0592x; 1.0060x over previous
//
#include <hip/hip_runtime.h>
#include <math.h>

// ---------------------------------------------------------------------------
// CNN-LSTM video predictor, round 15: MREP=2 on ec2/dt2 (B-fragment shared
// across 4 M-subtiles; grids stay >=2 blocks/CU). Rest = round 14
// (498us, absmax 1.95e-3).
// ---------------------------------------------------------------------------

typedef float f32x4 __attribute__((ext_vector_type(4)));
typedef short bf16x8 __attribute__((ext_vector_type(8)));

__device__ __forceinline__ float sig_(float x) { return 1.f / (1.f + expf(-x)); }
__device__ __forceinline__ float dot4(float4 a, float4 b) {
    return a.x * b.x + a.y * b.y + a.z * b.z + a.w * b.w;
}
// LSTM column permutation (8 cols/block, 2 j per block, 256 blocks):
// c = b*8 + g*2 + jl  ->  orig gate row g*512 + b*2 + jl
__device__ __forceinline__ int orig_row(int c) {
    return ((c >> 1) & 3) * 512 + (c >> 3) * 2 + (c & 1);
}
__device__ __forceinline__ unsigned short f2bf(float f) {
    unsigned int b = __float_as_uint(f);
    return (unsigned short)((b + 0x7fffu + ((b >> 16) & 1u)) >> 16);
}
__device__ __forceinline__ float bf2f(unsigned short h) {
    return __uint_as_float(((unsigned int)h) << 16);
}
__device__ __forceinline__ float4 bf4_to_f4(uint2 u) {
    float4 r;
    r.x = __uint_as_float((u.x & 0xffffu) << 16);
    r.y = __uint_as_float(u.x & 0xffff0000u);
    r.z = __uint_as_float((u.y & 0xffffu) << 16);
    r.w = __uint_as_float(u.y & 0xffff0000u);
    return r;
}

// =================== MFMA conv / convT (A bf16, W bf16) =====================
template<int CIP, int HI, int WI, int CO, int MREP, int WM, int WN, int MODE, int SRCF32>
__global__ __launch_bounds__(64 * WM * WN)
void conv_mfma(const unsigned short* __restrict__ Ahi, const float* __restrict__ Af,
               const unsigned short* __restrict__ WB, const float* __restrict__ bias,
               unsigned short* __restrict__ Yhi) {
    constexpr int K    = CIP * (MODE ? 4 : 16);
    constexpr int K32  = K / 32;
    constexpr int NI   = 2 * MREP;
    constexpr int TAPS = MODE ? 4 : 16;
    constexpr int CC   = (CIP >= 32) ? CIP / 32 : 1;
    constexpr int HO   = MODE ? HI * 2 : HI / 2;
    constexpr int WO   = MODE ? WI * 2 : WI / 2;
    constexpr int SH   = MODE ? HI : HI / 2;
    constexpr int SW   = MODE ? WI : WI / 2;
    constexpr int HWS  = SH * SW;
    constexpr int MT   = (256 * HWS) / (32 * MREP * WM);
    constexpr int NT   = CO / (32 * WN);
    constexpr int PLANE = CO * K;

    int bid = blockIdx.x;
    int mt = bid % MT; bid /= MT;
    int nt = bid % NT; int par = bid / NT;
    int p = par >> 1, q = par & 1;

    int tid = threadIdx.x;
    int lane = tid & 63, wid = tid >> 6;
    int wm = wid % WM, wn = wid / WM;
    int mbase = mt * (32 * MREP * WM) + wm * (32 * MREP);
    int nbase = nt * (32 * WN) + wn * 32;
    int lm = lane & 15, lg = lane >> 4;

    int ani[NI], asy[NI], asx[NI];
#pragma unroll
    for (int i = 0; i < NI; ++i) {
        int m = mbase + 16 * i + lm;
        ani[i] = m / HWS; int r = m % HWS; asy[i] = r / SW; asx[i] = r % SW;
    }

    f32x4 acc[NI][2];
#pragma unroll
    for (int i = 0; i < NI; ++i)
#pragma unroll
        for (int j = 0; j < 2; ++j)
#pragma unroll
            for (int e = 0; e < 4; ++e) acc[i][j][e] = 0.f;

    const unsigned short* WBp = WB + (long)par * 2 * PLANE;

    if constexpr (SRCF32) {
        for (int kb = 0; kb < K; kb += 32) {
            int k0 = kb + lg * 8;
            int t0 = k0 >> 2;
            bf16x8 ah[NI];
#pragma unroll
            for (int i = 0; i < NI; ++i) {
                float f[8];
#pragma unroll
                for (int h = 0; h < 2; ++h) {
                    int tap = t0 + h;
                    int ih = 2 * asy[i] + (tap >> 2) - 1;
                    int iw = 2 * asx[i] + (tap & 3) - 1;
                    float4 v = {0.f, 0.f, 0.f, 0.f};
                    if ((unsigned)ih < (unsigned)HI && (unsigned)iw < (unsigned)WI)
                        v = *(const float4*)(Af + (((long)ani[i] * HI + ih) * WI + iw) * 4);
                    f[h * 4 + 0] = v.x; f[h * 4 + 1] = v.y;
                    f[h * 4 + 2] = v.z; f[h * 4 + 3] = v.w;
                }
#pragma unroll
                for (int e = 0; e < 8; ++e) ah[i][e] = (short)f2bf(f[e]);
            }
            bf16x8 bh[2];
#pragma unroll
            for (int j = 0; j < 2; ++j) {
                long bidx = ((long)((nbase >> 4) + j) * K32 + (kb >> 5)) * 512 + lane * 8;
                bh[j] = *(const bf16x8*)(WBp + bidx);
            }
#pragma unroll
            for (int i = 0; i < NI; ++i)
#pragma unroll
                for (int j = 0; j < 2; ++j)
                    acc[i][j] = __builtin_amdgcn_mfma_f32_16x16x32_bf16(ah[i], bh[j], acc[i][j], 0, 0, 0);
        }
    } else {
        long abase[NI]; unsigned vmask[NI];
#pragma unroll
        for (int i = 0; i < NI; ++i) {
            abase[i] = (long)ani[i] * HI * WI * CIP;
            unsigned vm = 0;
#pragma unroll
            for (int t = 0; t < TAPS; ++t) {
                int iy, ix;
                if constexpr (MODE == 0) {
                    iy = 2 * asy[i] + (t >> 2) - 1; ix = 2 * asx[i] + (t & 3) - 1;
                } else {
                    iy = asy[i] + p + (t >> 1) - 1; ix = asx[i] + q + (t & 1) - 1;
                }
                if (iy >= 0 && iy < HI && ix >= 0 && ix < WI) vm |= (1u << t);
            }
            vmask[i] = vm;
        }
#pragma unroll 2
        for (int tap = 0; tap < TAPS; ++tap) {
            int dy, dx;
            if constexpr (MODE == 0) { dy = (tap >> 2) - 1; dx = (tap & 3) - 1; }
            else { dy = p + (tap >> 1) - 1; dx = q + (tap & 1) - 1; }
            long roff[NI]; unsigned msk[NI];
#pragma unroll
            for (int i = 0; i < NI; ++i) {
                int iy = (MODE == 0 ? 2 * asy[i] : asy[i]) + dy;
                int ix = (MODE == 0 ? 2 * asx[i] : asx[i]) + dx;
                int iyc = min(max(iy, 0), HI - 1);
                int ixc = min(max(ix, 0), WI - 1);
                roff[i] = abase[i] + ((long)iyc * WI + ixc) * CIP + lg * 8;
                msk[i] = ((vmask[i] >> tap) & 1u) ? 0xffffffffu : 0u;
            }
#pragma unroll
            for (int cc = 0; cc < CC; ++cc) {
                int kb32 = tap * CC + cc;
                bf16x8 ah[NI];
#pragma unroll
                for (int i = 0; i < NI; ++i) {
                    uint4 u = *(const uint4*)(Ahi + roff[i] + cc * 32);
                    u.x &= msk[i]; u.y &= msk[i]; u.z &= msk[i]; u.w &= msk[i];
                    ah[i] = *(bf16x8*)&u;
                }
                bf16x8 bh[2];
#pragma unroll
                for (int j = 0; j < 2; ++j) {
                    long bidx = ((long)((nbase >> 4) + j) * K32 + kb32) * 512 + lane * 8;
                    bh[j] = *(const bf16x8*)(WBp + bidx);
                }
#pragma unroll
                for (int i = 0; i < NI; ++i)
#pragma unroll
                    for (int j = 0; j < 2; ++j)
                        acc[i][j] = __builtin_amdgcn_mfma_f32_16x16x32_bf16(ah[i], bh[j], acc[i][j], 0, 0, 0);
            }
        }
    }

#pragma unroll
    for (int i = 0; i < NI; ++i)
#pragma unroll
        for (int j = 0; j < 2; ++j)
#pragma unroll
            for (int r = 0; r < 4; ++r) {
                int m = mbase + 16 * i + lg * 4 + r;
                int co = nbase + 16 * j + lm;
                float v = fmaxf(acc[i][j][r] + bias[co], 0.f);
                long off;
                if constexpr (MODE == 0) {
                    off = (long)m * CO + co;
                } else {
                    int ni = m / HWS; int rm = m % HWS;
                    int oy = 2 * (rm / SW) + p, ox = 2 * (rm % SW) + q;
                    off = (((long)ni * HO + oy) * WO + ox) * CO + co;
                }
                Yhi[off] = f2bf(v);
            }
}

// ====== dt4: LDS-tiled (bf16 LDS), 4-row stripes, CO=3, sigmoid, NCHW =======
__global__ __launch_bounds__(128)
void dt4_tiled(const unsigned short* __restrict__ Xh,
               const float4* __restrict__ Wd, const float* __restrict__ bias,
               float* __restrict__ out) {
    __shared__ uint2 xt[8 * 205];
    int bid = blockIdx.x;
    int n = bid >> 3, yg = bid & 7;
    int y0 = yg * 4;
    int tid = threadIdx.x;
    long nb = (long)n * 32768;
    for (int j = tid; j < 1632; j += 128) {
        int c4 = j & 7; int pos = j >> 3;
        int r = pos / 34, cc = pos % 34;
        int ih = y0 - 1 + r, iw = cc - 1;
        uint2 u = {0u, 0u};
        if ((unsigned)ih < 32u && (unsigned)iw < 32u)
            u = *(const uint2*)(Xh + nb + ((long)ih * 32 + iw) * 32 + c4 * 4);
        xt[c4 * 205 + pos] = u;
    }
    __syncthreads();
    int ly = tid >> 5, lx = tid & 31;
    float acc[3][4];
#pragma unroll
    for (int j = 0; j < 3; ++j) {
        float b = bias[j];
#pragma unroll
        for (int par = 0; par < 4; ++par) acc[j][par] = b;
    }
#pragma unroll
    for (int ci4 = 0; ci4 < 8; ++ci4) {
        float4 xv[9];
        int base = ci4 * 205 + ly * 34 + lx;
#pragma unroll
        for (int r = 0; r < 3; ++r)
#pragma unroll
            for (int c = 0; c < 3; ++c)
                xv[r * 3 + c] = bf4_to_f4(xt[base + r * 34 + c]);
        const float4* wp = Wd + ci4 * 48;
#pragma unroll
        for (int j = 0; j < 3; ++j)
#pragma unroll
            for (int par = 0; par < 4; ++par) {
                int p = par >> 1, q = par & 1;
#pragma unroll
                for (int t4 = 0; t4 < 4; ++t4) {
                    int dh = t4 >> 1, dw = t4 & 1;
                    acc[j][par] += dot4(xv[(p + dh) * 3 + (q + dw)],
                                        wp[(j * 4 + par) * 4 + t4]);
                }
            }
    }
    int yy = y0 + ly, xx = lx;
#pragma unroll
    for (int j = 0; j < 3; ++j)
#pragma unroll
        for (int p = 0; p < 2; ++p) {
            float2 v;
            v.x = sig_(acc[j][p * 2 + 0]);
            v.y = sig_(acc[j][p * 2 + 1]);
            *(float2*)(out + (((long)n * 3 + j) * 64 + 2 * yy + p) * 64 + 2 * xx) = v;
        }
}

// ========================= weight / layout prep =============================
__global__ void prep_packs(const float* __restrict__ ec3_w, const float* __restrict__ ec4_w,
                           const float* __restrict__ dt1_w, const float* __restrict__ dt2_w,
                           unsigned short* __restrict__ WBe3, unsigned short* __restrict__ WBe4,
                           unsigned short* __restrict__ WBd1, unsigned short* __restrict__ WBd2) {
    int idx = blockIdx.x * 256 + threadIdx.x;
    if (idx < 131072) {  // ec3 conv: CI=64 CO=128 K=1024
        int li = idx;
        int j = li & 7, lane = (li >> 3) & 63;
        int kb = (li >> 9) & 31, nt = li >> 14;
        int k = kb * 32 + (lane >> 4) * 8 + j;
        int tap = k >> 6, ci = k & 63;
        int co = nt * 16 + (lane & 15);
        float f = ec3_w[((long)co * 64 + ci) * 16 + tap];
        WBe3[li] = f2bf(f);
    } else if (idx < 655360) {  // ec4 conv: CI=128 CO=256 K=2048
        int li = idx - 131072;
        int j = li & 7, lane = (li >> 3) & 63;
        int kb = (li >> 9) & 63, nt = li >> 15;
        int k = kb * 32 + (lane >> 4) * 8 + j;
        int tap = k >> 7, ci = k & 127;
        int co = nt * 16 + (lane & 15);
        float f = ec4_w[((long)co * 128 + ci) * 16 + tap];
        WBe4[li] = f2bf(f);
    } else if (idx < 1179648) {  // dt1 convt: CI=256 CO=128 Kp=1024
        int li = idx - 655360;
        int par = li >> 17; int rem = li & 131071;
        int j = rem & 7, lane = (rem >> 3) & 63;
        int kb = (rem >> 9) & 31, nt = rem >> 14;
        int k = kb * 32 + (lane >> 4) * 8 + j;
        int t4 = k >> 8, ci = k & 255;
        int p = par >> 1, q = par & 1, dh = t4 >> 1, dw = t4 & 1;
        int tap = (p + 2 * dh) * 4 + (q + 2 * dw);
        int co = nt * 16 + (lane & 15);
        float f = dt1_w[((long)co * 256 + ci) * 16 + tap];
        WBd1[(long)par * 262144 + rem] = f2bf(f);
    } else if (idx < 1310720) {  // dt2 convt: CI=128 CO=64 Kp=512
        int li = idx - 1179648;
        int par = li >> 15; int rem = li & 32767;
        int j = rem & 7, lane = (rem >> 3) & 63;
        int kb = (rem >> 9) & 15, nt = rem >> 13;
        int k = kb * 32 + (lane >> 4) * 8 + j;
        int t4 = k >> 7, ci = k & 127;
        int p = par >> 1, q = par & 1, dh = t4 >> 1, dw = t4 & 1;
        int tap = (p + 2 * dh) * 4 + (q + 2 * dw);
        int co = nt * 16 + (lane & 15);
        float f = dt2_w[((long)co * 128 + ci) * 16 + tap];
        WBd2[(long)par * 65536 + rem] = f2bf(f);
    }
}

__global__ void prep_tail(const float* __restrict__ ec1_w, const float* __restrict__ ec2_w,
                          const float* __restrict__ dt3_w, const float* __restrict__ dt4_w,
                          unsigned short* __restrict__ WBe1, unsigned short* __restrict__ WBe2,
                          unsigned short* __restrict__ WBd3, float4* __restrict__ WTd4) {
    int idx = blockIdx.x * 256 + threadIdx.x;
    if (idx < 2048) {
        int li = idx;
        int j = li & 7, lane = (li >> 3) & 63;
        int kb = (li >> 9) & 1, nt = li / 1024;
        int k = kb * 32 + (lane >> 4) * 8 + j;
        int tap = k >> 2, ci = k & 3;
        int co = nt * 16 + (lane & 15);
        float f = (ci < 3) ? ec1_w[((long)co * 3 + ci) * 16 + tap] : 0.f;
        WBe1[li] = f2bf(f);
    } else if (idx < 34816) {
        int li = idx - 2048;
        int j = li & 7, lane = (li >> 3) & 63;
        int kb = (li >> 9) & 15, nt = li / 8192;
        int k = kb * 32 + (lane >> 4) * 8 + j;
        int tap = k >> 5, ci = k & 31;
        int co = nt * 16 + (lane & 15);
        float f = ec2_w[((long)co * 32 + ci) * 16 + tap];
        WBe2[li] = f2bf(f);
    } else if (idx < 67584) {
        int li = idx - 34816;
        int par = li >> 13; int rem = li & 8191;
        int j = rem & 7, lane = (rem >> 3) & 63;
        int kb = (rem >> 9) & 7, nt = rem >> 12;
        int k = kb * 32 + (lane >> 4) * 8 + j;
        int t4 = k >> 6, ci = k & 63;
        int p = par >> 1, q = par & 1, dh = t4 >> 1, dw = t4 & 1;
        int tap = (p + 2 * dh) * 4 + (q + 2 * dw);
        int co = nt * 16 + (lane & 15);
        float f = dt3_w[((long)co * 64 + ci) * 16 + tap];
        WBd3[par * 16384 + rem] = f2bf(f);
    } else if (idx < 67968) {
        int li = idx - 67584;
        int t4 = li & 3, par = (li >> 2) & 3;
        int co = (li >> 4) % 3, ci4 = (li >> 4) / 3;
        int p = par >> 1, q = par & 1, dh = t4 >> 1, dw = t4 & 1;
        int tap = (p + 2 * dh) * 4 + (q + 2 * dw);
        float4 v; float* pv = (float*)&v;
#pragma unroll
        for (int l = 0; l < 4; ++l)
            pv[l] = dt4_w[((long)co * 32 + ci4 * 4 + l) * 16 + tap];
        WTd4[li] = v;
    }
}

__global__ void prep_r1(const float* __restrict__ wih_e, const float* __restrict__ wih_d,
                        const float* __restrict__ fc_w,
                        const float* __restrict__ bih_d, const float* __restrict__ bhh_d,
                        const float* __restrict__ fc_b,
                        const float* __restrict__ fcmu_w, const float* __restrict__ dfc_w,
                        const float* __restrict__ dfc_b,
                        float* __restrict__ WIHP_E, float* __restrict__ WIHP_D,
                        float* __restrict__ FCP, float* __restrict__ BIASDC,
                        float* __restrict__ FCMUP, float* __restrict__ DFCP,
                        float* __restrict__ DFCB) {
    int idx = blockIdx.x * 256 + threadIdx.x;
    if (idx < 262144) {
        int c = idx & 2047, m = idx >> 11;
        WIHP_E[idx] = wih_e[orig_row(c) * 128 + m];
    } else if (idx < 524288) {
        int li = idx - 262144;
        int c = li & 2047, m = li >> 11;
        WIHP_D[li] = wih_d[orig_row(c) * 128 + m];
    } else if (idx < 589824) {
        int li = idx - 524288;
        int r = li & 127, c = li >> 7;
        FCP[li] = fc_w[(long)r * 512 + c];
    } else if (idx < 591872) {
        int c = idx - 589824;
        int orow = orig_row(c);
        float s = bih_d[orow] + bhh_d[orow];
        for (int m = 0; m < 128; ++m) s += fc_b[m] * wih_d[orow * 128 + m];
        BIASDC[c] = s;
    } else if (idx < 1116160) {
        int li = idx - 591872;
        int j = li & 127, k = li >> 7;
        FCMUP[li] = fcmu_w[(long)j * 4096 + (k & 255) * 16 + (k >> 8)];
    } else {
        int li = idx - 1116160;
        int j = li & 4095, m = li >> 12;
        int jc = (j & 255) * 16 + (j >> 8);
        DFCP[li] = dfc_w[(long)jc * 128 + m];
        if (li < 4096) DFCB[li] = dfc_b[(li & 255) * 16 + (li >> 8)];
    }
}

__global__ void to_nhwc4v(const float* __restrict__ v, float4* __restrict__ out) {
    int idx = blockIdx.x * 256 + threadIdx.x;  // 1,048,576
    int w = idx & 63, h = (idx >> 6) & 63, n = idx >> 12;
    long base = (long)n * 12288 + h * 64 + w;
    float4 o;
    o.x = v[base];
    o.y = v[base + 4096];
    o.z = v[base + 8192];
    o.w = 0.f;
    out[idx] = o;
}

__global__ void pack_whh(const float* __restrict__ whh, float4* __restrict__ out) {
    int idx = blockIdx.x * 256 + threadIdx.x;  // 262144
    int c = idx & 2047, k4 = idx >> 11;
    const float4* src = (const float4*)(whh + orig_row(c) * 512);
    out[idx] = src[k4];
}

__global__ __launch_bounds__(256)
void merge_dc(const float* __restrict__ wih_d, const float* __restrict__ fc_w,
              const float* __restrict__ whh_d, float* __restrict__ out) {
    int cb = (blockIdx.x >> 3) * 64, kb = (blockIdx.x & 7) * 64;
    int tid = threadIdx.x;
    int cgl = (tid & 15) * 4, kgl = (tid >> 4) * 4;
    __shared__ float At[64][65];
    __shared__ float Bt[64][65];
    float acc[4][4] = {};
    for (int mc = 0; mc < 128; mc += 64) {
        __syncthreads();
        for (int i = tid; i < 4096; i += 256) {
            int cl = i >> 6, m = i & 63;
            At[cl][m] = wih_d[orig_row(cb + cl) * 128 + mc + m];
            Bt[cl][m] = fc_w[(mc + cl) * 512 + kb + m];
        }
        __syncthreads();
        for (int m = 0; m < 64; ++m) {
            float a[4], b[4];
#pragma unroll
            for (int i = 0; i < 4; ++i) { a[i] = At[cgl + i][m]; b[i] = Bt[m][kgl + i]; }
#pragma unroll
            for (int i = 0; i < 4; ++i)
#pragma unroll
                for (int j = 0; j < 4; ++j) acc[i][j] += a[i] * b[j];
        }
    }
    for (int i = 0; i < 4; ++i) {
        int c = cb + cgl + i; int orow = orig_row(c);
        for (int j = 0; j < 4; ++j) {
            int k = kb + kgl + j;
            out[((k >> 2) * 2048 + c) * 4 + (k & 3)] = acc[i][j] + whh_d[orow * 512 + k];
        }
    }
}

// ============================ LSTM / FC path ================================
__global__ __launch_bounds__(512)
void gx2_kernel(const float* __restrict__ Z,
                const float* __restrict__ wE, const float* __restrict__ biE,
                const float* __restrict__ bhE,
                const float* __restrict__ wD, const float* __restrict__ biD,
                const float* __restrict__ bhD,
                float* __restrict__ gxe, float* __restrict__ gxd0) {
    __shared__ float zl[2048];
    int bid = blockIdx.x, tid = threadIdx.x;
    if (bid < 128) {
        int rg = bid >> 2, cch = bid & 3;   // 32 groups of 8 rows
        for (int i = tid; i < 1024; i += 512)
            zl[i] = Z[(long)(rg * 8 + (i >> 7)) * 128 + (i & 127)];
        __syncthreads();
        int c = cch * 512 + tid;
        int orow = orig_row(c);
        float bsum = biE[orow] + bhE[orow];
        float acc[8];
#pragma unroll
        for (int r = 0; r < 8; ++r) acc[r] = bsum;
        for (int m = 0; m < 128; ++m) {
            float wv = wE[m * 2048 + c];
#pragma unroll
            for (int r = 0; r < 8; ++r) acc[r] += zl[r * 128 + m] * wv;
        }
        for (int r = 0; r < 8; ++r) gxe[(long)(rg * 8 + r) * 2048 + c] = acc[r];
    } else {
        int cch = bid - 128;
        for (int i = tid; i < 2048; i += 512)
            zl[i] = Z[(long)((i >> 7) * 16 + 15) * 128 + (i & 127)];
        __syncthreads();
        int c = cch * 512 + tid;
        int orow = orig_row(c);
        float bsum = biD[orow] + bhD[orow];
        float acc[16];
#pragma unroll
        for (int r = 0; r < 16; ++r) acc[r] = bsum;
        for (int m = 0; m < 128; ++m) {
            float wv = wD[m * 2048 + c];
#pragma unroll
            for (int r = 0; r < 16; ++r) acc[r] += zl[r * 128 + m] * wv;
        }
        for (int r = 0; r < 16; ++r) gxd0[(long)r * 2048 + c] = acc[r];
    }
}

// one LSTM step: 256 blocks x 256 threads; block owns 8 cols (2 j x 4 gates),
// 2-way k-split per column, LDS pair-reduce.
__global__ __launch_bounds__(256)
void lstm_step(const float4* __restrict__ wh4, const float* __restrict__ gadd,
               int gstride, const float* __restrict__ h_in, float* __restrict__ h_out,
               float* __restrict__ cst, float* __restrict__ hall) {
    __shared__ float hs[8192];
    __shared__ float gp[2][16][8];
    int tid = threadIdx.x;
    float4* hs4 = (float4*)hs;
    const float4* hi4 = (const float4*)h_in;
#pragma unroll
    for (int i = 0; i < 8; ++i) hs4[tid + 256 * i] = hi4[tid + 256 * i];
    __syncthreads();
    int col = tid & 7, n = (tid >> 3) & 15, kh = tid >> 7;
    int cg = blockIdx.x * 8 + col;
    const float4* wp = wh4 + cg;
    const float4* hv = (const float4*)(hs + n * 512);
    float acc = 0.f;
    int k0 = kh * 64;
#pragma unroll 8
    for (int k4 = k0; k4 < k0 + 64; ++k4) {
        float4 wv = wp[(long)k4 * 2048];
        float4 h4 = hv[k4];
        acc += wv.x * h4.x + wv.y * h4.y + wv.z * h4.z + wv.w * h4.w;
    }
    gp[kh][n][col] = acc;
    __syncthreads();
    if (tid < 128) {
        int cc = tid & 7, nn = tid >> 3;
        gp[0][nn][cc] = gp[0][nn][cc] + gp[1][nn][cc]
                      + gadd[nn * gstride + blockIdx.x * 8 + cc];
    }
    __syncthreads();
    if (tid < 32) {
        int c2 = tid & 1, n2 = tid >> 1;
        float gi = sig_(gp[0][n2][c2]);
        float gf = sig_(gp[0][n2][c2 + 2]);
        float gg = tanhf(gp[0][n2][c2 + 4]);
        float go = sig_(gp[0][n2][c2 + 6]);
        int j = blockIdx.x * 2 + c2;
        int idx = n2 * 512 + j;
        float cv = gf * cst[idx] + gi * gg;
        cst[idx] = cv;
        float hvv = go * tanhf(cv);
        h_out[idx] = hvv;
        if (hall) hall[idx] = hvv;
    }
}

// fcmu partials: 256 blocks = 16 row-groups x 16 k-slices (256 K each)
__global__ __launch_bounds__(512)
void fcmu_part(const unsigned short* __restrict__ xh,
               const float* __restrict__ wP, float* __restrict__ part) {
    int rg = blockIdx.x >> 4, ks = blockIdx.x & 15;
    int tid = threadIdx.x;
    __shared__ float xls[16 * 256];
    for (int i = tid; i < 4096; i += 512) {
        long gi = (long)(rg * 16 + (i >> 8)) * 4096 + ks * 256 + (i & 255);
        xls[i] = bf2f(xh[gi]);
    }
    __syncthreads();
    int j = tid & 127, rq = tid >> 7;
    float acc[4] = {0, 0, 0, 0};
    for (int k = 0; k < 256; ++k) {
        float wv = wP[(ks * 256 + k) * 128 + j];
#pragma unroll
        for (int i = 0; i < 4; ++i) acc[i] += xls[(rq + 4 * i) * 256 + k] * wv;
    }
    for (int i = 0; i < 4; ++i)
        part[((long)ks * 256 + rg * 16 + rq + 4 * i) * 128 + j] = acc[i];
}

__global__ void fcmu_red(const float* __restrict__ part, const float* __restrict__ b,
                         float* __restrict__ z) {
    int idx = blockIdx.x * 256 + threadIdx.x;  // 32768
    float s = b[idx & 127];
    for (int k = 0; k < 16; ++k) s += part[k * 32768 + idx];
    z[idx] = s;
}

// zs: 64 blocks = 16 t x 4 n-quads; thread = (j, n-local), 1 output
__global__ __launch_bounds__(512)
void zs_k(const float* __restrict__ hall, const float* __restrict__ fcP,
          const float* __restrict__ fcb, float* __restrict__ zs) {
    int t = blockIdx.x >> 2, nq = blockIdx.x & 3;
    int tid = threadIdx.x;
    __shared__ float hs[4 * 512];
    const float* h = hall + (long)t * 8192 + nq * 2048;
    for (int i = tid; i < 2048; i += 512) hs[i] = h[i];
    __syncthreads();
    int j = tid & 127, nl = tid >> 7;
    float a0 = 0.f, a1 = 0.f, a2 = 0.f, a3 = 0.f;
    const float* hr = hs + nl * 512;
    for (int k = 0; k < 512; k += 4) {
        a0 += hr[k] * fcP[k * 128 + j];
        a1 += hr[k + 1] * fcP[(k + 1) * 128 + j];
        a2 += hr[k + 2] * fcP[(k + 2) * 128 + j];
        a3 += hr[k + 3] * fcP[(k + 3) * 128 + j];
    }
    int n = nq * 4 + nl;
    zs[((long)n * 16 + t) * 128 + j] = (a0 + a1) + (a2 + a3) + fcb[j];
}

// dfc: 1024 blocks = 64 row-quads x 16 j-chunks (256 j each)
__global__ __launch_bounds__(256)
void dfc_k(const float* __restrict__ zs, const float* __restrict__ dP,
           const float* __restrict__ db, unsigned short* __restrict__ outh) {
    int rg = blockIdx.x >> 4, jc = blockIdx.x & 15;
    int tid = threadIdx.x;
    __shared__ float zl[512];
    for (int i = tid; i < 512; i += 256) zl[i] = zs[(long)rg * 512 + i];
    __syncthreads();
    int j = jc * 256 + tid;
    float acc[4] = {0.f, 0.f, 0.f, 0.f};
    for (int m = 0; m < 128; ++m) {
        float wv = dP[(long)m * 4096 + j];
#pragma unroll
        for (int r = 0; r < 4; ++r) acc[r] += zl[r * 128 + m] * wv;
    }
    float bv = db[j];
    for (int r = 0; r < 4; ++r) {
        float v = fmaxf(acc[r] + bv, 0.f);
        outh[(long)(rg * 4 + r) * 4096 + j] = f2bf(v);
    }
}

extern "C" void kernel_launch(void* const* d_in, const int* in_sizes, int n_in,
                              void* d_out, int out_size, void* d_ws, size_t ws_size,
                              hipStream_t stream) {
    (void)in_sizes; (void)n_in; (void)out_size; (void)ws_size;
    const float* video  = (const float*)d_in[0];
    const float* ec1_w  = (const float*)d_in[2];  const float* ec1_b = (const float*)d_in[3];
    const float* ec2_w  = (const float*)d_in[4];  const float* ec2_b = (const float*)d_in[5];
    const float* ec3_w  = (const float*)d_in[6];  const float* ec3_b = (const float*)d_in[7];
    const float* ec4_w  = (const float*)d_in[8];  const float* ec4_b = (const float*)d_in[9];
    const float* fcmu_w = (const float*)d_in[10]; const float* fcmu_b = (const float*)d_in[11];
    const float* dfc_w  = (const float*)d_in[12]; const float* dfc_b = (const float*)d_in[13];
    const float* dt1_w  = (const float*)d_in[14]; const float* dt1_b = (const float*)d_in[15];
    const float* dt2_w  = (const float*)d_in[16]; const float* dt2_b = (const float*)d_in[17];
    const float* dt3_w  = (const float*)d_in[18]; const float* dt3_b = (const float*)d_in[19];
    const float* dt4_w  = (const float*)d_in[20]; const float* dt4_b = (const float*)d_in[21];
    const float* wih_e  = (const float*)d_in[22]; const float* whh_e = (const float*)d_in[23];
    const float* bih_e  = (const float*)d_in[24]; const float* bhh_e = (const float*)d_in[25];
    const float* wih_d  = (const float*)d_in[26]; const float* whh_d = (const float*)d_in[27];
    const float* bih_d  = (const float*)d_in[28]; const float* bhh_d = (const float*)d_in[29];
    const float* fc_w   = (const float*)d_in[30]; const float* fc_b  = (const float*)d_in[31];

    char* wsb = (char*)d_ws;
    unsigned short* B1h = (unsigned short*)wsb;              // 8,388,608 e
    float*          X0f = (float*)(wsb + 33554432);
    unsigned short* B2h = (unsigned short*)(wsb + 33554432); // 4,194,304 e
    unsigned short* B3h = (unsigned short*)(wsb + 50331648); // 2,097,152 e
    unsigned short* B4h = (unsigned short*)(wsb + 58720256); // 1,048,576 e
    float* R1f    = (float*)wsb;
    float* WH4_E  = R1f;
    float* WH4_DC = R1f + 1048576;
    float* WIHP_E = R1f + 2097152;
    float* WIHP_D = R1f + 2359296;
    float* GX_E   = R1f + 2621440;
    float* GX_D0  = R1f + 3145728;
    float* BIASDC = R1f + 3178496;
    float* HA     = R1f + 3180544;
    float* HB     = R1f + 3188736;
    float* CB     = R1f + 3196928;
    float* HALL   = R1f + 3205120;
    float* FCMUP  = R1f + 3336192;
    float* FCP    = R1f + 4122624;
    float* DFCP   = R1f + 4188160;
    float* DFCB   = R1f + 4712448;
    float* Z      = R1f + 4716544;
    float* ZS     = R1f + 4749312;
    unsigned short* WBe3 = (unsigned short*)(R1f + 4782080);
    unsigned short* WBe4 = (unsigned short*)(R1f + 4913152);
    unsigned short* WBd1 = (unsigned short*)(R1f + 5437440);
    unsigned short* WBd2 = (unsigned short*)(R1f + 5961728);
    float* ZPART  = R1f + 6092800;   // 524,288 (16 k-slices)
    float* WH4_D0 = R1f + 6617088;   // 1,048,576 (decoder step-0 whh pack)
    unsigned short* WBe1 = (unsigned short*)(wsb + 62914560);
    unsigned short* WBe2 = (unsigned short*)(wsb + 62922752);
    unsigned short* WBd3 = (unsigned short*)(wsb + 63053824);
    float*          WTd4 = (float*)(wsb + 63184896);

    // ---- merged tail prep + encoder ec1/ec2 ----
    prep_tail<<<266, 256, 0, stream>>>(ec1_w, ec2_w, dt3_w, dt4_w,
                                       WBe1, WBe2, WBd3, (float4*)WTd4);
    to_nhwc4v<<<4096, 256, 0, stream>>>(video, (float4*)X0f);
    conv_mfma<4, 64, 64, 32, 2, 4, 1, 0, 1><<<1024, 256, 0, stream>>>(
        nullptr, X0f, WBe1, ec1_b, B1h);
    conv_mfma<32, 32, 32, 64, 2, 2, 2, 0, 0><<<512, 256, 0, stream>>>(
        B1h, nullptr, WBe2, ec2_b, B2h);

    // ---- R1 free: merged preps ----
    prep_r1<<<6408, 256, 0, stream>>>(wih_e, wih_d, fc_w, bih_d, bhh_d, fc_b,
                                      fcmu_w, dfc_w, dfc_b,
                                      WIHP_E, WIHP_D, FCP, BIASDC, FCMUP, DFCP, DFCB);
    prep_packs<<<5120, 256, 0, stream>>>(ec3_w, ec4_w, dt1_w, dt2_w,
                                         WBe3, WBe4, WBd1, WBd2);
    pack_whh<<<1024, 256, 0, stream>>>(whh_e, (float4*)WH4_E);
    pack_whh<<<1024, 256, 0, stream>>>(whh_d, (float4*)WH4_D0);
    merge_dc<<<256, 256, 0, stream>>>(wih_d, fc_w, whh_d, WH4_DC);
    hipMemsetAsync(HA, 0, 3 * 8192 * sizeof(float), stream);

    // ---- encoder ec3/ec4 + fcmu ----
    conv_mfma<64, 16, 16, 128, 1, 2, 2, 0, 0><<<512, 256, 0, stream>>>(
        B2h, nullptr, WBe3, ec3_b, B3h);
    conv_mfma<128, 8, 8, 256, 1, 1, 2, 0, 0><<<512, 128, 0, stream>>>(
        B3h, nullptr, WBe4, ec4_b, B4h);
    fcmu_part<<<256, 512, 0, stream>>>(B4h, FCMUP, ZPART);
    fcmu_red<<<128, 256, 0, stream>>>(ZPART, fcmu_b, Z);

    // ---- merged x projections ----
    gx2_kernel<<<132, 512, 0, stream>>>(Z, WIHP_E, bih_e, bhh_e,
                                        WIHP_D, bih_d, bhh_d, GX_E, GX_D0);

    // ---- LSTM chains (per-step launches; coop grid-sync measured 5x slower) ----
    float* hin = HA; float* hout = HB;
    for (int t = 0; t < 16; ++t) {
        lstm_step<<<256, 256, 0, stream>>>((const float4*)WH4_E, GX_E + t * 2048, 32768,
                                           hin, hout, CB, (float*)nullptr);
        float* tmp = hin; hin = hout; hout = tmp;
    }
    lstm_step<<<256, 256, 0, stream>>>((const float4*)WH4_D0, GX_D0, 2048,
                                       hin, hout, CB, HALL);
    { float* tmp = hin; hin = hout; hout = tmp; }
    for (int t = 1; t < 16; ++t) {
        lstm_step<<<256, 256, 0, stream>>>((const float4*)WH4_DC, BIASDC, 0,
                                           hin, hout, CB, HALL + t * 8192);
        float* tmp = hin; hin = hout; hout = tmp;
    }
    zs_k<<<64, 512, 0, stream>>>(HALL, FCP, fc_b, ZS);

    // ---- decoder ----
    dfc_k<<<1024, 256, 0, stream>>>(ZS, DFCP, DFCB, B4h);
    conv_mfma<256, 4, 4, 128, 1, 2, 2, 1, 0><<<512, 256, 0, stream>>>(
        B4h, nullptr, WBd1, dt1_b, B3h);
    conv_mfma<128, 8, 8, 64, 2, 2, 2, 1, 0><<<512, 256, 0, stream>>>(
        B3h, nullptr, WBd2, dt2_b, B2h);
    conv_mfma<64, 16, 16, 32, 2, 4, 1, 1, 0><<<1024, 256, 0, stream>>>(
        B2h, nullptr, WBd3, dt3_b, B1h);
    dt4_tiled<<<2048, 128, 0, stream>>>(B1h, (const float4*)WTd4, dt4_b, (float*)d_out);
}